// Round 9
// baseline (1413.117 us; speedup 1.0000x reference)
//
#include <hip/hip_runtime.h>

#define HW 65536
#define NC 12
#define NF 64
#define NT 8
#define P2 260   // padded pitch (2-wide zero border each side)

typedef float2 c32;
typedef __attribute__((ext_vector_type(8))) short bf16x8;   // 8 bf16 = 4 VGPR
typedef __attribute__((ext_vector_type(4))) float f32x4;    // MFMA C/D

__device__ __forceinline__ float ssign(int p) {
    return ((p ^ (p >> 8)) & 1) ? -1.0f : 1.0f;
}

__device__ __forceinline__ short f2bf(float f) {   // RNE float->bf16
    union { float f; unsigned u; } v; v.f = f;
    unsigned r = (v.u + 0x7FFFu + ((v.u >> 16) & 1u)) >> 16;
    return (short)r;
}

// ===================== 256-point radix-2 DIT FFT in LDS =====================
__device__ __forceinline__ void fft256_stages(c32* X, const c32* tw, int j, float conjf) {
    #pragma unroll
    for (int s = 1; s <= 8; ++s) {
        const int half = 1 << (s - 1);
        #pragma unroll
        for (int b = 0; b < 2; ++b) {
            int idx = j + (b << 6);
            int grp = idx >> (s - 1);
            int pos = idx & (half - 1);
            int i0 = (grp << s) + pos;
            int i1 = i0 + half;
            c32 w = tw[pos << (8 - s)];
            float wy = conjf * w.y;
            c32 a = X[i0], cc = X[i1];
            c32 t = make_float2(w.x * cc.x - wy * cc.y, w.x * cc.y + wy * cc.x);
            X[i0] = make_float2(a.x + t.x, a.y + t.y);
            X[i1] = make_float2(a.x - t.x, a.y - t.y);
        }
        __syncthreads();
    }
}

__device__ __forceinline__ void build_tw(c32* tw, int tid) {
    if (tid < 128) {
        float a = -3.14159265358979323846f * (float)tid * (1.0f / 128.0f);
        float sv, cv;
        sincosf(a, &sv, &cv);
        tw[tid] = make_float2(cv, sv);
    }
}

__global__ __launch_bounds__(256) void fft_rows(c32* __restrict__ buf, float conjf) {
    __shared__ c32 lds[4][256];
    __shared__ c32 tw[128];
    int tid = threadIdx.x;
    build_tw(tw, tid);
    int wid = tid >> 6, j = tid & 63;
    c32* rp = buf + (size_t)(blockIdx.x * 4 + wid) * 256;
    c32* X = lds[wid];
    #pragma unroll
    for (int e = 0; e < 4; ++e) {
        int n = (e << 6) + j;
        X[__brev((unsigned)n) >> 24] = rp[n];
    }
    __syncthreads();
    fft256_stages(X, tw, j, conjf);
    #pragma unroll
    for (int e = 0; e < 4; ++e) {
        int n = (e << 6) + j;
        rp[n] = X[n];
    }
}

__global__ __launch_bounds__(256) void fft_rows_pre(c32* __restrict__ buf,
        const c32* __restrict__ pred) {
    __shared__ c32 lds[4][256];
    __shared__ c32 tw[128];
    int tid = threadIdx.x;
    build_tw(tw, tid);
    int wid = tid >> 6, j = tid & 63;
    int r = blockIdx.x * 4 + wid;
    int coil = r >> 8, y = r & 255;
    c32* rp = buf + (size_t)r * 256;
    c32* X = lds[wid];
    #pragma unroll
    for (int e = 0; e < 4; ++e) {
        int n = (e << 6) + j;
        float s = ((n + y) & 1) ? -1.0f : 1.0f;
        c32 pv = pred[(size_t)coil * HW + y * 256 + n];
        X[__brev((unsigned)n) >> 24] = make_float2(s * pv.x, s * pv.y);
    }
    __syncthreads();
    fft256_stages(X, tw, j, -1.0f);
    #pragma unroll
    for (int e = 0; e < 4; ++e) {
        int n = (e << 6) + j;
        rp[n] = X[n];
    }
}

__global__ __launch_bounds__(256) void fft_rows_exp(c32* __restrict__ buf,
        const c32* __restrict__ eta, const c32* __restrict__ sense) {
    __shared__ c32 lds[4][256];
    __shared__ c32 tw[128];
    int tid = threadIdx.x;
    build_tw(tw, tid);
    int wid = tid >> 6, j = tid & 63;
    int r = blockIdx.x * 4 + wid;
    int coil = r >> 8, y = r & 255;
    c32* rp = buf + (size_t)r * 256;
    c32* X = lds[wid];
    #pragma unroll
    for (int e = 0; e < 4; ++e) {
        int n = (e << 6) + j;
        float s = ((n + y) & 1) ? -1.0f : 1.0f;
        c32 ev = eta[y * 256 + n];
        c32 sn = sense[(size_t)coil * HW + y * 256 + n];
        X[__brev((unsigned)n) >> 24] =
            make_float2(s * (ev.x * sn.x - ev.y * sn.y),
                        s * (ev.x * sn.y + ev.y * sn.x));
    }
    __syncthreads();
    fft256_stages(X, tw, j, 1.0f);
    #pragma unroll
    for (int e = 0; e < 4; ++e) {
        int n = (e << 6) + j;
        rp[n] = X[n];
    }
}

__global__ __launch_bounds__(256) void fft_cols(c32* __restrict__ buf, float conjf) {
    __shared__ c32 lds[4][257];
    __shared__ c32 tw[128];
    int tid = threadIdx.x;
    build_tw(tw, tid);
    c32* ip = buf + (size_t)blockIdx.y * HW;
    int x0 = blockIdx.x * 4;
    int cl = tid & 3, yb = tid >> 2;
    #pragma unroll
    for (int e = 0; e < 4; ++e) {
        int y = yb + (e << 6);
        lds[cl][__brev((unsigned)y) >> 24] = ip[y * 256 + x0 + cl];
    }
    __syncthreads();
    int col = tid >> 6, j = tid & 63;
    fft256_stages(&lds[col][0], tw, j, conjf);
    #pragma unroll
    for (int e = 0; e < 4; ++e) {
        int y = yb + (e << 6);
        ip[y * 256 + x0 + cl] = lds[cl][y];
    }
}

// Fused: fwd col FFT -> (out write + masked residual) -> inv col FFT, one LDS tile.
__global__ __launch_bounds__(256) void fft_cols_fused(c32* __restrict__ buf,
        const c32* __restrict__ base, const c32* __restrict__ ksp,
        const int* __restrict__ mask, c32* __restrict__ outp, int write_out) {
    __shared__ c32 lds[4][257];
    __shared__ c32 tw[128];
    int tid = threadIdx.x;
    build_tw(tw, tid);
    int coil = blockIdx.y;
    c32* ip = buf + (size_t)coil * HW;
    int x0 = blockIdx.x * 4;
    int cl = tid & 3, yb = tid >> 2;
    #pragma unroll
    for (int e = 0; e < 4; ++e) {
        int y = yb + (e << 6);
        lds[cl][__brev((unsigned)y) >> 24] = ip[y * 256 + x0 + cl];
    }
    __syncthreads();
    int col = tid >> 6, j = tid & 63;
    fft256_stages(&lds[col][0], tw, j, 1.0f);

    int x = x0 + cl;
    c32 G[4];
    #pragma unroll
    for (int e = 0; e < 4; ++e) {
        int y = yb + (e << 6);
        G[e] = lds[cl][y];
    }
    __syncthreads();
    #pragma unroll
    for (int e = 0; e < 4; ++e) {
        int y = yb + (e << 6);
        int p = y * 256 + x;
        size_t i = (size_t)coil * HW + p;
        float s = ((p ^ (p >> 8)) & 1) ? -1.0f : 1.0f;
        if (write_out) {
            c32 bv = base[i];
            float sc = s * (1.0f / 256.0f);
            outp[i] = make_float2(bv.x - sc * G[e].x, bv.y - sc * G[e].y);
        }
        c32 rv = make_float2(0.f, 0.f);
        if (mask[p]) {
            c32 k = ksp[i];
            rv = make_float2(G[e].x * (1.0f / 256.0f) - s * k.x,
                             G[e].y * (1.0f / 256.0f) - s * k.y);
        }
        lds[cl][__brev((unsigned)y) >> 24] = rv;
    }
    __syncthreads();
    fft256_stages(&lds[col][0], tw, j, -1.0f);
    #pragma unroll
    for (int e = 0; e < 4; ++e) {
        int y = yb + (e << 6);
        ip[y * 256 + x0 + cl] = lds[cl][y];
    }
}

// ===================== pointwise kernels =====================
__global__ __launch_bounds__(256) void k_combine_eta0(const c32* __restrict__ tmp,
        const c32* __restrict__ sense, c32* __restrict__ eta) {
    int p = blockIdx.x * 256 + threadIdx.x;
    float ax = 0.f, ay = 0.f;
    for (int c = 0; c < NC; ++c) {
        c32 t = tmp[c * HW + p], s = sense[c * HW + p];
        ax += t.x * s.x + t.y * s.y;
        ay += t.y * s.x - t.x * s.y;
    }
    float sc = ssign(p) * (1.0f / 256.0f);
    eta[p] = make_float2(ax * sc, ay * sc);
}

__global__ __launch_bounds__(256) void k_base(const c32* __restrict__ ksp,
        const c32* __restrict__ pred, const int* __restrict__ mask,
        const float* __restrict__ dcw, c32* __restrict__ base) {
    int i = blockIdx.x * 256 + threadIdx.x;
    int p = i & (HW - 1);
    c32 k = ksp[i];
    c32 o = k;
    if (mask[p]) {
        float w = dcw[0];
        c32 pr = pred[i];
        o.x -= (pr.x - k.x) * w;
        o.y -= (pr.y - k.y) * w;
    }
    base[i] = o;
}

// grad+g -> padded transposed bf16 gTp[(y+2)*P2 + x+2][4]
__global__ __launch_bounds__(256) void k_grad_g(const c32* __restrict__ tmp,
        const c32* __restrict__ sense, const c32* __restrict__ eta,
        short* __restrict__ gTp) {
    int p = blockIdx.x * 256 + threadIdx.x;
    float ax = 0.f, ay = 0.f;
    for (int c = 0; c < NC; ++c) {
        c32 t = tmp[c * HW + p], s = sense[c * HW + p];
        ax += t.x * s.x + t.y * s.y;
        ay += t.y * s.x - t.x * s.y;
    }
    float sc = ssign(p) * (1.0f / 256.0f);
    c32 e = eta[p];
    ushort4 o;
    o.x = (unsigned short)f2bf(e.x);
    o.y = (unsigned short)f2bf(e.y);
    o.z = (unsigned short)f2bf(ax * sc);
    o.w = (unsigned short)f2bf(ay * sc);
    int y = p >> 8, x = p & 255;
    ((ushort4*)gTp)[(y + 2) * P2 + x + 2] = o;
}

// ===================== weight prep kernels =====================
__global__ __launch_bounds__(256) void k_prep_c1(const float* __restrict__ w,
        short* __restrict__ wA) {
    int i = blockIdx.x * 256 + threadIdx.x;    // 64*128
    int co = i >> 7, k = i & 127;
    int tap = k >> 2, ci = k & 3;
    float v = (tap < 25) ? w[co * 100 + ci * 25 + tap] : 0.f;
    wA[i] = f2bf(v);
}

__global__ __launch_bounds__(256) void k_prep_c2(const float* __restrict__ w,
        short* __restrict__ wA) {
    int i = blockIdx.x * 256 + threadIdx.x;     // 36864
    int tap = i >> 12, co = (i >> 6) & 63, ci = i & 63;
    wA[i] = f2bf(w[co * 576 + ci * 9 + tap]);
}

__global__ __launch_bounds__(256) void k_prep_cf(const float* __restrict__ w,
        short* __restrict__ wA) {
    int i = blockIdx.x * 256 + threadIdx.x;    // 9216
    int tap = i >> 10, r = (i >> 6) & 15, ci = i & 63;
    float v = (r < 2) ? w[r * 576 + ci * 9 + tap] : 0.f;
    wA[i] = f2bf(v);
}

__global__ __launch_bounds__(128) void k_prep_gru(const float* __restrict__ ihw,
        const float* __restrict__ ihb, const float* __restrict__ hhw,
        const float* __restrict__ hhb, short* __restrict__ w2, float* __restrict__ bias) {
    int k = threadIdx.x;
    int r = blockIdx.x;
    int g = r >> 6, co = r & 63;
    float v = 0.f;
    if (g == 0)      v = (k < 64) ? ihw[co * 64 + k]         : hhw[co * 64 + k - 64];
    else if (g == 1) v = (k < 64) ? ihw[(64 + co) * 64 + k]  : hhw[(64 + co) * 64 + k - 64];
    else if (g == 2) v = (k < 64) ? ihw[(128 + co) * 64 + k] : 0.f;
    else             v = (k < 64) ? 0.f : hhw[(128 + co) * 64 + k - 64];
    w2[r * 128 + k] = f2bf(v);
    if (k == 0) {
        float b = (g == 0) ? ihb[co] + hhb[co]
                : (g == 1) ? ihb[64 + co] + hhb[64 + co]
                : (g == 2) ? ihb[128 + co] : hhb[128 + co];
        bias[r] = b;
    }
}

// ===================== conv1 via MFMA (padded, branchless, hoisted B) ======
// grid 2048 (y*8 xseg), 256 thr. Wave wv: co [16wv,16wv+16). nt=2 (32 px/wave).
__global__ __launch_bounds__(256, 2) void conv1_mfma(const short* __restrict__ gTp,
        const short* __restrict__ wA, const float* __restrict__ bias,
        float* __restrict__ out) {
    int wv = threadIdx.x >> 6, l = threadIdx.x & 63;
    int lr = l & 15, lg = l >> 4;
    int y = blockIdx.x >> 3;
    int x0 = (blockIdx.x & 7) << 5;

    bf16x8 A[4];
    const short* pA = wA + (size_t)(wv * 16 + lr) * 128 + lg * 8;
    #pragma unroll
    for (int kt = 0; kt < 4; ++kt) A[kt] = *(const bf16x8*)(pA + kt * 32);

    // hoist all B fragments (2 nt x 4 kt), unconditional padded loads
    bf16x8 B[2][4];
    #pragma unroll
    for (int nt = 0; nt < 2; ++nt) {
        int x = x0 + nt * 16 + lr;
        #pragma unroll
        for (int kt = 0; kt < 4; ++kt) {
            int t0 = kt * 8 + lg * 2;
            #pragma unroll
            for (int half = 0; half < 2; ++half) {
                int tap = t0 + half;
                int tt = (tap < 25) ? tap : 0;   // pad taps: A rows are zero
                int dy = tt / 5 - 2, dx = tt % 5 - 2;
                ushort4 v = *(const ushort4*)(gTp +
                    ((size_t)((y + dy + 2) * P2 + (x + dx + 2)) << 2));
                B[nt][kt][half * 4 + 0] = (short)v.x;
                B[nt][kt][half * 4 + 1] = (short)v.y;
                B[nt][kt][half * 4 + 2] = (short)v.z;
                B[nt][kt][half * 4 + 3] = (short)v.w;
            }
        }
    }
    f32x4 C[2];
    #pragma unroll
    for (int nt = 0; nt < 2; ++nt) {
        C[nt] = (f32x4){0.f, 0.f, 0.f, 0.f};
        #pragma unroll
        for (int kt = 0; kt < 4; ++kt)
            C[nt] = __builtin_amdgcn_mfma_f32_16x16x32_bf16(A[kt], B[nt][kt], C[nt], 0, 0, 0);
    }
    int co = wv * 16 + lg * 4;
    #pragma unroll
    for (int nt = 0; nt < 2; ++nt) {
        int px = y * 256 + x0 + nt * 16 + lr;
        #pragma unroll
        for (int i = 0; i < 4; ++i)
            out[(size_t)(co + i) * HW + px] = fmaxf(C[nt][i] + bias[co + i], 0.f);
    }
}

// ===================== conv2 via MFMA (padded, branchless, prefetch) =======
// grid 2048, 256 thr, nt=2.
__global__ __launch_bounds__(256, 2) void conv2_mfma(const short* __restrict__ hTp,
        const short* __restrict__ wA, const float* __restrict__ bias,
        float* __restrict__ out) {
    int wv = threadIdx.x >> 6, l = threadIdx.x & 63;
    int lr = l & 15, lg = l >> 4;
    int y = blockIdx.x >> 3;
    int x0 = (blockIdx.x & 7) << 5;

    f32x4 C[2];
    C[0] = (f32x4){0.f, 0.f, 0.f, 0.f};
    C[1] = (f32x4){0.f, 0.f, 0.f, 0.f};

    auto loadB = [&](int tap, bf16x8 b0[2], bf16x8 b1[2]) {
        int dy = (tap / 3 - 1) * 2, dx = (tap % 3 - 1) * 2;
        #pragma unroll
        for (int nt = 0; nt < 2; ++nt) {
            int xx = x0 + nt * 16 + lr + dx;
            const short* pB = hTp +
                ((size_t)((y + dy + 2) * P2 + (xx + 2)) << 6) + lg * 8;
            b0[nt] = *(const bf16x8*)(pB);
            b1[nt] = *(const bf16x8*)(pB + 32);
        }
    };

    bf16x8 cB0[2], cB1[2];
    loadB(0, cB0, cB1);
    #pragma unroll
    for (int tap = 0; tap < 9; ++tap) {
        const short* pA = wA + (size_t)(tap * 64 + wv * 16 + lr) * 64 + lg * 8;
        bf16x8 A0 = *(const bf16x8*)(pA);
        bf16x8 A1 = *(const bf16x8*)(pA + 32);
        bf16x8 nB0[2], nB1[2];
        if (tap < 8) loadB(tap + 1, nB0, nB1);
        #pragma unroll
        for (int nt = 0; nt < 2; ++nt) {
            C[nt] = __builtin_amdgcn_mfma_f32_16x16x32_bf16(A0, cB0[nt], C[nt], 0, 0, 0);
            C[nt] = __builtin_amdgcn_mfma_f32_16x16x32_bf16(A1, cB1[nt], C[nt], 0, 0, 0);
        }
        if (tap < 8) {
            cB0[0] = nB0[0]; cB0[1] = nB0[1];
            cB1[0] = nB1[0]; cB1[1] = nB1[1];
        }
    }
    int co = wv * 16 + lg * 4;
    #pragma unroll
    for (int nt = 0; nt < 2; ++nt) {
        int px = y * 256 + x0 + nt * 16 + lr;
        #pragma unroll
        for (int i = 0; i < 4; ++i)
            out[(size_t)(co + i) * HW + px] = fmaxf(C[nt][i] + bias[co + i], 0.f);
    }
}

// ===================== GRU via MFMA (padded hT emit) =====================
__global__ __launch_bounds__(256, 2) void gru_mfma(const float* __restrict__ xin,
        const float* __restrict__ h, const short* __restrict__ w2,
        const float* __restrict__ bias, float* __restrict__ hout,
        short* __restrict__ hTp) {
    int wv = threadIdx.x >> 6, l = threadIdx.x & 63;
    int lr = l & 15, lg = l >> 4;
    int px0 = blockIdx.x * 64;

    bf16x8 A0[4], A1[4], A2[2], A3[2];
    {
        const short* w0 = w2 + (0   + wv * 16 + lr) * 128 + lg * 8;
        const short* w1 = w2 + (64  + wv * 16 + lr) * 128 + lg * 8;
        const short* w2p = w2 + (128 + wv * 16 + lr) * 128 + lg * 8;
        const short* w3 = w2 + (192 + wv * 16 + lr) * 128 + lg * 8;
        #pragma unroll
        for (int kt = 0; kt < 4; ++kt) {
            A0[kt] = *(const bf16x8*)(w0 + kt * 32);
            A1[kt] = *(const bf16x8*)(w1 + kt * 32);
        }
        A2[0] = *(const bf16x8*)(w2p);          A2[1] = *(const bf16x8*)(w2p + 32);
        A3[0] = *(const bf16x8*)(w3 + 64);      A3[1] = *(const bf16x8*)(w3 + 96);
    }

    f32x4 C0[4], C1[4], C2[4], C3[4];
    #pragma unroll
    for (int nt = 0; nt < 4; ++nt) {
        C0[nt] = (f32x4){0.f, 0.f, 0.f, 0.f};
        C1[nt] = (f32x4){0.f, 0.f, 0.f, 0.f};
        C2[nt] = (f32x4){0.f, 0.f, 0.f, 0.f};
        C3[nt] = (f32x4){0.f, 0.f, 0.f, 0.f};
    }

    #pragma unroll
    for (int nt = 0; nt < 4; ++nt) {
        int px = px0 + nt * 16 + lr;
        bf16x8 B[4];
        #pragma unroll
        for (int kt = 0; kt < 4; ++kt) {
            const float* src = (kt < 2) ? xin + (size_t)(kt * 32 + lg * 8) * HW + px
                                        : h   + (size_t)((kt - 2) * 32 + lg * 8) * HW + px;
            #pragma unroll
            for (int j = 0; j < 8; ++j) B[kt][j] = f2bf(src[(size_t)j * HW]);
        }
        #pragma unroll
        for (int kt = 0; kt < 4; ++kt) {
            C0[nt] = __builtin_amdgcn_mfma_f32_16x16x32_bf16(A0[kt], B[kt], C0[nt], 0, 0, 0);
            C1[nt] = __builtin_amdgcn_mfma_f32_16x16x32_bf16(A1[kt], B[kt], C1[nt], 0, 0, 0);
        }
        C2[nt] = __builtin_amdgcn_mfma_f32_16x16x32_bf16(A2[0], B[0], C2[nt], 0, 0, 0);
        C2[nt] = __builtin_amdgcn_mfma_f32_16x16x32_bf16(A2[1], B[1], C2[nt], 0, 0, 0);
        C3[nt] = __builtin_amdgcn_mfma_f32_16x16x32_bf16(A3[0], B[2], C3[nt], 0, 0, 0);
        C3[nt] = __builtin_amdgcn_mfma_f32_16x16x32_bf16(A3[1], B[3], C3[nt], 0, 0, 0);
    }

    int co = wv * 16 + lg * 4;
    float br[4], bz[4], bin_[4], bhn[4];
    #pragma unroll
    for (int i = 0; i < 4; ++i) {
        br[i]   = bias[co + i];
        bz[i]   = bias[64 + co + i];
        bin_[i] = bias[128 + co + i];
        bhn[i]  = bias[192 + co + i];
    }
    #pragma unroll
    for (int nt = 0; nt < 4; ++nt) {
        int px = px0 + nt * 16 + lr;
        int y = px >> 8, x = px & 255;
        size_t tb = ((size_t)((y + 2) * P2 + (x + 2)) << 6);
        #pragma unroll
        for (int i = 0; i < 4; ++i) {
            float r = 1.0f / (1.0f + expf(-(C0[nt][i] + br[i])));
            float z = 1.0f / (1.0f + expf(-(C1[nt][i] + bz[i])));
            float nn = tanhf(C2[nt][i] + bin_[i] + r * (C3[nt][i] + bhn[i]));
            float ho = h[(size_t)(co + i) * HW + px];
            float hv = (1.0f - z) * nn + z * ho;
            hout[(size_t)(co + i) * HW + px] = hv;
            hTp[tb + co + i] = f2bf(hv);
        }
    }
}

// ===================== final conv via MFMA (padded, prefetch) ==============
__global__ __launch_bounds__(256, 2) void final_mfma(const short* __restrict__ hTp,
        const short* __restrict__ wA, c32* __restrict__ eta) {
    int wv = threadIdx.x >> 6, l = threadIdx.x & 63;
    int lr = l & 15, lg = l >> 4;
    int y = blockIdx.x >> 2;
    int x0 = (blockIdx.x & 3) << 6;
    int x = x0 + wv * 16 + lr;

    auto loadB = [&](int tap, bf16x8& b0, bf16x8& b1) {
        int dy = tap / 3 - 1, dx = tap % 3 - 1;
        const short* pB = hTp +
            ((size_t)((y + dy + 2) * P2 + (x + dx + 2)) << 6) + lg * 8;
        b0 = *(const bf16x8*)(pB);
        b1 = *(const bf16x8*)(pB + 32);
    };

    f32x4 C = (f32x4){0.f, 0.f, 0.f, 0.f};
    bf16x8 cB0, cB1;
    loadB(0, cB0, cB1);
    #pragma unroll
    for (int tap = 0; tap < 9; ++tap) {
        const short* pA = wA + (size_t)(tap * 16 + lr) * 64 + lg * 8;
        bf16x8 A0 = *(const bf16x8*)(pA);
        bf16x8 A1 = *(const bf16x8*)(pA + 32);
        bf16x8 nB0, nB1;
        if (tap < 8) loadB(tap + 1, nB0, nB1);
        C = __builtin_amdgcn_mfma_f32_16x16x32_bf16(A0, cB0, C, 0, 0, 0);
        C = __builtin_amdgcn_mfma_f32_16x16x32_bf16(A1, cB1, C, 0, 0, 0);
        if (tap < 8) { cB0 = nB0; cB1 = nB1; }
    }
    if (lg == 0) {
        int px = y * 256 + x;
        c32 e = eta[px];
        eta[px] = make_float2(e.x + C[0], e.y + C[1]);
    }
}

// ===================== host orchestration =====================
extern "C" void kernel_launch(void* const* d_in, const int* in_sizes, int n_in,
                              void* d_out, int out_size, void* d_ws, size_t ws_size,
                              hipStream_t stream) {
    const c32* pred   = (const c32*)d_in[0];
    const c32* ksp    = (const c32*)d_in[1];
    const c32* sense  = (const c32*)d_in[2];
    const int* mask   = (const int*)d_in[3];
    const float* c1w  = (const float*)d_in[4];
    const float* c1b  = (const float*)d_in[5];
    const float* g1iw = (const float*)d_in[6];
    const float* g1ib = (const float*)d_in[7];
    const float* g1hw = (const float*)d_in[8];
    const float* g1hb = (const float*)d_in[9];
    const float* c2w  = (const float*)d_in[10];
    const float* c2b  = (const float*)d_in[11];
    const float* g2iw = (const float*)d_in[12];
    const float* g2ib = (const float*)d_in[13];
    const float* g2hw = (const float*)d_in[14];
    const float* g2hb = (const float*)d_in[15];
    const float* fw   = (const float*)d_in[16];
    const float* dcw  = (const float*)d_in[17];

    const size_t PP = (size_t)P2 * P2;     // 67600 padded pixels
    float* w0 = (float*)d_ws;
    c32* base = (c32*)w0;                  // NC*HW complex
    c32* Fk   = base + NC * HW;            // NC*HW complex
    c32* tmp  = Fk + NC * HW;              // NC*HW complex (init only)
    c32* eta  = tmp + NC * HW;             // HW complex
    short* gTp = (short*)(eta + HW);       // PP*4 bf16 (padded)
    float* x1 = (float*)(gTp + PP * 4);    // NF*HW
    float* h1a = x1 + NF * HW;
    float* h1b = h1a + NF * HW;
    float* h2a = h1b + NF * HW;
    float* h2b = h2a + NF * HW;
    short* w2a  = (short*)(h2b + NF * HW); // 256*128 bf16
    short* w2b  = w2a + 256 * 128;
    float* biasA = (float*)(w2b + 256 * 128);
    float* biasB = biasA + 256;
    short* h1Tp = (short*)(biasB + 256);   // PP*64 bf16 (padded)
    short* h2Tp = h1Tp + PP * 64;          // PP*64 bf16 (padded)
    short* wAc2 = h2Tp + PP * 64;          // 9*64*64 bf16
    short* wAc1 = wAc2 + 9 * 64 * 64;      // 64*128 bf16
    short* wAcf = wAc1 + 64 * 128;         // 9*16*64 bf16

    (void)hipMemsetAsync(h1a, 0, (size_t)NF * HW * 4, stream);
    (void)hipMemsetAsync(h2a, 0, (size_t)NF * HW * 4, stream);
    (void)hipMemsetAsync(gTp, 0, PP * 4 * 2, stream);      // zero borders
    (void)hipMemsetAsync(h1Tp, 0, PP * 64 * 2, stream);
    (void)hipMemsetAsync(h2Tp, 0, PP * 64 * 2, stream);

    dim3 B(256);
    const int gCHW = NC * HW / 256;   // 3072
    const int gHW  = HW / 256;        // 256
    const int gROW = NC * 256 / 4;    // 768
    dim3 gCOL(64, NC);
    const int gGRU = HW / 64;         // 1024 blocks
    const int gCNV = HW / 32;         // 2048 blocks (nt=2)

    // weight prep (once per call)
    k_prep_gru<<<256, 128, 0, stream>>>(g1iw, g1ib, g1hw, g1hb, w2a, biasA);
    k_prep_gru<<<256, 128, 0, stream>>>(g2iw, g2ib, g2hw, g2hb, w2b, biasB);
    k_prep_c2<<<144, 256, 0, stream>>>(c2w, wAc2);
    k_prep_c1<<<32, 256, 0, stream>>>(c1w, wAc1);
    k_prep_cf<<<36, 256, 0, stream>>>(fw, wAcf);

    // eta0 = sum_c ifft2c(pred_c) * conj(sense_c)
    fft_rows_pre<<<gROW, B, 0, stream>>>(tmp, pred);
    fft_cols<<<gCOL, B, 0, stream>>>(tmp, -1.0f);
    k_combine_eta0<<<gHW, B, 0, stream>>>(tmp, sense, eta);

    k_base<<<gCHW, B, 0, stream>>>(ksp, pred, mask, dcw, base);

    // F_0: forward FFT of S*(eta0*sense); fused epilogue -> residual (no out)
    fft_rows_exp<<<gROW, B, 0, stream>>>(Fk, eta, sense);
    fft_cols_fused<<<gCOL, B, 0, stream>>>(Fk, base, ksp, mask, (c32*)d_out, 0);

    float* h1c = h1a; float* h1n = h1b;
    float* h2c = h2a; float* h2n = h2b;
    c32* outp = (c32*)d_out;

    for (int t = 0; t < NT; ++t) {
        fft_rows<<<gROW, B, 0, stream>>>(Fk, -1.0f);
        k_grad_g<<<gHW, B, 0, stream>>>(Fk, sense, eta, gTp);

        conv1_mfma<<<gCNV, B, 0, stream>>>(gTp, wAc1, c1b, x1);
        gru_mfma<<<gGRU, B, 0, stream>>>(x1, h1c, w2a, biasA, h1n, h1Tp);
        { float* s = h1c; h1c = h1n; h1n = s; }
        conv2_mfma<<<gCNV, B, 0, stream>>>(h1Tp, wAc2, c2b, x1);
        gru_mfma<<<gGRU, B, 0, stream>>>(x1, h2c, w2b, biasB, h2n, h2Tp);
        { float* s = h2c; h2c = h2n; h2n = s; }
        final_mfma<<<gGRU, B, 0, stream>>>(h2Tp, wAcf, eta);

        fft_rows_exp<<<gROW, B, 0, stream>>>(Fk, eta, sense);
        fft_cols_fused<<<gCOL, B, 0, stream>>>(Fk, base, ksp, mask,
                                               outp + (size_t)t * NC * HW, 1);
    }
}

// Round 10
// 1120.264 us; speedup vs baseline: 1.2614x; 1.2614x over previous
//
#include <hip/hip_runtime.h>

#define HW 65536
#define NC 12
#define NF 64
#define NT 8
#define P2 260   // padded pitch (2-wide zero border each side)

typedef float2 c32;
typedef __attribute__((ext_vector_type(8))) short bf16x8;   // 8 bf16 = 4 VGPR
typedef __attribute__((ext_vector_type(4))) float f32x4;    // MFMA C/D

__device__ __forceinline__ float ssign(int p) {
    return ((p ^ (p >> 8)) & 1) ? -1.0f : 1.0f;
}

__device__ __forceinline__ short f2bf(float f) {   // RNE float->bf16
    union { float f; unsigned u; } v; v.f = f;
    unsigned r = (v.u + 0x7FFFu + ((v.u >> 16) & 1u)) >> 16;
    return (short)r;
}

// ===================== 256-point radix-2 DIT FFT in LDS =====================
__device__ __forceinline__ void fft256_stages(c32* X, const c32* tw, int j, float conjf) {
    #pragma unroll
    for (int s = 1; s <= 8; ++s) {
        const int half = 1 << (s - 1);
        #pragma unroll
        for (int b = 0; b < 2; ++b) {
            int idx = j + (b << 6);
            int grp = idx >> (s - 1);
            int pos = idx & (half - 1);
            int i0 = (grp << s) + pos;
            int i1 = i0 + half;
            c32 w = tw[pos << (8 - s)];
            float wy = conjf * w.y;
            c32 a = X[i0], cc = X[i1];
            c32 t = make_float2(w.x * cc.x - wy * cc.y, w.x * cc.y + wy * cc.x);
            X[i0] = make_float2(a.x + t.x, a.y + t.y);
            X[i1] = make_float2(a.x - t.x, a.y - t.y);
        }
        __syncthreads();
    }
}

__device__ __forceinline__ void build_tw(c32* tw, int tid) {
    if (tid < 128) {
        float a = -3.14159265358979323846f * (float)tid * (1.0f / 128.0f);
        float sv, cv;
        sincosf(a, &sv, &cv);
        tw[tid] = make_float2(cv, sv);
    }
}

__global__ __launch_bounds__(256) void fft_rows(c32* __restrict__ buf, float conjf) {
    __shared__ c32 lds[4][256];
    __shared__ c32 tw[128];
    int tid = threadIdx.x;
    build_tw(tw, tid);
    int wid = tid >> 6, j = tid & 63;
    c32* rp = buf + (size_t)(blockIdx.x * 4 + wid) * 256;
    c32* X = lds[wid];
    #pragma unroll
    for (int e = 0; e < 4; ++e) {
        int n = (e << 6) + j;
        X[__brev((unsigned)n) >> 24] = rp[n];
    }
    __syncthreads();
    fft256_stages(X, tw, j, conjf);
    #pragma unroll
    for (int e = 0; e < 4; ++e) {
        int n = (e << 6) + j;
        rp[n] = X[n];
    }
}

__global__ __launch_bounds__(256) void fft_rows_pre(c32* __restrict__ buf,
        const c32* __restrict__ pred) {
    __shared__ c32 lds[4][256];
    __shared__ c32 tw[128];
    int tid = threadIdx.x;
    build_tw(tw, tid);
    int wid = tid >> 6, j = tid & 63;
    int r = blockIdx.x * 4 + wid;
    int coil = r >> 8, y = r & 255;
    c32* rp = buf + (size_t)r * 256;
    c32* X = lds[wid];
    #pragma unroll
    for (int e = 0; e < 4; ++e) {
        int n = (e << 6) + j;
        float s = ((n + y) & 1) ? -1.0f : 1.0f;
        c32 pv = pred[(size_t)coil * HW + y * 256 + n];
        X[__brev((unsigned)n) >> 24] = make_float2(s * pv.x, s * pv.y);
    }
    __syncthreads();
    fft256_stages(X, tw, j, -1.0f);
    #pragma unroll
    for (int e = 0; e < 4; ++e) {
        int n = (e << 6) + j;
        rp[n] = X[n];
    }
}

__global__ __launch_bounds__(256) void fft_rows_exp(c32* __restrict__ buf,
        const c32* __restrict__ eta, const c32* __restrict__ sense) {
    __shared__ c32 lds[4][256];
    __shared__ c32 tw[128];
    int tid = threadIdx.x;
    build_tw(tw, tid);
    int wid = tid >> 6, j = tid & 63;
    int r = blockIdx.x * 4 + wid;
    int coil = r >> 8, y = r & 255;
    c32* rp = buf + (size_t)r * 256;
    c32* X = lds[wid];
    #pragma unroll
    for (int e = 0; e < 4; ++e) {
        int n = (e << 6) + j;
        float s = ((n + y) & 1) ? -1.0f : 1.0f;
        c32 ev = eta[y * 256 + n];
        c32 sn = sense[(size_t)coil * HW + y * 256 + n];
        X[__brev((unsigned)n) >> 24] =
            make_float2(s * (ev.x * sn.x - ev.y * sn.y),
                        s * (ev.x * sn.y + ev.y * sn.x));
    }
    __syncthreads();
    fft256_stages(X, tw, j, 1.0f);
    #pragma unroll
    for (int e = 0; e < 4; ++e) {
        int n = (e << 6) + j;
        rp[n] = X[n];
    }
}

__global__ __launch_bounds__(256) void fft_cols(c32* __restrict__ buf, float conjf) {
    __shared__ c32 lds[4][257];
    __shared__ c32 tw[128];
    int tid = threadIdx.x;
    build_tw(tw, tid);
    c32* ip = buf + (size_t)blockIdx.y * HW;
    int x0 = blockIdx.x * 4;
    int cl = tid & 3, yb = tid >> 2;
    #pragma unroll
    for (int e = 0; e < 4; ++e) {
        int y = yb + (e << 6);
        lds[cl][__brev((unsigned)y) >> 24] = ip[y * 256 + x0 + cl];
    }
    __syncthreads();
    int col = tid >> 6, j = tid & 63;
    fft256_stages(&lds[col][0], tw, j, conjf);
    #pragma unroll
    for (int e = 0; e < 4; ++e) {
        int y = yb + (e << 6);
        ip[y * 256 + x0 + cl] = lds[cl][y];
    }
}

// Fused: fwd col FFT -> (out write + masked residual) -> inv col FFT, one LDS tile.
__global__ __launch_bounds__(256) void fft_cols_fused(c32* __restrict__ buf,
        const c32* __restrict__ base, const c32* __restrict__ ksp,
        const int* __restrict__ mask, c32* __restrict__ outp, int write_out) {
    __shared__ c32 lds[4][257];
    __shared__ c32 tw[128];
    int tid = threadIdx.x;
    build_tw(tw, tid);
    int coil = blockIdx.y;
    c32* ip = buf + (size_t)coil * HW;
    int x0 = blockIdx.x * 4;
    int cl = tid & 3, yb = tid >> 2;
    #pragma unroll
    for (int e = 0; e < 4; ++e) {
        int y = yb + (e << 6);
        lds[cl][__brev((unsigned)y) >> 24] = ip[y * 256 + x0 + cl];
    }
    __syncthreads();
    int col = tid >> 6, j = tid & 63;
    fft256_stages(&lds[col][0], tw, j, 1.0f);

    int x = x0 + cl;
    c32 G[4];
    #pragma unroll
    for (int e = 0; e < 4; ++e) {
        int y = yb + (e << 6);
        G[e] = lds[cl][y];
    }
    __syncthreads();
    #pragma unroll
    for (int e = 0; e < 4; ++e) {
        int y = yb + (e << 6);
        int p = y * 256 + x;
        size_t i = (size_t)coil * HW + p;
        float s = ((p ^ (p >> 8)) & 1) ? -1.0f : 1.0f;
        if (write_out) {
            c32 bv = base[i];
            float sc = s * (1.0f / 256.0f);
            outp[i] = make_float2(bv.x - sc * G[e].x, bv.y - sc * G[e].y);
        }
        c32 rv = make_float2(0.f, 0.f);
        if (mask[p]) {
            c32 k = ksp[i];
            rv = make_float2(G[e].x * (1.0f / 256.0f) - s * k.x,
                             G[e].y * (1.0f / 256.0f) - s * k.y);
        }
        lds[cl][__brev((unsigned)y) >> 24] = rv;
    }
    __syncthreads();
    fft256_stages(&lds[col][0], tw, j, -1.0f);
    #pragma unroll
    for (int e = 0; e < 4; ++e) {
        int y = yb + (e << 6);
        ip[y * 256 + x0 + cl] = lds[cl][y];
    }
}

// ===================== pointwise kernels =====================
__global__ __launch_bounds__(256) void k_combine_eta0(const c32* __restrict__ tmp,
        const c32* __restrict__ sense, c32* __restrict__ eta) {
    int p = blockIdx.x * 256 + threadIdx.x;
    float ax = 0.f, ay = 0.f;
    for (int c = 0; c < NC; ++c) {
        c32 t = tmp[c * HW + p], s = sense[c * HW + p];
        ax += t.x * s.x + t.y * s.y;
        ay += t.y * s.x - t.x * s.y;
    }
    float sc = ssign(p) * (1.0f / 256.0f);
    eta[p] = make_float2(ax * sc, ay * sc);
}

__global__ __launch_bounds__(256) void k_base(const c32* __restrict__ ksp,
        const c32* __restrict__ pred, const int* __restrict__ mask,
        const float* __restrict__ dcw, c32* __restrict__ base) {
    int i = blockIdx.x * 256 + threadIdx.x;
    int p = i & (HW - 1);
    c32 k = ksp[i];
    c32 o = k;
    if (mask[p]) {
        float w = dcw[0];
        c32 pr = pred[i];
        o.x -= (pr.x - k.x) * w;
        o.y -= (pr.y - k.y) * w;
    }
    base[i] = o;
}

// grad+g -> padded transposed bf16 gTp[(y+2)*P2 + x+2][4]
__global__ __launch_bounds__(256) void k_grad_g(const c32* __restrict__ tmp,
        const c32* __restrict__ sense, const c32* __restrict__ eta,
        short* __restrict__ gTp) {
    int p = blockIdx.x * 256 + threadIdx.x;
    float ax = 0.f, ay = 0.f;
    for (int c = 0; c < NC; ++c) {
        c32 t = tmp[c * HW + p], s = sense[c * HW + p];
        ax += t.x * s.x + t.y * s.y;
        ay += t.y * s.x - t.x * s.y;
    }
    float sc = ssign(p) * (1.0f / 256.0f);
    c32 e = eta[p];
    ushort4 o;
    o.x = (unsigned short)f2bf(e.x);
    o.y = (unsigned short)f2bf(e.y);
    o.z = (unsigned short)f2bf(ax * sc);
    o.w = (unsigned short)f2bf(ay * sc);
    int y = p >> 8, x = p & 255;
    ((ushort4*)gTp)[(y + 2) * P2 + x + 2] = o;
}

// ===================== weight prep kernels =====================
__global__ __launch_bounds__(256) void k_prep_c1(const float* __restrict__ w,
        short* __restrict__ wA) {
    int i = blockIdx.x * 256 + threadIdx.x;    // 64*128
    int co = i >> 7, k = i & 127;
    int tap = k >> 2, ci = k & 3;
    float v = (tap < 25) ? w[co * 100 + ci * 25 + tap] : 0.f;
    wA[i] = f2bf(v);
}

__global__ __launch_bounds__(256) void k_prep_c2(const float* __restrict__ w,
        short* __restrict__ wA) {
    int i = blockIdx.x * 256 + threadIdx.x;     // 36864
    int tap = i >> 12, co = (i >> 6) & 63, ci = i & 63;
    wA[i] = f2bf(w[co * 576 + ci * 9 + tap]);
}

__global__ __launch_bounds__(256) void k_prep_cf(const float* __restrict__ w,
        short* __restrict__ wA) {
    int i = blockIdx.x * 256 + threadIdx.x;    // 9216
    int tap = i >> 10, r = (i >> 6) & 15, ci = i & 63;
    float v = (r < 2) ? w[r * 576 + ci * 9 + tap] : 0.f;
    wA[i] = f2bf(v);
}

__global__ __launch_bounds__(128) void k_prep_gru(const float* __restrict__ ihw,
        const float* __restrict__ ihb, const float* __restrict__ hhw,
        const float* __restrict__ hhb, short* __restrict__ w2, float* __restrict__ bias) {
    int k = threadIdx.x;
    int r = blockIdx.x;
    int g = r >> 6, co = r & 63;
    float v = 0.f;
    if (g == 0)      v = (k < 64) ? ihw[co * 64 + k]         : hhw[co * 64 + k - 64];
    else if (g == 1) v = (k < 64) ? ihw[(64 + co) * 64 + k]  : hhw[(64 + co) * 64 + k - 64];
    else if (g == 2) v = (k < 64) ? ihw[(128 + co) * 64 + k] : 0.f;
    else             v = (k < 64) ? 0.f : hhw[(128 + co) * 64 + k - 64];
    w2[r * 128 + k] = f2bf(v);
    if (k == 0) {
        float b = (g == 0) ? ihb[co] + hhb[co]
                : (g == 1) ? ihb[64 + co] + hhb[64 + co]
                : (g == 2) ? ihb[128 + co] : hhb[128 + co];
        bias[r] = b;
    }
}

// ===================== conv1 via MFMA (padded, branchless, hoisted B) ======
// grid 2048 (y*8 xseg), 256 thr. nt=2 (32 px/wave).
__global__ __launch_bounds__(256, 2) void conv1_mfma(const short* __restrict__ gTp,
        const short* __restrict__ wA, const float* __restrict__ bias,
        float* __restrict__ out) {
    int wv = threadIdx.x >> 6, l = threadIdx.x & 63;
    int lr = l & 15, lg = l >> 4;
    int y = blockIdx.x >> 3;
    int x0 = (blockIdx.x & 7) << 5;

    bf16x8 A[4];
    const short* pA = wA + (size_t)(wv * 16 + lr) * 128 + lg * 8;
    #pragma unroll
    for (int kt = 0; kt < 4; ++kt) A[kt] = *(const bf16x8*)(pA + kt * 32);

    bf16x8 B[2][4];
    #pragma unroll
    for (int nt = 0; nt < 2; ++nt) {
        int x = x0 + nt * 16 + lr;
        #pragma unroll
        for (int kt = 0; kt < 4; ++kt) {
            int t0 = kt * 8 + lg * 2;
            #pragma unroll
            for (int half = 0; half < 2; ++half) {
                int tap = t0 + half;
                int tt = (tap < 25) ? tap : 0;   // pad taps: A rows are zero
                int dy = tt / 5 - 2, dx = tt % 5 - 2;
                ushort4 v = *(const ushort4*)(gTp +
                    ((size_t)((y + dy + 2) * P2 + (x + dx + 2)) << 2));
                B[nt][kt][half * 4 + 0] = (short)v.x;
                B[nt][kt][half * 4 + 1] = (short)v.y;
                B[nt][kt][half * 4 + 2] = (short)v.z;
                B[nt][kt][half * 4 + 3] = (short)v.w;
            }
        }
    }
    f32x4 C[2];
    #pragma unroll
    for (int nt = 0; nt < 2; ++nt) {
        C[nt] = (f32x4){0.f, 0.f, 0.f, 0.f};
        #pragma unroll
        for (int kt = 0; kt < 4; ++kt)
            C[nt] = __builtin_amdgcn_mfma_f32_16x16x32_bf16(A[kt], B[nt][kt], C[nt], 0, 0, 0);
    }
    int co = wv * 16 + lg * 4;
    #pragma unroll
    for (int nt = 0; nt < 2; ++nt) {
        int px = y * 256 + x0 + nt * 16 + lr;
        #pragma unroll
        for (int i = 0; i < 4; ++i)
            out[(size_t)(co + i) * HW + px] = fmaxf(C[nt][i] + bias[co + i], 0.f);
    }
}

// ===================== conv2 via MFMA + LDS staging =====================
// grid 1024 (256 y x 4 xseg), 256 thr (4 waves), nt=4 (64 px strip).
// Block stages rows {y-2,y,y+2} x 68 px x 64ci from padded hTp into LDS
// (entry pitch 9x16B per px -> 2-way bank conflicts = free), then all B
// fragments come from ds_read_b128.
__global__ __launch_bounds__(256, 2) void conv2_mfma(const short* __restrict__ hTp,
        const short* __restrict__ wA, const float* __restrict__ bias,
        float* __restrict__ out) {
    __shared__ uint4 Ld[3][68][9];       // 29376 B, entries 0..7 used
    int tid = threadIdx.x;
    int wv = tid >> 6, l = tid & 63;
    int lr = l & 15, lg = l >> 4;
    int y = blockIdx.x >> 2;
    int x0 = (blockIdx.x & 3) << 6;

    // cooperative stage: 3*68*8 = 1632 entries of 16B, coalesced
    for (int n = tid; n < 3 * 68 * 8; n += 256) {
        int r = n / (68 * 8);
        int rem = n - r * (68 * 8);
        int px = rem >> 3, e = rem & 7;
        const uint4* src = (const uint4*)(hTp +
            (((size_t)(y + 2 * r) * P2 + (x0 + px)) << 6)) + e;
        Ld[r][px][e] = *src;
    }
    __syncthreads();

    f32x4 C[4];
    #pragma unroll
    for (int nt = 0; nt < 4; ++nt) C[nt] = (f32x4){0.f, 0.f, 0.f, 0.f};

    #pragma unroll
    for (int tap = 0; tap < 9; ++tap) {
        int r = tap / 3;
        int dx = (tap % 3 - 1) * 2;
        const short* pA = wA + (size_t)(tap * 64 + wv * 16 + lr) * 64 + lg * 8;
        bf16x8 A0 = *(const bf16x8*)(pA);
        bf16x8 A1 = *(const bf16x8*)(pA + 32);
        #pragma unroll
        for (int nt = 0; nt < 4; ++nt) {
            int xl = nt * 16 + lr + dx + 2;
            bf16x8 B0 = *(const bf16x8*)&Ld[r][xl][lg];
            bf16x8 B1 = *(const bf16x8*)&Ld[r][xl][4 + lg];
            C[nt] = __builtin_amdgcn_mfma_f32_16x16x32_bf16(A0, B0, C[nt], 0, 0, 0);
            C[nt] = __builtin_amdgcn_mfma_f32_16x16x32_bf16(A1, B1, C[nt], 0, 0, 0);
        }
    }
    int co = wv * 16 + lg * 4;
    #pragma unroll
    for (int nt = 0; nt < 4; ++nt) {
        int px = y * 256 + x0 + nt * 16 + lr;
        #pragma unroll
        for (int i = 0; i < 4; ++i)
            out[(size_t)(co + i) * HW + px] = fmaxf(C[nt][i] + bias[co + i], 0.f);
    }
}

// ===================== GRU via MFMA (padded hT emit) =====================
__global__ __launch_bounds__(256, 2) void gru_mfma(const float* __restrict__ xin,
        const float* __restrict__ h, const short* __restrict__ w2,
        const float* __restrict__ bias, float* __restrict__ hout,
        short* __restrict__ hTp) {
    int wv = threadIdx.x >> 6, l = threadIdx.x & 63;
    int lr = l & 15, lg = l >> 4;
    int px0 = blockIdx.x * 64;

    bf16x8 A0[4], A1[4], A2[2], A3[2];
    {
        const short* w0 = w2 + (0   + wv * 16 + lr) * 128 + lg * 8;
        const short* w1 = w2 + (64  + wv * 16 + lr) * 128 + lg * 8;
        const short* w2p = w2 + (128 + wv * 16 + lr) * 128 + lg * 8;
        const short* w3 = w2 + (192 + wv * 16 + lr) * 128 + lg * 8;
        #pragma unroll
        for (int kt = 0; kt < 4; ++kt) {
            A0[kt] = *(const bf16x8*)(w0 + kt * 32);
            A1[kt] = *(const bf16x8*)(w1 + kt * 32);
        }
        A2[0] = *(const bf16x8*)(w2p);          A2[1] = *(const bf16x8*)(w2p + 32);
        A3[0] = *(const bf16x8*)(w3 + 64);      A3[1] = *(const bf16x8*)(w3 + 96);
    }

    f32x4 C0[4], C1[4], C2[4], C3[4];
    #pragma unroll
    for (int nt = 0; nt < 4; ++nt) {
        C0[nt] = (f32x4){0.f, 0.f, 0.f, 0.f};
        C1[nt] = (f32x4){0.f, 0.f, 0.f, 0.f};
        C2[nt] = (f32x4){0.f, 0.f, 0.f, 0.f};
        C3[nt] = (f32x4){0.f, 0.f, 0.f, 0.f};
    }

    #pragma unroll
    for (int nt = 0; nt < 4; ++nt) {
        int px = px0 + nt * 16 + lr;
        bf16x8 B[4];
        #pragma unroll
        for (int kt = 0; kt < 4; ++kt) {
            const float* src = (kt < 2) ? xin + (size_t)(kt * 32 + lg * 8) * HW + px
                                        : h   + (size_t)((kt - 2) * 32 + lg * 8) * HW + px;
            #pragma unroll
            for (int j = 0; j < 8; ++j) B[kt][j] = f2bf(src[(size_t)j * HW]);
        }
        #pragma unroll
        for (int kt = 0; kt < 4; ++kt) {
            C0[nt] = __builtin_amdgcn_mfma_f32_16x16x32_bf16(A0[kt], B[kt], C0[nt], 0, 0, 0);
            C1[nt] = __builtin_amdgcn_mfma_f32_16x16x32_bf16(A1[kt], B[kt], C1[nt], 0, 0, 0);
        }
        C2[nt] = __builtin_amdgcn_mfma_f32_16x16x32_bf16(A2[0], B[0], C2[nt], 0, 0, 0);
        C2[nt] = __builtin_amdgcn_mfma_f32_16x16x32_bf16(A2[1], B[1], C2[nt], 0, 0, 0);
        C3[nt] = __builtin_amdgcn_mfma_f32_16x16x32_bf16(A3[0], B[2], C3[nt], 0, 0, 0);
        C3[nt] = __builtin_amdgcn_mfma_f32_16x16x32_bf16(A3[1], B[3], C3[nt], 0, 0, 0);
    }

    int co = wv * 16 + lg * 4;
    float br[4], bz[4], bin_[4], bhn[4];
    #pragma unroll
    for (int i = 0; i < 4; ++i) {
        br[i]   = bias[co + i];
        bz[i]   = bias[64 + co + i];
        bin_[i] = bias[128 + co + i];
        bhn[i]  = bias[192 + co + i];
    }
    #pragma unroll
    for (int nt = 0; nt < 4; ++nt) {
        int px = px0 + nt * 16 + lr;
        int y = px >> 8, x = px & 255;
        size_t tb = ((size_t)((y + 2) * P2 + (x + 2)) << 6);
        #pragma unroll
        for (int i = 0; i < 4; ++i) {
            float r = 1.0f / (1.0f + expf(-(C0[nt][i] + br[i])));
            float z = 1.0f / (1.0f + expf(-(C1[nt][i] + bz[i])));
            float nn = tanhf(C2[nt][i] + bin_[i] + r * (C3[nt][i] + bhn[i]));
            float ho = h[(size_t)(co + i) * HW + px];
            float hv = (1.0f - z) * nn + z * ho;
            hout[(size_t)(co + i) * HW + px] = hv;
            hTp[tb + co + i] = f2bf(hv);
        }
    }
}

// ===================== final conv via MFMA (padded, prefetch) ==============
__global__ __launch_bounds__(256, 2) void final_mfma(const short* __restrict__ hTp,
        const short* __restrict__ wA, c32* __restrict__ eta) {
    int wv = threadIdx.x >> 6, l = threadIdx.x & 63;
    int lr = l & 15, lg = l >> 4;
    int y = blockIdx.x >> 2;
    int x0 = (blockIdx.x & 3) << 6;
    int x = x0 + wv * 16 + lr;

    auto loadB = [&](int tap, bf16x8& b0, bf16x8& b1) {
        int dy = tap / 3 - 1, dx = tap % 3 - 1;
        const short* pB = hTp +
            ((size_t)((y + dy + 2) * P2 + (x + dx + 2)) << 6) + lg * 8;
        b0 = *(const bf16x8*)(pB);
        b1 = *(const bf16x8*)(pB + 32);
    };

    f32x4 C = (f32x4){0.f, 0.f, 0.f, 0.f};
    bf16x8 cB0, cB1;
    loadB(0, cB0, cB1);
    #pragma unroll
    for (int tap = 0; tap < 9; ++tap) {
        const short* pA = wA + (size_t)(tap * 16 + lr) * 64 + lg * 8;
        bf16x8 A0 = *(const bf16x8*)(pA);
        bf16x8 A1 = *(const bf16x8*)(pA + 32);
        bf16x8 nB0, nB1;
        if (tap < 8) loadB(tap + 1, nB0, nB1);
        C = __builtin_amdgcn_mfma_f32_16x16x32_bf16(A0, cB0, C, 0, 0, 0);
        C = __builtin_amdgcn_mfma_f32_16x16x32_bf16(A1, cB1, C, 0, 0, 0);
        if (tap < 8) { cB0 = nB0; cB1 = nB1; }
    }
    if (lg == 0) {
        int px = y * 256 + x;
        c32 e = eta[px];
        eta[px] = make_float2(e.x + C[0], e.y + C[1]);
    }
}

// ===================== host orchestration =====================
extern "C" void kernel_launch(void* const* d_in, const int* in_sizes, int n_in,
                              void* d_out, int out_size, void* d_ws, size_t ws_size,
                              hipStream_t stream) {
    const c32* pred   = (const c32*)d_in[0];
    const c32* ksp    = (const c32*)d_in[1];
    const c32* sense  = (const c32*)d_in[2];
    const int* mask   = (const int*)d_in[3];
    const float* c1w  = (const float*)d_in[4];
    const float* c1b  = (const float*)d_in[5];
    const float* g1iw = (const float*)d_in[6];
    const float* g1ib = (const float*)d_in[7];
    const float* g1hw = (const float*)d_in[8];
    const float* g1hb = (const float*)d_in[9];
    const float* c2w  = (const float*)d_in[10];
    const float* c2b  = (const float*)d_in[11];
    const float* g2iw = (const float*)d_in[12];
    const float* g2ib = (const float*)d_in[13];
    const float* g2hw = (const float*)d_in[14];
    const float* g2hb = (const float*)d_in[15];
    const float* fw   = (const float*)d_in[16];
    const float* dcw  = (const float*)d_in[17];

    const size_t PP = (size_t)P2 * P2;     // 67600 padded pixels
    float* w0 = (float*)d_ws;
    c32* base = (c32*)w0;                  // NC*HW complex
    c32* Fk   = base + NC * HW;            // NC*HW complex
    c32* tmp  = Fk + NC * HW;              // NC*HW complex (init only)
    c32* eta  = tmp + NC * HW;             // HW complex
    short* gTp = (short*)(eta + HW);       // PP*4 bf16 (padded)
    float* x1 = (float*)(gTp + PP * 4);    // NF*HW
    float* h1a = x1 + NF * HW;
    float* h1b = h1a + NF * HW;
    float* h2a = h1b + NF * HW;
    float* h2b = h2a + NF * HW;
    short* w2a  = (short*)(h2b + NF * HW); // 256*128 bf16
    short* w2b  = w2a + 256 * 128;
    float* biasA = (float*)(w2b + 256 * 128);
    float* biasB = biasA + 256;
    short* h1Tp = (short*)(biasB + 256);   // PP*64 bf16 (padded)
    short* h2Tp = h1Tp + PP * 64;          // PP*64 bf16 (padded)
    short* wAc2 = h2Tp + PP * 64;          // 9*64*64 bf16
    short* wAc1 = wAc2 + 9 * 64 * 64;      // 64*128 bf16
    short* wAcf = wAc1 + 64 * 128;         // 9*16*64 bf16

    (void)hipMemsetAsync(h1a, 0, (size_t)NF * HW * 4, stream);
    (void)hipMemsetAsync(h2a, 0, (size_t)NF * HW * 4, stream);
    (void)hipMemsetAsync(gTp, 0, PP * 4 * 2, stream);      // zero borders
    (void)hipMemsetAsync(h1Tp, 0, PP * 64 * 2, stream);
    (void)hipMemsetAsync(h2Tp, 0, PP * 64 * 2, stream);

    dim3 B(256);
    const int gCHW = NC * HW / 256;   // 3072
    const int gHW  = HW / 256;        // 256
    const int gROW = NC * 256 / 4;    // 768
    dim3 gCOL(64, NC);
    const int gGRU = HW / 64;         // 1024 blocks
    const int gCNV = HW / 32;         // 2048 blocks (conv1, nt=2)

    // weight prep (once per call)
    k_prep_gru<<<256, 128, 0, stream>>>(g1iw, g1ib, g1hw, g1hb, w2a, biasA);
    k_prep_gru<<<256, 128, 0, stream>>>(g2iw, g2ib, g2hw, g2hb, w2b, biasB);
    k_prep_c2<<<144, 256, 0, stream>>>(c2w, wAc2);
    k_prep_c1<<<32, 256, 0, stream>>>(c1w, wAc1);
    k_prep_cf<<<36, 256, 0, stream>>>(fw, wAcf);

    // eta0 = sum_c ifft2c(pred_c) * conj(sense_c)
    fft_rows_pre<<<gROW, B, 0, stream>>>(tmp, pred);
    fft_cols<<<gCOL, B, 0, stream>>>(tmp, -1.0f);
    k_combine_eta0<<<gHW, B, 0, stream>>>(tmp, sense, eta);

    k_base<<<gCHW, B, 0, stream>>>(ksp, pred, mask, dcw, base);

    // F_0: forward FFT of S*(eta0*sense); fused epilogue -> residual (no out)
    fft_rows_exp<<<gROW, B, 0, stream>>>(Fk, eta, sense);
    fft_cols_fused<<<gCOL, B, 0, stream>>>(Fk, base, ksp, mask, (c32*)d_out, 0);

    float* h1c = h1a; float* h1n = h1b;
    float* h2c = h2a; float* h2n = h2b;
    c32* outp = (c32*)d_out;

    for (int t = 0; t < NT; ++t) {
        fft_rows<<<gROW, B, 0, stream>>>(Fk, -1.0f);
        k_grad_g<<<gHW, B, 0, stream>>>(Fk, sense, eta, gTp);

        conv1_mfma<<<gCNV, B, 0, stream>>>(gTp, wAc1, c1b, x1);
        gru_mfma<<<gGRU, B, 0, stream>>>(x1, h1c, w2a, biasA, h1n, h1Tp);
        { float* s = h1c; h1c = h1n; h1n = s; }
        conv2_mfma<<<gGRU, B, 0, stream>>>(h1Tp, wAc2, c2b, x1);
        gru_mfma<<<gGRU, B, 0, stream>>>(x1, h2c, w2b, biasB, h2n, h2Tp);
        { float* s = h2c; h2c = h2n; h2n = s; }
        final_mfma<<<gGRU, B, 0, stream>>>(h2Tp, wAcf, eta);

        fft_rows_exp<<<gROW, B, 0, stream>>>(Fk, eta, sense);
        fft_cols_fused<<<gCOL, B, 0, stream>>>(Fk, base, ksp, mask,
                                               outp + (size_t)t * NC * HW, 1);
    }
}

// Round 11
// 1082.127 us; speedup vs baseline: 1.3059x; 1.0352x over previous
//
#include <hip/hip_runtime.h>

#define HW 65536
#define NC 12
#define NF 64
#define NT 8
#define P2 260   // padded pitch (2-wide zero border each side)

typedef float2 c32;
typedef __attribute__((ext_vector_type(8))) short bf16x8;   // 8 bf16 = 4 VGPR
typedef __attribute__((ext_vector_type(4))) float f32x4;    // MFMA C/D

__device__ __forceinline__ float ssign(int p) {
    return ((p ^ (p >> 8)) & 1) ? -1.0f : 1.0f;
}

__device__ __forceinline__ short f2bf(float f) {   // RNE float->bf16
    union { float f; unsigned u; } v; v.f = f;
    unsigned r = (v.u + 0x7FFFu + ((v.u >> 16) & 1u)) >> 16;
    return (short)r;
}

// ===================== 256-point radix-2 DIT FFT in LDS =====================
__device__ __forceinline__ void fft256_stages(c32* X, const c32* tw, int j, float conjf) {
    #pragma unroll
    for (int s = 1; s <= 8; ++s) {
        const int half = 1 << (s - 1);
        #pragma unroll
        for (int b = 0; b < 2; ++b) {
            int idx = j + (b << 6);
            int grp = idx >> (s - 1);
            int pos = idx & (half - 1);
            int i0 = (grp << s) + pos;
            int i1 = i0 + half;
            c32 w = tw[pos << (8 - s)];
            float wy = conjf * w.y;
            c32 a = X[i0], cc = X[i1];
            c32 t = make_float2(w.x * cc.x - wy * cc.y, w.x * cc.y + wy * cc.x);
            X[i0] = make_float2(a.x + t.x, a.y + t.y);
            X[i1] = make_float2(a.x - t.x, a.y - t.y);
        }
        __syncthreads();
    }
}

__device__ __forceinline__ void build_tw(c32* tw, int tid) {
    if (tid < 128) {
        float a = -3.14159265358979323846f * (float)tid * (1.0f / 128.0f);
        float sv, cv;
        sincosf(a, &sv, &cv);
        tw[tid] = make_float2(cv, sv);
    }
}

__global__ __launch_bounds__(256) void fft_rows(c32* __restrict__ buf, float conjf) {
    __shared__ c32 lds[4][256];
    __shared__ c32 tw[128];
    int tid = threadIdx.x;
    build_tw(tw, tid);
    int wid = tid >> 6, j = tid & 63;
    c32* rp = buf + (size_t)(blockIdx.x * 4 + wid) * 256;
    c32* X = lds[wid];
    #pragma unroll
    for (int e = 0; e < 4; ++e) {
        int n = (e << 6) + j;
        X[__brev((unsigned)n) >> 24] = rp[n];
    }
    __syncthreads();
    fft256_stages(X, tw, j, conjf);
    #pragma unroll
    for (int e = 0; e < 4; ++e) {
        int n = (e << 6) + j;
        rp[n] = X[n];
    }
}

__global__ __launch_bounds__(256) void fft_rows_pre(c32* __restrict__ buf,
        const c32* __restrict__ pred) {
    __shared__ c32 lds[4][256];
    __shared__ c32 tw[128];
    int tid = threadIdx.x;
    build_tw(tw, tid);
    int wid = tid >> 6, j = tid & 63;
    int r = blockIdx.x * 4 + wid;
    int coil = r >> 8, y = r & 255;
    c32* rp = buf + (size_t)r * 256;
    c32* X = lds[wid];
    #pragma unroll
    for (int e = 0; e < 4; ++e) {
        int n = (e << 6) + j;
        float s = ((n + y) & 1) ? -1.0f : 1.0f;
        c32 pv = pred[(size_t)coil * HW + y * 256 + n];
        X[__brev((unsigned)n) >> 24] = make_float2(s * pv.x, s * pv.y);
    }
    __syncthreads();
    fft256_stages(X, tw, j, -1.0f);
    #pragma unroll
    for (int e = 0; e < 4; ++e) {
        int n = (e << 6) + j;
        rp[n] = X[n];
    }
}

__global__ __launch_bounds__(256) void fft_rows_exp(c32* __restrict__ buf,
        const c32* __restrict__ eta, const c32* __restrict__ sense) {
    __shared__ c32 lds[4][256];
    __shared__ c32 tw[128];
    int tid = threadIdx.x;
    build_tw(tw, tid);
    int wid = tid >> 6, j = tid & 63;
    int r = blockIdx.x * 4 + wid;
    int coil = r >> 8, y = r & 255;
    c32* rp = buf + (size_t)r * 256;
    c32* X = lds[wid];
    #pragma unroll
    for (int e = 0; e < 4; ++e) {
        int n = (e << 6) + j;
        float s = ((n + y) & 1) ? -1.0f : 1.0f;
        c32 ev = eta[y * 256 + n];
        c32 sn = sense[(size_t)coil * HW + y * 256 + n];
        X[__brev((unsigned)n) >> 24] =
            make_float2(s * (ev.x * sn.x - ev.y * sn.y),
                        s * (ev.x * sn.y + ev.y * sn.x));
    }
    __syncthreads();
    fft256_stages(X, tw, j, 1.0f);
    #pragma unroll
    for (int e = 0; e < 4; ++e) {
        int n = (e << 6) + j;
        rp[n] = X[n];
    }
}

__global__ __launch_bounds__(256) void fft_cols(c32* __restrict__ buf, float conjf) {
    __shared__ c32 lds[4][257];
    __shared__ c32 tw[128];
    int tid = threadIdx.x;
    build_tw(tw, tid);
    c32* ip = buf + (size_t)blockIdx.y * HW;
    int x0 = blockIdx.x * 4;
    int cl = tid & 3, yb = tid >> 2;
    #pragma unroll
    for (int e = 0; e < 4; ++e) {
        int y = yb + (e << 6);
        lds[cl][__brev((unsigned)y) >> 24] = ip[y * 256 + x0 + cl];
    }
    __syncthreads();
    int col = tid >> 6, j = tid & 63;
    fft256_stages(&lds[col][0], tw, j, conjf);
    #pragma unroll
    for (int e = 0; e < 4; ++e) {
        int y = yb + (e << 6);
        ip[y * 256 + x0 + cl] = lds[cl][y];
    }
}

// Fused: fwd col FFT -> (out write + masked residual) -> inv col FFT, one LDS tile.
__global__ __launch_bounds__(256) void fft_cols_fused(c32* __restrict__ buf,
        const c32* __restrict__ base, const c32* __restrict__ ksp,
        const int* __restrict__ mask, c32* __restrict__ outp, int write_out) {
    __shared__ c32 lds[4][257];
    __shared__ c32 tw[128];
    int tid = threadIdx.x;
    build_tw(tw, tid);
    int coil = blockIdx.y;
    c32* ip = buf + (size_t)coil * HW;
    int x0 = blockIdx.x * 4;
    int cl = tid & 3, yb = tid >> 2;
    #pragma unroll
    for (int e = 0; e < 4; ++e) {
        int y = yb + (e << 6);
        lds[cl][__brev((unsigned)y) >> 24] = ip[y * 256 + x0 + cl];
    }
    __syncthreads();
    int col = tid >> 6, j = tid & 63;
    fft256_stages(&lds[col][0], tw, j, 1.0f);

    int x = x0 + cl;
    c32 G[4];
    #pragma unroll
    for (int e = 0; e < 4; ++e) {
        int y = yb + (e << 6);
        G[e] = lds[cl][y];
    }
    __syncthreads();
    #pragma unroll
    for (int e = 0; e < 4; ++e) {
        int y = yb + (e << 6);
        int p = y * 256 + x;
        size_t i = (size_t)coil * HW + p;
        float s = ((p ^ (p >> 8)) & 1) ? -1.0f : 1.0f;
        if (write_out) {
            c32 bv = base[i];
            float sc = s * (1.0f / 256.0f);
            outp[i] = make_float2(bv.x - sc * G[e].x, bv.y - sc * G[e].y);
        }
        c32 rv = make_float2(0.f, 0.f);
        if (mask[p]) {
            c32 k = ksp[i];
            rv = make_float2(G[e].x * (1.0f / 256.0f) - s * k.x,
                             G[e].y * (1.0f / 256.0f) - s * k.y);
        }
        lds[cl][__brev((unsigned)y) >> 24] = rv;
    }
    __syncthreads();
    fft256_stages(&lds[col][0], tw, j, -1.0f);
    #pragma unroll
    for (int e = 0; e < 4; ++e) {
        int y = yb + (e << 6);
        ip[y * 256 + x0 + cl] = lds[cl][y];
    }
}

// ===================== pointwise kernels =====================
__global__ __launch_bounds__(256) void k_combine_eta0(const c32* __restrict__ tmp,
        const c32* __restrict__ sense, c32* __restrict__ eta) {
    int p = blockIdx.x * 256 + threadIdx.x;
    float ax = 0.f, ay = 0.f;
    for (int c = 0; c < NC; ++c) {
        c32 t = tmp[c * HW + p], s = sense[c * HW + p];
        ax += t.x * s.x + t.y * s.y;
        ay += t.y * s.x - t.x * s.y;
    }
    float sc = ssign(p) * (1.0f / 256.0f);
    eta[p] = make_float2(ax * sc, ay * sc);
}

__global__ __launch_bounds__(256) void k_base(const c32* __restrict__ ksp,
        const c32* __restrict__ pred, const int* __restrict__ mask,
        const float* __restrict__ dcw, c32* __restrict__ base) {
    int i = blockIdx.x * 256 + threadIdx.x;
    int p = i & (HW - 1);
    c32 k = ksp[i];
    c32 o = k;
    if (mask[p]) {
        float w = dcw[0];
        c32 pr = pred[i];
        o.x -= (pr.x - k.x) * w;
        o.y -= (pr.y - k.y) * w;
    }
    base[i] = o;
}

// grad+g -> padded transposed bf16 gTp[(y+2)*P2 + x+2][4]
__global__ __launch_bounds__(256) void k_grad_g(const c32* __restrict__ tmp,
        const c32* __restrict__ sense, const c32* __restrict__ eta,
        short* __restrict__ gTp) {
    int p = blockIdx.x * 256 + threadIdx.x;
    float ax = 0.f, ay = 0.f;
    for (int c = 0; c < NC; ++c) {
        c32 t = tmp[c * HW + p], s = sense[c * HW + p];
        ax += t.x * s.x + t.y * s.y;
        ay += t.y * s.x - t.x * s.y;
    }
    float sc = ssign(p) * (1.0f / 256.0f);
    c32 e = eta[p];
    ushort4 o;
    o.x = (unsigned short)f2bf(e.x);
    o.y = (unsigned short)f2bf(e.y);
    o.z = (unsigned short)f2bf(ax * sc);
    o.w = (unsigned short)f2bf(ay * sc);
    int y = p >> 8, x = p & 255;
    ((ushort4*)gTp)[(y + 2) * P2 + x + 2] = o;
}

// Zero only the 2064 border pixels of the padded buffers (replaces 17.8 MB
// of hipMemsetAsync; interiors are fully rewritten by producers each step).
__global__ __launch_bounds__(256) void k_zero_border(short* __restrict__ gTp,
        short* __restrict__ h1Tp, short* __restrict__ h2Tp) {
    int i = blockIdx.x * 256 + threadIdx.x;
    if (i >= 2064) return;
    int y, x;
    if (i < 1040) {                        // rows 0,1,258,259 full width
        int r = i / 260;
        y = (r < 2) ? r : 256 + r;
        x = i % 260;
    } else {                               // cols 0,1,258,259 for y in [2,258)
        int j = i - 1040;
        y = 2 + (j >> 2);
        int cix = j & 3;
        x = (cix < 2) ? cix : 256 + cix;
    }
    size_t px = (size_t)y * P2 + x;
    ((ushort4*)gTp)[px] = make_ushort4(0, 0, 0, 0);
    uint4 z = make_uint4(0, 0, 0, 0);
    uint4* p1 = (uint4*)(h1Tp + (px << 6));
    uint4* p2 = (uint4*)(h2Tp + (px << 6));
    #pragma unroll
    for (int e = 0; e < 8; ++e) { p1[e] = z; p2[e] = z; }
}

// ===================== weight prep kernels =====================
__global__ __launch_bounds__(256) void k_prep_c1(const float* __restrict__ w,
        short* __restrict__ wA) {
    int i = blockIdx.x * 256 + threadIdx.x;    // 64*128
    int co = i >> 7, k = i & 127;
    int tap = k >> 2, ci = k & 3;
    float v = (tap < 25) ? w[co * 100 + ci * 25 + tap] : 0.f;
    wA[i] = f2bf(v);
}

__global__ __launch_bounds__(256) void k_prep_c2(const float* __restrict__ w,
        short* __restrict__ wA) {
    int i = blockIdx.x * 256 + threadIdx.x;     // 36864
    int tap = i >> 12, co = (i >> 6) & 63, ci = i & 63;
    wA[i] = f2bf(w[co * 576 + ci * 9 + tap]);
}

__global__ __launch_bounds__(256) void k_prep_cf(const float* __restrict__ w,
        short* __restrict__ wA) {
    int i = blockIdx.x * 256 + threadIdx.x;    // 9216
    int tap = i >> 10, r = (i >> 6) & 15, ci = i & 63;
    float v = (r < 2) ? w[r * 576 + ci * 9 + tap] : 0.f;
    wA[i] = f2bf(v);
}

__global__ __launch_bounds__(128) void k_prep_gru(const float* __restrict__ ihw,
        const float* __restrict__ ihb, const float* __restrict__ hhw,
        const float* __restrict__ hhb, short* __restrict__ w2, float* __restrict__ bias) {
    int k = threadIdx.x;
    int r = blockIdx.x;
    int g = r >> 6, co = r & 63;
    float v = 0.f;
    if (g == 0)      v = (k < 64) ? ihw[co * 64 + k]         : hhw[co * 64 + k - 64];
    else if (g == 1) v = (k < 64) ? ihw[(64 + co) * 64 + k]  : hhw[(64 + co) * 64 + k - 64];
    else if (g == 2) v = (k < 64) ? ihw[(128 + co) * 64 + k] : 0.f;
    else             v = (k < 64) ? 0.f : hhw[(128 + co) * 64 + k - 64];
    w2[r * 128 + k] = f2bf(v);
    if (k == 0) {
        float b = (g == 0) ? ihb[co] + hhb[co]
                : (g == 1) ? ihb[64 + co] + hhb[64 + co]
                : (g == 2) ? ihb[128 + co] : hhb[128 + co];
        bias[r] = b;
    }
}

// ===================== conv1 via MFMA (padded, branchless, hoisted B) ======
__global__ __launch_bounds__(256, 2) void conv1_mfma(const short* __restrict__ gTp,
        const short* __restrict__ wA, const float* __restrict__ bias,
        float* __restrict__ out) {
    int wv = threadIdx.x >> 6, l = threadIdx.x & 63;
    int lr = l & 15, lg = l >> 4;
    int y = blockIdx.x >> 3;
    int x0 = (blockIdx.x & 7) << 5;

    bf16x8 A[4];
    const short* pA = wA + (size_t)(wv * 16 + lr) * 128 + lg * 8;
    #pragma unroll
    for (int kt = 0; kt < 4; ++kt) A[kt] = *(const bf16x8*)(pA + kt * 32);

    bf16x8 B[2][4];
    #pragma unroll
    for (int nt = 0; nt < 2; ++nt) {
        int x = x0 + nt * 16 + lr;
        #pragma unroll
        for (int kt = 0; kt < 4; ++kt) {
            int t0 = kt * 8 + lg * 2;
            #pragma unroll
            for (int half = 0; half < 2; ++half) {
                int tap = t0 + half;
                int tt = (tap < 25) ? tap : 0;   // pad taps: A rows are zero
                int dy = tt / 5 - 2, dx = tt % 5 - 2;
                ushort4 v = *(const ushort4*)(gTp +
                    ((size_t)((y + dy + 2) * P2 + (x + dx + 2)) << 2));
                B[nt][kt][half * 4 + 0] = (short)v.x;
                B[nt][kt][half * 4 + 1] = (short)v.y;
                B[nt][kt][half * 4 + 2] = (short)v.z;
                B[nt][kt][half * 4 + 3] = (short)v.w;
            }
        }
    }
    f32x4 C[2];
    #pragma unroll
    for (int nt = 0; nt < 2; ++nt) {
        C[nt] = (f32x4){0.f, 0.f, 0.f, 0.f};
        #pragma unroll
        for (int kt = 0; kt < 4; ++kt)
            C[nt] = __builtin_amdgcn_mfma_f32_16x16x32_bf16(A[kt], B[nt][kt], C[nt], 0, 0, 0);
    }
    int co = wv * 16 + lg * 4;
    #pragma unroll
    for (int nt = 0; nt < 2; ++nt) {
        int px = y * 256 + x0 + nt * 16 + lr;
        #pragma unroll
        for (int i = 0; i < 4; ++i)
            out[(size_t)(co + i) * HW + px] = fmaxf(C[nt][i] + bias[co + i], 0.f);
    }
}

// ===================== conv2 via MFMA + LDS staging =====================
__global__ __launch_bounds__(256, 2) void conv2_mfma(const short* __restrict__ hTp,
        const short* __restrict__ wA, const float* __restrict__ bias,
        float* __restrict__ out) {
    __shared__ uint4 Ld[3][68][9];       // 29376 B, entries 0..7 used
    int tid = threadIdx.x;
    int wv = tid >> 6, l = tid & 63;
    int lr = l & 15, lg = l >> 4;
    int y = blockIdx.x >> 2;
    int x0 = (blockIdx.x & 3) << 6;

    for (int n = tid; n < 3 * 68 * 8; n += 256) {
        int r = n / (68 * 8);
        int rem = n - r * (68 * 8);
        int px = rem >> 3, e = rem & 7;
        const uint4* src = (const uint4*)(hTp +
            (((size_t)(y + 2 * r) * P2 + (x0 + px)) << 6)) + e;
        Ld[r][px][e] = *src;
    }
    __syncthreads();

    f32x4 C[4];
    #pragma unroll
    for (int nt = 0; nt < 4; ++nt) C[nt] = (f32x4){0.f, 0.f, 0.f, 0.f};

    #pragma unroll
    for (int tap = 0; tap < 9; ++tap) {
        int r = tap / 3;
        int dx = (tap % 3 - 1) * 2;
        const short* pA = wA + (size_t)(tap * 64 + wv * 16 + lr) * 64 + lg * 8;
        bf16x8 A0 = *(const bf16x8*)(pA);
        bf16x8 A1 = *(const bf16x8*)(pA + 32);
        #pragma unroll
        for (int nt = 0; nt < 4; ++nt) {
            int xl = nt * 16 + lr + dx + 2;
            bf16x8 B0 = *(const bf16x8*)&Ld[r][xl][lg];
            bf16x8 B1 = *(const bf16x8*)&Ld[r][xl][4 + lg];
            C[nt] = __builtin_amdgcn_mfma_f32_16x16x32_bf16(A0, B0, C[nt], 0, 0, 0);
            C[nt] = __builtin_amdgcn_mfma_f32_16x16x32_bf16(A1, B1, C[nt], 0, 0, 0);
        }
    }
    int co = wv * 16 + lg * 4;
    #pragma unroll
    for (int nt = 0; nt < 4; ++nt) {
        int px = y * 256 + x0 + nt * 16 + lr;
        #pragma unroll
        for (int i = 0; i < 4; ++i)
            out[(size_t)(co + i) * HW + px] = fmaxf(C[nt][i] + bias[co + i], 0.f);
    }
}

// ===================== GRU via MFMA (padded hT emit) =====================
// FIRST=true: h == 0 (t=0) -> skip all H reads; C3=0; hout=(1-z)*n.
template <bool FIRST>
__global__ __launch_bounds__(256, 2) void gru_mfma(const float* __restrict__ xin,
        const float* __restrict__ h, const short* __restrict__ w2,
        const float* __restrict__ bias, float* __restrict__ hout,
        short* __restrict__ hTp) {
    int wv = threadIdx.x >> 6, l = threadIdx.x & 63;
    int lr = l & 15, lg = l >> 4;
    int px0 = blockIdx.x * 64;

    bf16x8 A0[4], A1[4], A2[2], A3[2];
    {
        const short* w0 = w2 + (0   + wv * 16 + lr) * 128 + lg * 8;
        const short* w1 = w2 + (64  + wv * 16 + lr) * 128 + lg * 8;
        const short* w2p = w2 + (128 + wv * 16 + lr) * 128 + lg * 8;
        const short* w3 = w2 + (192 + wv * 16 + lr) * 128 + lg * 8;
        #pragma unroll
        for (int kt = 0; kt < 4; ++kt) {
            A0[kt] = *(const bf16x8*)(w0 + kt * 32);
            A1[kt] = *(const bf16x8*)(w1 + kt * 32);
        }
        A2[0] = *(const bf16x8*)(w2p);          A2[1] = *(const bf16x8*)(w2p + 32);
        A3[0] = *(const bf16x8*)(w3 + 64);      A3[1] = *(const bf16x8*)(w3 + 96);
    }

    f32x4 C0[4], C1[4], C2[4], C3[4];
    #pragma unroll
    for (int nt = 0; nt < 4; ++nt) {
        C0[nt] = (f32x4){0.f, 0.f, 0.f, 0.f};
        C1[nt] = (f32x4){0.f, 0.f, 0.f, 0.f};
        C2[nt] = (f32x4){0.f, 0.f, 0.f, 0.f};
        C3[nt] = (f32x4){0.f, 0.f, 0.f, 0.f};
    }

    #pragma unroll
    for (int nt = 0; nt < 4; ++nt) {
        int px = px0 + nt * 16 + lr;
        bf16x8 B[4];
        const int NKT = FIRST ? 2 : 4;
        #pragma unroll
        for (int kt = 0; kt < NKT; ++kt) {
            const float* src = (kt < 2) ? xin + (size_t)(kt * 32 + lg * 8) * HW + px
                                        : h   + (size_t)((kt - 2) * 32 + lg * 8) * HW + px;
            #pragma unroll
            for (int j = 0; j < 8; ++j) B[kt][j] = f2bf(src[(size_t)j * HW]);
        }
        #pragma unroll
        for (int kt = 0; kt < NKT; ++kt) {
            C0[nt] = __builtin_amdgcn_mfma_f32_16x16x32_bf16(A0[kt], B[kt], C0[nt], 0, 0, 0);
            C1[nt] = __builtin_amdgcn_mfma_f32_16x16x32_bf16(A1[kt], B[kt], C1[nt], 0, 0, 0);
        }
        C2[nt] = __builtin_amdgcn_mfma_f32_16x16x32_bf16(A2[0], B[0], C2[nt], 0, 0, 0);
        C2[nt] = __builtin_amdgcn_mfma_f32_16x16x32_bf16(A2[1], B[1], C2[nt], 0, 0, 0);
        if (!FIRST) {
            C3[nt] = __builtin_amdgcn_mfma_f32_16x16x32_bf16(A3[0], B[2], C3[nt], 0, 0, 0);
            C3[nt] = __builtin_amdgcn_mfma_f32_16x16x32_bf16(A3[1], B[3], C3[nt], 0, 0, 0);
        }
    }

    int co = wv * 16 + lg * 4;
    float br[4], bz[4], bin_[4], bhn[4];
    #pragma unroll
    for (int i = 0; i < 4; ++i) {
        br[i]   = bias[co + i];
        bz[i]   = bias[64 + co + i];
        bin_[i] = bias[128 + co + i];
        bhn[i]  = bias[192 + co + i];
    }
    #pragma unroll
    for (int nt = 0; nt < 4; ++nt) {
        int px = px0 + nt * 16 + lr;
        int y = px >> 8, x = px & 255;
        size_t tb = ((size_t)((y + 2) * P2 + (x + 2)) << 6);
        #pragma unroll
        for (int i = 0; i < 4; ++i) {
            float r = 1.0f / (1.0f + expf(-(C0[nt][i] + br[i])));
            float z = 1.0f / (1.0f + expf(-(C1[nt][i] + bz[i])));
            float nn = tanhf(C2[nt][i] + bin_[i] + r * (C3[nt][i] + bhn[i]));
            float hv;
            if (FIRST) {
                hv = (1.0f - z) * nn;
            } else {
                float ho = h[(size_t)(co + i) * HW + px];
                hv = (1.0f - z) * nn + z * ho;
            }
            hout[(size_t)(co + i) * HW + px] = hv;
            hTp[tb + co + i] = f2bf(hv);
        }
    }
}

// ===================== final conv via MFMA (padded, prefetch) ==============
__global__ __launch_bounds__(256, 2) void final_mfma(const short* __restrict__ hTp,
        const short* __restrict__ wA, c32* __restrict__ eta) {
    int wv = threadIdx.x >> 6, l = threadIdx.x & 63;
    int lr = l & 15, lg = l >> 4;
    int y = blockIdx.x >> 2;
    int x0 = (blockIdx.x & 3) << 6;
    int x = x0 + wv * 16 + lr;

    auto loadB = [&](int tap, bf16x8& b0, bf16x8& b1) {
        int dy = tap / 3 - 1, dx = tap % 3 - 1;
        const short* pB = hTp +
            ((size_t)((y + dy + 2) * P2 + (x + dx + 2)) << 6) + lg * 8;
        b0 = *(const bf16x8*)(pB);
        b1 = *(const bf16x8*)(pB + 32);
    };

    f32x4 C = (f32x4){0.f, 0.f, 0.f, 0.f};
    bf16x8 cB0, cB1;
    loadB(0, cB0, cB1);
    #pragma unroll
    for (int tap = 0; tap < 9; ++tap) {
        const short* pA = wA + (size_t)(tap * 16 + lr) * 64 + lg * 8;
        bf16x8 A0 = *(const bf16x8*)(pA);
        bf16x8 A1 = *(const bf16x8*)(pA + 32);
        bf16x8 nB0, nB1;
        if (tap < 8) loadB(tap + 1, nB0, nB1);
        C = __builtin_amdgcn_mfma_f32_16x16x32_bf16(A0, cB0, C, 0, 0, 0);
        C = __builtin_amdgcn_mfma_f32_16x16x32_bf16(A1, cB1, C, 0, 0, 0);
        if (tap < 8) { cB0 = nB0; cB1 = nB1; }
    }
    if (lg == 0) {
        int px = y * 256 + x;
        c32 e = eta[px];
        eta[px] = make_float2(e.x + C[0], e.y + C[1]);
    }
}

// ===================== host orchestration =====================
extern "C" void kernel_launch(void* const* d_in, const int* in_sizes, int n_in,
                              void* d_out, int out_size, void* d_ws, size_t ws_size,
                              hipStream_t stream) {
    const c32* pred   = (const c32*)d_in[0];
    const c32* ksp    = (const c32*)d_in[1];
    const c32* sense  = (const c32*)d_in[2];
    const int* mask   = (const int*)d_in[3];
    const float* c1w  = (const float*)d_in[4];
    const float* c1b  = (const float*)d_in[5];
    const float* g1iw = (const float*)d_in[6];
    const float* g1ib = (const float*)d_in[7];
    const float* g1hw = (const float*)d_in[8];
    const float* g1hb = (const float*)d_in[9];
    const float* c2w  = (const float*)d_in[10];
    const float* c2b  = (const float*)d_in[11];
    const float* g2iw = (const float*)d_in[12];
    const float* g2ib = (const float*)d_in[13];
    const float* g2hw = (const float*)d_in[14];
    const float* g2hb = (const float*)d_in[15];
    const float* fw   = (const float*)d_in[16];
    const float* dcw  = (const float*)d_in[17];

    const size_t PP = (size_t)P2 * P2;     // 67600 padded pixels
    float* w0 = (float*)d_ws;
    c32* base = (c32*)w0;                  // NC*HW complex
    c32* Fk   = base + NC * HW;            // NC*HW complex
    c32* tmp  = Fk + NC * HW;              // NC*HW complex (init only)
    c32* eta  = tmp + NC * HW;             // HW complex
    short* gTp = (short*)(eta + HW);       // PP*4 bf16 (padded)
    float* x1 = (float*)(gTp + PP * 4);    // NF*HW
    float* h1a = x1 + NF * HW;
    float* h1b = h1a + NF * HW;
    float* h2a = h1b + NF * HW;
    float* h2b = h2a + NF * HW;
    short* w2a  = (short*)(h2b + NF * HW); // 256*128 bf16
    short* w2b  = w2a + 256 * 128;
    float* biasA = (float*)(w2b + 256 * 128);
    float* biasB = biasA + 256;
    short* h1Tp = (short*)(biasB + 256);   // PP*64 bf16 (padded)
    short* h2Tp = h1Tp + PP * 64;          // PP*64 bf16 (padded)
    short* wAc2 = h2Tp + PP * 64;          // 9*64*64 bf16
    short* wAc1 = wAc2 + 9 * 64 * 64;      // 64*128 bf16
    short* wAcf = wAc1 + 64 * 128;         // 9*16*64 bf16

    dim3 B(256);
    const int gCHW = NC * HW / 256;   // 3072
    const int gHW  = HW / 256;        // 256
    const int gROW = NC * 256 / 4;    // 768
    dim3 gCOL(64, NC);
    const int gGRU = HW / 64;         // 1024 blocks
    const int gCNV = HW / 32;         // 2048 blocks (conv1, nt=2)

    // border zeroing (replaces all big memsets) + weight prep (once per call)
    k_zero_border<<<9, B, 0, stream>>>(gTp, h1Tp, h2Tp);
    k_prep_gru<<<256, 128, 0, stream>>>(g1iw, g1ib, g1hw, g1hb, w2a, biasA);
    k_prep_gru<<<256, 128, 0, stream>>>(g2iw, g2ib, g2hw, g2hb, w2b, biasB);
    k_prep_c2<<<144, 256, 0, stream>>>(c2w, wAc2);
    k_prep_c1<<<32, 256, 0, stream>>>(c1w, wAc1);
    k_prep_cf<<<36, 256, 0, stream>>>(fw, wAcf);

    // eta0 = sum_c ifft2c(pred_c) * conj(sense_c)
    fft_rows_pre<<<gROW, B, 0, stream>>>(tmp, pred);
    fft_cols<<<gCOL, B, 0, stream>>>(tmp, -1.0f);
    k_combine_eta0<<<gHW, B, 0, stream>>>(tmp, sense, eta);

    k_base<<<gCHW, B, 0, stream>>>(ksp, pred, mask, dcw, base);

    // F_0: forward FFT of S*(eta0*sense); fused epilogue -> residual (no out)
    fft_rows_exp<<<gROW, B, 0, stream>>>(Fk, eta, sense);
    fft_cols_fused<<<gCOL, B, 0, stream>>>(Fk, base, ksp, mask, (c32*)d_out, 0);

    float* h1c = h1a; float* h1n = h1b;
    float* h2c = h2a; float* h2n = h2b;
    c32* outp = (c32*)d_out;

    for (int t = 0; t < NT; ++t) {
        fft_rows<<<gROW, B, 0, stream>>>(Fk, -1.0f);
        k_grad_g<<<gHW, B, 0, stream>>>(Fk, sense, eta, gTp);

        conv1_mfma<<<gCNV, B, 0, stream>>>(gTp, wAc1, c1b, x1);
        if (t == 0) {
            gru_mfma<true><<<gGRU, B, 0, stream>>>(x1, h1c, w2a, biasA, h1n, h1Tp);
        } else {
            gru_mfma<false><<<gGRU, B, 0, stream>>>(x1, h1c, w2a, biasA, h1n, h1Tp);
        }
        { float* s = h1c; h1c = h1n; h1n = s; }
        conv2_mfma<<<gGRU, B, 0, stream>>>(h1Tp, wAc2, c2b, x1);
        if (t == 0) {
            gru_mfma<true><<<gGRU, B, 0, stream>>>(x1, h2c, w2b, biasB, h2n, h2Tp);
        } else {
            gru_mfma<false><<<gGRU, B, 0, stream>>>(x1, h2c, w2b, biasB, h2n, h2Tp);
        }
        { float* s = h2c; h2c = h2n; h2n = s; }
        final_mfma<<<gGRU, B, 0, stream>>>(h2Tp, wAcf, eta);

        fft_rows_exp<<<gROW, B, 0, stream>>>(Fk, eta, sense);
        fft_cols_fused<<<gCOL, B, 0, stream>>>(Fk, base, ksp, mask,
                                               outp + (size_t)t * NC * HW, 1);
    }
}

// Round 12
// 1062.174 us; speedup vs baseline: 1.3304x; 1.0188x over previous
//
#include <hip/hip_runtime.h>

#define HW 65536
#define NC 12
#define NF 64
#define NT 8
#define P2 260   // padded pitch (2-wide zero border each side)

typedef float2 c32;
typedef __attribute__((ext_vector_type(8))) short bf16x8;   // 8 bf16 = 4 VGPR
typedef __attribute__((ext_vector_type(4))) float f32x4;    // MFMA C/D

__device__ __forceinline__ float ssign(int p) {
    return ((p ^ (p >> 8)) & 1) ? -1.0f : 1.0f;
}

__device__ __forceinline__ short f2bf(float f) {   // RNE float->bf16
    union { float f; unsigned u; } v; v.f = f;
    unsigned r = (v.u + 0x7FFFu + ((v.u >> 16) & 1u)) >> 16;
    return (short)r;
}

// ===================== 256-point radix-2 DIT FFT, wave-synchronous ==========
// One wave owns one 256-pt line: per-stage __syncthreads becomes a
// wave-internal s_waitcnt (in-order DS unit + lgkmcnt drain; "memory"
// clobber stops compiler reordering). Butterfly pairs are disjoint within
// a stage, so no cross-lane hazard inside a stage.
__device__ __forceinline__ void wave_sync() {
    asm volatile("s_waitcnt lgkmcnt(0)" ::: "memory");
}

__device__ __forceinline__ void fft256_wave(c32* X, const c32* tw, int j, float conjf) {
    #pragma unroll
    for (int s = 1; s <= 8; ++s) {
        const int half = 1 << (s - 1);
        #pragma unroll
        for (int b = 0; b < 2; ++b) {
            int idx = j + (b << 6);
            int grp = idx >> (s - 1);
            int pos = idx & (half - 1);
            int i0 = (grp << s) + pos;
            int i1 = i0 + half;
            c32 w = tw[pos << (8 - s)];
            float wy = conjf * w.y;
            c32 a = X[i0], cc = X[i1];
            c32 t = make_float2(w.x * cc.x - wy * cc.y, w.x * cc.y + wy * cc.x);
            X[i0] = make_float2(a.x + t.x, a.y + t.y);
            X[i1] = make_float2(a.x - t.x, a.y - t.y);
        }
        wave_sync();
    }
}

__device__ __forceinline__ void build_tw(c32* tw, int tid) {
    if (tid < 128) {
        float a = -3.14159265358979323846f * (float)tid * (1.0f / 128.0f);
        float sv, cv;
        sincosf(a, &sv, &cv);
        tw[tid] = make_float2(cv, sv);
    }
}

// Row inverse FFT with fused load (X = S * pred). grid 768. 1 barrier.
__global__ __launch_bounds__(256) void fft_rows_pre(c32* __restrict__ buf,
        const c32* __restrict__ pred) {
    __shared__ c32 lds[4][256];
    __shared__ c32 tw[128];
    int tid = threadIdx.x;
    build_tw(tw, tid);
    int wid = tid >> 6, j = tid & 63;
    int r = blockIdx.x * 4 + wid;
    int coil = r >> 8, y = r & 255;
    c32* rp = buf + (size_t)r * 256;
    c32* X = lds[wid];
    #pragma unroll
    for (int e = 0; e < 4; ++e) {
        int n = (e << 6) + j;
        float s = ((n + y) & 1) ? -1.0f : 1.0f;
        c32 pv = pred[(size_t)coil * HW + y * 256 + n];
        X[__brev((unsigned)n) >> 24] = make_float2(s * pv.x, s * pv.y);
    }
    __syncthreads();                 // tw visibility (loads are wave-local)
    fft256_wave(X, tw, j, -1.0f);
    #pragma unroll
    for (int e = 0; e < 4; ++e) {
        int n = (e << 6) + j;
        rp[n] = X[n];
    }
}

// Row forward FFT with fused load (X = S * eta * sense). grid 768. 1 barrier.
__global__ __launch_bounds__(256) void fft_rows_exp(c32* __restrict__ buf,
        const c32* __restrict__ eta, const c32* __restrict__ sense) {
    __shared__ c32 lds[4][256];
    __shared__ c32 tw[128];
    int tid = threadIdx.x;
    build_tw(tw, tid);
    int wid = tid >> 6, j = tid & 63;
    int r = blockIdx.x * 4 + wid;
    int coil = r >> 8, y = r & 255;
    c32* rp = buf + (size_t)r * 256;
    c32* X = lds[wid];
    #pragma unroll
    for (int e = 0; e < 4; ++e) {
        int n = (e << 6) + j;
        float s = ((n + y) & 1) ? -1.0f : 1.0f;
        c32 ev = eta[y * 256 + n];
        c32 sn = sense[(size_t)coil * HW + y * 256 + n];
        X[__brev((unsigned)n) >> 24] =
            make_float2(s * (ev.x * sn.x - ev.y * sn.y),
                        s * (ev.x * sn.y + ev.y * sn.x));
    }
    __syncthreads();
    fft256_wave(X, tw, j, 1.0f);
    #pragma unroll
    for (int e = 0; e < 4; ++e) {
        int n = (e << 6) + j;
        rp[n] = X[n];
    }
}

// Merged: row-inverse FFT of all 12 coils of row y + coil-combine + g emit.
// grid 256 (one block per row), 256 thr; wave w inverse-FFTs coils 3w..3w+2.
__global__ __launch_bounds__(256) void fft_rows_grad(const c32* __restrict__ Fk,
        const c32* __restrict__ sense, const c32* __restrict__ eta,
        short* __restrict__ gTp) {
    __shared__ c32 lds[12][256];     // 24 KB
    __shared__ c32 tw[128];
    int tid = threadIdx.x;
    build_tw(tw, tid);
    int wid = tid >> 6, j = tid & 63;
    int y = blockIdx.x;
    #pragma unroll
    for (int cc = 0; cc < 3; ++cc) {
        int c = wid * 3 + cc;
        const c32* rp = Fk + (size_t)c * HW + y * 256;
        #pragma unroll
        for (int e = 0; e < 4; ++e) {
            int n = (e << 6) + j;
            lds[c][__brev((unsigned)n) >> 24] = rp[n];
        }
    }
    __syncthreads();                 // tw + loads
    #pragma unroll
    for (int cc = 0; cc < 3; ++cc)
        fft256_wave(&lds[wid * 3 + cc][0], tw, j, -1.0f);
    __syncthreads();                 // combine reads all 12 rows
    int x = tid;
    int p = y * 256 + x;
    float ax = 0.f, ay = 0.f;
    #pragma unroll
    for (int c = 0; c < NC; ++c) {
        c32 t = lds[c][x];
        c32 s = sense[(size_t)c * HW + p];
        ax += t.x * s.x + t.y * s.y;
        ay += t.y * s.x - t.x * s.y;
    }
    float sc = (((x + y) & 1) ? -1.0f : 1.0f) * (1.0f / 256.0f);
    c32 e = eta[p];
    ushort4 o;
    o.x = (unsigned short)f2bf(e.x);
    o.y = (unsigned short)f2bf(e.y);
    o.z = (unsigned short)f2bf(ax * sc);
    o.w = (unsigned short)f2bf(ay * sc);
    ((ushort4*)gTp)[(y + 2) * P2 + x + 2] = o;
}

// Plain col FFT (init inverse only). grid (64, NC). 2 barriers.
__global__ __launch_bounds__(256) void fft_cols(c32* __restrict__ buf, float conjf) {
    __shared__ c32 lds[4][257];
    __shared__ c32 tw[128];
    int tid = threadIdx.x;
    build_tw(tw, tid);
    c32* ip = buf + (size_t)blockIdx.y * HW;
    int x0 = blockIdx.x * 4;
    int cl = tid & 3, yb = tid >> 2;
    #pragma unroll
    for (int e = 0; e < 4; ++e) {
        int y = yb + (e << 6);
        lds[cl][__brev((unsigned)y) >> 24] = ip[y * 256 + x0 + cl];
    }
    __syncthreads();                 // cross-wave load
    int col = tid >> 6, j = tid & 63;
    fft256_wave(&lds[col][0], tw, j, conjf);
    __syncthreads();                 // cross-wave store
    #pragma unroll
    for (int e = 0; e < 4; ++e) {
        int y = yb + (e << 6);
        ip[y * 256 + x0 + cl] = lds[cl][y];
    }
}

// Fused: fwd col FFT -> (out write + masked residual) -> inv col FFT.
// 5 block barriers (was ~19).
__global__ __launch_bounds__(256) void fft_cols_fused(c32* __restrict__ buf,
        const c32* __restrict__ base, const c32* __restrict__ ksp,
        const int* __restrict__ mask, c32* __restrict__ outp, int write_out) {
    __shared__ c32 lds[4][257];
    __shared__ c32 tw[128];
    int tid = threadIdx.x;
    build_tw(tw, tid);
    int coil = blockIdx.y;
    c32* ip = buf + (size_t)coil * HW;
    int x0 = blockIdx.x * 4;
    int cl = tid & 3, yb = tid >> 2;
    #pragma unroll
    for (int e = 0; e < 4; ++e) {
        int y = yb + (e << 6);
        lds[cl][__brev((unsigned)y) >> 24] = ip[y * 256 + x0 + cl];
    }
    __syncthreads();                 // 1: cross-wave load
    int col = tid >> 6, j = tid & 63;
    fft256_wave(&lds[col][0], tw, j, 1.0f);
    __syncthreads();                 // 2: epilogue reads cross-wave

    int x = x0 + cl;
    c32 G[4];
    #pragma unroll
    for (int e = 0; e < 4; ++e) {
        int y = yb + (e << 6);
        G[e] = lds[cl][y];
    }
    __syncthreads();                 // 3: all G reads done before overwrite
    #pragma unroll
    for (int e = 0; e < 4; ++e) {
        int y = yb + (e << 6);
        int p = y * 256 + x;
        size_t i = (size_t)coil * HW + p;
        float s = ((p ^ (p >> 8)) & 1) ? -1.0f : 1.0f;
        if (write_out) {
            c32 bv = base[i];
            float sc = s * (1.0f / 256.0f);
            outp[i] = make_float2(bv.x - sc * G[e].x, bv.y - sc * G[e].y);
        }
        c32 rv = make_float2(0.f, 0.f);
        if (mask[p]) {
            c32 k = ksp[i];
            rv = make_float2(G[e].x * (1.0f / 256.0f) - s * k.x,
                             G[e].y * (1.0f / 256.0f) - s * k.y);
        }
        lds[cl][__brev((unsigned)y) >> 24] = rv;
    }
    __syncthreads();                 // 4: resid writes before inv stages
    fft256_wave(&lds[col][0], tw, j, -1.0f);
    __syncthreads();                 // 5: cross-wave store
    #pragma unroll
    for (int e = 0; e < 4; ++e) {
        int y = yb + (e << 6);
        ip[y * 256 + x0 + cl] = lds[cl][y];
    }
}

// ===================== pointwise kernels =====================
__global__ __launch_bounds__(256) void k_combine_eta0(const c32* __restrict__ tmp,
        const c32* __restrict__ sense, c32* __restrict__ eta) {
    int p = blockIdx.x * 256 + threadIdx.x;
    float ax = 0.f, ay = 0.f;
    for (int c = 0; c < NC; ++c) {
        c32 t = tmp[c * HW + p], s = sense[c * HW + p];
        ax += t.x * s.x + t.y * s.y;
        ay += t.y * s.x - t.x * s.y;
    }
    float sc = ssign(p) * (1.0f / 256.0f);
    eta[p] = make_float2(ax * sc, ay * sc);
}

__global__ __launch_bounds__(256) void k_base(const c32* __restrict__ ksp,
        const c32* __restrict__ pred, const int* __restrict__ mask,
        const float* __restrict__ dcw, c32* __restrict__ base) {
    int i = blockIdx.x * 256 + threadIdx.x;
    int p = i & (HW - 1);
    c32 k = ksp[i];
    c32 o = k;
    if (mask[p]) {
        float w = dcw[0];
        c32 pr = pred[i];
        o.x -= (pr.x - k.x) * w;
        o.y -= (pr.y - k.y) * w;
    }
    base[i] = o;
}

// Zero only the 2064 border pixels of the padded buffers.
__global__ __launch_bounds__(256) void k_zero_border(short* __restrict__ gTp,
        short* __restrict__ h1Tp, short* __restrict__ h2Tp) {
    int i = blockIdx.x * 256 + threadIdx.x;
    if (i >= 2064) return;
    int y, x;
    if (i < 1040) {
        int r = i / 260;
        y = (r < 2) ? r : 256 + r;
        x = i % 260;
    } else {
        int j = i - 1040;
        y = 2 + (j >> 2);
        int cix = j & 3;
        x = (cix < 2) ? cix : 256 + cix;
    }
    size_t px = (size_t)y * P2 + x;
    ((ushort4*)gTp)[px] = make_ushort4(0, 0, 0, 0);
    uint4 z = make_uint4(0, 0, 0, 0);
    uint4* p1 = (uint4*)(h1Tp + (px << 6));
    uint4* p2 = (uint4*)(h2Tp + (px << 6));
    #pragma unroll
    for (int e = 0; e < 8; ++e) { p1[e] = z; p2[e] = z; }
}

// ===================== weight prep kernels =====================
__global__ __launch_bounds__(256) void k_prep_c1(const float* __restrict__ w,
        short* __restrict__ wA) {
    int i = blockIdx.x * 256 + threadIdx.x;    // 64*128
    int co = i >> 7, k = i & 127;
    int tap = k >> 2, ci = k & 3;
    float v = (tap < 25) ? w[co * 100 + ci * 25 + tap] : 0.f;
    wA[i] = f2bf(v);
}

__global__ __launch_bounds__(256) void k_prep_c2(const float* __restrict__ w,
        short* __restrict__ wA) {
    int i = blockIdx.x * 256 + threadIdx.x;     // 36864
    int tap = i >> 12, co = (i >> 6) & 63, ci = i & 63;
    wA[i] = f2bf(w[co * 576 + ci * 9 + tap]);
}

__global__ __launch_bounds__(256) void k_prep_cf(const float* __restrict__ w,
        short* __restrict__ wA) {
    int i = blockIdx.x * 256 + threadIdx.x;    // 9216
    int tap = i >> 10, r = (i >> 6) & 15, ci = i & 63;
    float v = (r < 2) ? w[r * 576 + ci * 9 + tap] : 0.f;
    wA[i] = f2bf(v);
}

__global__ __launch_bounds__(128) void k_prep_gru(const float* __restrict__ ihw,
        const float* __restrict__ ihb, const float* __restrict__ hhw,
        const float* __restrict__ hhb, short* __restrict__ w2, float* __restrict__ bias) {
    int k = threadIdx.x;
    int r = blockIdx.x;
    int g = r >> 6, co = r & 63;
    float v = 0.f;
    if (g == 0)      v = (k < 64) ? ihw[co * 64 + k]         : hhw[co * 64 + k - 64];
    else if (g == 1) v = (k < 64) ? ihw[(64 + co) * 64 + k]  : hhw[(64 + co) * 64 + k - 64];
    else if (g == 2) v = (k < 64) ? ihw[(128 + co) * 64 + k] : 0.f;
    else             v = (k < 64) ? 0.f : hhw[(128 + co) * 64 + k - 64];
    w2[r * 128 + k] = f2bf(v);
    if (k == 0) {
        float b = (g == 0) ? ihb[co] + hhb[co]
                : (g == 1) ? ihb[64 + co] + hhb[64 + co]
                : (g == 2) ? ihb[128 + co] : hhb[128 + co];
        bias[r] = b;
    }
}

// ===================== conv1 via MFMA (padded, branchless, hoisted B) ======
__global__ __launch_bounds__(256, 2) void conv1_mfma(const short* __restrict__ gTp,
        const short* __restrict__ wA, const float* __restrict__ bias,
        float* __restrict__ out) {
    int wv = threadIdx.x >> 6, l = threadIdx.x & 63;
    int lr = l & 15, lg = l >> 4;
    int y = blockIdx.x >> 3;
    int x0 = (blockIdx.x & 7) << 5;

    bf16x8 A[4];
    const short* pA = wA + (size_t)(wv * 16 + lr) * 128 + lg * 8;
    #pragma unroll
    for (int kt = 0; kt < 4; ++kt) A[kt] = *(const bf16x8*)(pA + kt * 32);

    bf16x8 B[2][4];
    #pragma unroll
    for (int nt = 0; nt < 2; ++nt) {
        int x = x0 + nt * 16 + lr;
        #pragma unroll
        for (int kt = 0; kt < 4; ++kt) {
            int t0 = kt * 8 + lg * 2;
            #pragma unroll
            for (int half = 0; half < 2; ++half) {
                int tap = t0 + half;
                int tt = (tap < 25) ? tap : 0;   // pad taps: A rows are zero
                int dy = tt / 5 - 2, dx = tt % 5 - 2;
                ushort4 v = *(const ushort4*)(gTp +
                    ((size_t)((y + dy + 2) * P2 + (x + dx + 2)) << 2));
                B[nt][kt][half * 4 + 0] = (short)v.x;
                B[nt][kt][half * 4 + 1] = (short)v.y;
                B[nt][kt][half * 4 + 2] = (short)v.z;
                B[nt][kt][half * 4 + 3] = (short)v.w;
            }
        }
    }
    f32x4 C[2];
    #pragma unroll
    for (int nt = 0; nt < 2; ++nt) {
        C[nt] = (f32x4){0.f, 0.f, 0.f, 0.f};
        #pragma unroll
        for (int kt = 0; kt < 4; ++kt)
            C[nt] = __builtin_amdgcn_mfma_f32_16x16x32_bf16(A[kt], B[nt][kt], C[nt], 0, 0, 0);
    }
    int co = wv * 16 + lg * 4;
    #pragma unroll
    for (int nt = 0; nt < 2; ++nt) {
        int px = y * 256 + x0 + nt * 16 + lr;
        #pragma unroll
        for (int i = 0; i < 4; ++i)
            out[(size_t)(co + i) * HW + px] = fmaxf(C[nt][i] + bias[co + i], 0.f);
    }
}

// ===================== conv2 via MFMA + LDS staging =====================
__global__ __launch_bounds__(256, 2) void conv2_mfma(const short* __restrict__ hTp,
        const short* __restrict__ wA, const float* __restrict__ bias,
        float* __restrict__ out) {
    __shared__ uint4 Ld[3][68][9];       // 29376 B, entries 0..7 used
    int tid = threadIdx.x;
    int wv = tid >> 6, l = tid & 63;
    int lr = l & 15, lg = l >> 4;
    int y = blockIdx.x >> 2;
    int x0 = (blockIdx.x & 3) << 6;

    for (int n = tid; n < 3 * 68 * 8; n += 256) {
        int r = n / (68 * 8);
        int rem = n - r * (68 * 8);
        int px = rem >> 3, e = rem & 7;
        const uint4* src = (const uint4*)(hTp +
            (((size_t)(y + 2 * r) * P2 + (x0 + px)) << 6)) + e;
        Ld[r][px][e] = *src;
    }
    __syncthreads();

    f32x4 C[4];
    #pragma unroll
    for (int nt = 0; nt < 4; ++nt) C[nt] = (f32x4){0.f, 0.f, 0.f, 0.f};

    #pragma unroll
    for (int tap = 0; tap < 9; ++tap) {
        int r = tap / 3;
        int dx = (tap % 3 - 1) * 2;
        const short* pA = wA + (size_t)(tap * 64 + wv * 16 + lr) * 64 + lg * 8;
        bf16x8 A0 = *(const bf16x8*)(pA);
        bf16x8 A1 = *(const bf16x8*)(pA + 32);
        #pragma unroll
        for (int nt = 0; nt < 4; ++nt) {
            int xl = nt * 16 + lr + dx + 2;
            bf16x8 B0 = *(const bf16x8*)&Ld[r][xl][lg];
            bf16x8 B1 = *(const bf16x8*)&Ld[r][xl][4 + lg];
            C[nt] = __builtin_amdgcn_mfma_f32_16x16x32_bf16(A0, B0, C[nt], 0, 0, 0);
            C[nt] = __builtin_amdgcn_mfma_f32_16x16x32_bf16(A1, B1, C[nt], 0, 0, 0);
        }
    }
    int co = wv * 16 + lg * 4;
    #pragma unroll
    for (int nt = 0; nt < 4; ++nt) {
        int px = y * 256 + x0 + nt * 16 + lr;
        #pragma unroll
        for (int i = 0; i < 4; ++i)
            out[(size_t)(co + i) * HW + px] = fmaxf(C[nt][i] + bias[co + i], 0.f);
    }
}

// ===================== GRU via MFMA (padded hT emit) =====================
// FIRST=true: h == 0 (t=0) -> skip all H reads; C3=0; hout=(1-z)*n.
template <bool FIRST>
__global__ __launch_bounds__(256, 2) void gru_mfma(const float* __restrict__ xin,
        const float* __restrict__ h, const short* __restrict__ w2,
        const float* __restrict__ bias, float* __restrict__ hout,
        short* __restrict__ hTp) {
    int wv = threadIdx.x >> 6, l = threadIdx.x & 63;
    int lr = l & 15, lg = l >> 4;
    int px0 = blockIdx.x * 64;

    bf16x8 A0[4], A1[4], A2[2], A3[2];
    {
        const short* w0 = w2 + (0   + wv * 16 + lr) * 128 + lg * 8;
        const short* w1 = w2 + (64  + wv * 16 + lr) * 128 + lg * 8;
        const short* w2p = w2 + (128 + wv * 16 + lr) * 128 + lg * 8;
        const short* w3 = w2 + (192 + wv * 16 + lr) * 128 + lg * 8;
        #pragma unroll
        for (int kt = 0; kt < 4; ++kt) {
            A0[kt] = *(const bf16x8*)(w0 + kt * 32);
            A1[kt] = *(const bf16x8*)(w1 + kt * 32);
        }
        A2[0] = *(const bf16x8*)(w2p);          A2[1] = *(const bf16x8*)(w2p + 32);
        A3[0] = *(const bf16x8*)(w3 + 64);      A3[1] = *(const bf16x8*)(w3 + 96);
    }

    f32x4 C0[4], C1[4], C2[4], C3[4];
    #pragma unroll
    for (int nt = 0; nt < 4; ++nt) {
        C0[nt] = (f32x4){0.f, 0.f, 0.f, 0.f};
        C1[nt] = (f32x4){0.f, 0.f, 0.f, 0.f};
        C2[nt] = (f32x4){0.f, 0.f, 0.f, 0.f};
        C3[nt] = (f32x4){0.f, 0.f, 0.f, 0.f};
    }

    #pragma unroll
    for (int nt = 0; nt < 4; ++nt) {
        int px = px0 + nt * 16 + lr;
        bf16x8 B[4];
        const int NKT = FIRST ? 2 : 4;
        #pragma unroll
        for (int kt = 0; kt < NKT; ++kt) {
            const float* src = (kt < 2) ? xin + (size_t)(kt * 32 + lg * 8) * HW + px
                                        : h   + (size_t)((kt - 2) * 32 + lg * 8) * HW + px;
            #pragma unroll
            for (int j = 0; j < 8; ++j) B[kt][j] = f2bf(src[(size_t)j * HW]);
        }
        #pragma unroll
        for (int kt = 0; kt < NKT; ++kt) {
            C0[nt] = __builtin_amdgcn_mfma_f32_16x16x32_bf16(A0[kt], B[kt], C0[nt], 0, 0, 0);
            C1[nt] = __builtin_amdgcn_mfma_f32_16x16x32_bf16(A1[kt], B[kt], C1[nt], 0, 0, 0);
        }
        C2[nt] = __builtin_amdgcn_mfma_f32_16x16x32_bf16(A2[0], B[0], C2[nt], 0, 0, 0);
        C2[nt] = __builtin_amdgcn_mfma_f32_16x16x32_bf16(A2[1], B[1], C2[nt], 0, 0, 0);
        if (!FIRST) {
            C3[nt] = __builtin_amdgcn_mfma_f32_16x16x32_bf16(A3[0], B[2], C3[nt], 0, 0, 0);
            C3[nt] = __builtin_amdgcn_mfma_f32_16x16x32_bf16(A3[1], B[3], C3[nt], 0, 0, 0);
        }
    }

    int co = wv * 16 + lg * 4;
    float br[4], bz[4], bin_[4], bhn[4];
    #pragma unroll
    for (int i = 0; i < 4; ++i) {
        br[i]   = bias[co + i];
        bz[i]   = bias[64 + co + i];
        bin_[i] = bias[128 + co + i];
        bhn[i]  = bias[192 + co + i];
    }
    #pragma unroll
    for (int nt = 0; nt < 4; ++nt) {
        int px = px0 + nt * 16 + lr;
        int y = px >> 8, x = px & 255;
        size_t tb = ((size_t)((y + 2) * P2 + (x + 2)) << 6);
        #pragma unroll
        for (int i = 0; i < 4; ++i) {
            float r = 1.0f / (1.0f + expf(-(C0[nt][i] + br[i])));
            float z = 1.0f / (1.0f + expf(-(C1[nt][i] + bz[i])));
            float nn = tanhf(C2[nt][i] + bin_[i] + r * (C3[nt][i] + bhn[i]));
            float hv;
            if (FIRST) {
                hv = (1.0f - z) * nn;
            } else {
                float ho = h[(size_t)(co + i) * HW + px];
                hv = (1.0f - z) * nn + z * ho;
            }
            hout[(size_t)(co + i) * HW + px] = hv;
            hTp[tb + co + i] = f2bf(hv);
        }
    }
}

// ===================== final conv via MFMA (padded, prefetch) ==============
__global__ __launch_bounds__(256, 2) void final_mfma(const short* __restrict__ hTp,
        const short* __restrict__ wA, c32* __restrict__ eta) {
    int wv = threadIdx.x >> 6, l = threadIdx.x & 63;
    int lr = l & 15, lg = l >> 4;
    int y = blockIdx.x >> 2;
    int x0 = (blockIdx.x & 3) << 6;
    int x = x0 + wv * 16 + lr;

    auto loadB = [&](int tap, bf16x8& b0, bf16x8& b1) {
        int dy = tap / 3 - 1, dx = tap % 3 - 1;
        const short* pB = hTp +
            ((size_t)((y + dy + 2) * P2 + (x + dx + 2)) << 6) + lg * 8;
        b0 = *(const bf16x8*)(pB);
        b1 = *(const bf16x8*)(pB + 32);
    };

    f32x4 C = (f32x4){0.f, 0.f, 0.f, 0.f};
    bf16x8 cB0, cB1;
    loadB(0, cB0, cB1);
    #pragma unroll
    for (int tap = 0; tap < 9; ++tap) {
        const short* pA = wA + (size_t)(tap * 16 + lr) * 64 + lg * 8;
        bf16x8 A0 = *(const bf16x8*)(pA);
        bf16x8 A1 = *(const bf16x8*)(pA + 32);
        bf16x8 nB0, nB1;
        if (tap < 8) loadB(tap + 1, nB0, nB1);
        C = __builtin_amdgcn_mfma_f32_16x16x32_bf16(A0, cB0, C, 0, 0, 0);
        C = __builtin_amdgcn_mfma_f32_16x16x32_bf16(A1, cB1, C, 0, 0, 0);
        if (tap < 8) { cB0 = nB0; cB1 = nB1; }
    }
    if (lg == 0) {
        int px = y * 256 + x;
        c32 e = eta[px];
        eta[px] = make_float2(e.x + C[0], e.y + C[1]);
    }
}

// ===================== host orchestration =====================
extern "C" void kernel_launch(void* const* d_in, const int* in_sizes, int n_in,
                              void* d_out, int out_size, void* d_ws, size_t ws_size,
                              hipStream_t stream) {
    const c32* pred   = (const c32*)d_in[0];
    const c32* ksp    = (const c32*)d_in[1];
    const c32* sense  = (const c32*)d_in[2];
    const int* mask   = (const int*)d_in[3];
    const float* c1w  = (const float*)d_in[4];
    const float* c1b  = (const float*)d_in[5];
    const float* g1iw = (const float*)d_in[6];
    const float* g1ib = (const float*)d_in[7];
    const float* g1hw = (const float*)d_in[8];
    const float* g1hb = (const float*)d_in[9];
    const float* c2w  = (const float*)d_in[10];
    const float* c2b  = (const float*)d_in[11];
    const float* g2iw = (const float*)d_in[12];
    const float* g2ib = (const float*)d_in[13];
    const float* g2hw = (const float*)d_in[14];
    const float* g2hb = (const float*)d_in[15];
    const float* fw   = (const float*)d_in[16];
    const float* dcw  = (const float*)d_in[17];

    const size_t PP = (size_t)P2 * P2;     // 67600 padded pixels
    float* w0 = (float*)d_ws;
    c32* base = (c32*)w0;                  // NC*HW complex
    c32* Fk   = base + NC * HW;            // NC*HW complex
    c32* tmp  = Fk + NC * HW;              // NC*HW complex (init only)
    c32* eta  = tmp + NC * HW;             // HW complex
    short* gTp = (short*)(eta + HW);       // PP*4 bf16 (padded)
    float* x1 = (float*)(gTp + PP * 4);    // NF*HW
    float* h1a = x1 + NF * HW;
    float* h1b = h1a + NF * HW;
    float* h2a = h1b + NF * HW;
    float* h2b = h2a + NF * HW;
    short* w2a  = (short*)(h2b + NF * HW); // 256*128 bf16
    short* w2b  = w2a + 256 * 128;
    float* biasA = (float*)(w2b + 256 * 128);
    float* biasB = biasA + 256;
    short* h1Tp = (short*)(biasB + 256);   // PP*64 bf16 (padded)
    short* h2Tp = h1Tp + PP * 64;          // PP*64 bf16 (padded)
    short* wAc2 = h2Tp + PP * 64;          // 9*64*64 bf16
    short* wAc1 = wAc2 + 9 * 64 * 64;      // 64*128 bf16
    short* wAcf = wAc1 + 64 * 128;         // 9*16*64 bf16

    dim3 B(256);
    const int gCHW = NC * HW / 256;   // 3072
    const int gHW  = HW / 256;        // 256
    const int gROW = NC * 256 / 4;    // 768
    dim3 gCOL(64, NC);
    const int gGRU = HW / 64;         // 1024 blocks
    const int gCNV = HW / 32;         // 2048 blocks (conv1, nt=2)

    // border zeroing + weight prep (once per call)
    k_zero_border<<<9, B, 0, stream>>>(gTp, h1Tp, h2Tp);
    k_prep_gru<<<256, 128, 0, stream>>>(g1iw, g1ib, g1hw, g1hb, w2a, biasA);
    k_prep_gru<<<256, 128, 0, stream>>>(g2iw, g2ib, g2hw, g2hb, w2b, biasB);
    k_prep_c2<<<144, 256, 0, stream>>>(c2w, wAc2);
    k_prep_c1<<<32, 256, 0, stream>>>(c1w, wAc1);
    k_prep_cf<<<36, 256, 0, stream>>>(fw, wAcf);

    // eta0 = sum_c ifft2c(pred_c) * conj(sense_c)
    fft_rows_pre<<<gROW, B, 0, stream>>>(tmp, pred);
    fft_cols<<<gCOL, B, 0, stream>>>(tmp, -1.0f);
    k_combine_eta0<<<gHW, B, 0, stream>>>(tmp, sense, eta);

    k_base<<<gCHW, B, 0, stream>>>(ksp, pred, mask, dcw, base);

    // F_0: forward FFT of S*(eta0*sense); fused epilogue -> residual (no out)
    fft_rows_exp<<<gROW, B, 0, stream>>>(Fk, eta, sense);
    fft_cols_fused<<<gCOL, B, 0, stream>>>(Fk, base, ksp, mask, (c32*)d_out, 0);

    float* h1c = h1a; float* h1n = h1b;
    float* h2c = h2a; float* h2n = h2b;
    c32* outp = (c32*)d_out;

    for (int t = 0; t < NT; ++t) {
        // row-inverse FFT of residual + coil-combine + g emit (merged)
        fft_rows_grad<<<gHW, B, 0, stream>>>(Fk, sense, eta, gTp);

        conv1_mfma<<<gCNV, B, 0, stream>>>(gTp, wAc1, c1b, x1);
        if (t == 0) {
            gru_mfma<true><<<gGRU, B, 0, stream>>>(x1, h1c, w2a, biasA, h1n, h1Tp);
        } else {
            gru_mfma<false><<<gGRU, B, 0, stream>>>(x1, h1c, w2a, biasA, h1n, h1Tp);
        }
        { float* s = h1c; h1c = h1n; h1n = s; }
        conv2_mfma<<<gGRU, B, 0, stream>>>(h1Tp, wAc2, c2b, x1);
        if (t == 0) {
            gru_mfma<true><<<gGRU, B, 0, stream>>>(x1, h2c, w2b, biasB, h2n, h2Tp);
        } else {
            gru_mfma<false><<<gGRU, B, 0, stream>>>(x1, h2c, w2b, biasB, h2n, h2Tp);
        }
        { float* s = h2c; h2c = h2n; h2n = s; }
        final_mfma<<<gGRU, B, 0, stream>>>(h2Tp, wAcf, eta);

        fft_rows_exp<<<gROW, B, 0, stream>>>(Fk, eta, sense);
        fft_cols_fused<<<gCOL, B, 0, stream>>>(Fk, base, ksp, mask,
                                               outp + (size_t)t * NC * HW, 1);
    }
}

// Round 13
// 978.487 us; speedup vs baseline: 1.4442x; 1.0855x over previous
//
#include <hip/hip_runtime.h>

#define HW 65536
#define NC 12
#define NF 64
#define NT 8
#define P2 260   // padded pitch (2-wide zero border each side)

typedef float2 c32;
typedef __attribute__((ext_vector_type(8))) short bf16x8;   // 8 bf16 = 4 VGPR
typedef __attribute__((ext_vector_type(4))) float f32x4;    // MFMA C/D

__device__ __forceinline__ float ssign(int p) {
    return ((p ^ (p >> 8)) & 1) ? -1.0f : 1.0f;
}

__device__ __forceinline__ short f2bf(float f) {   // RNE float->bf16
    union { float f; unsigned u; } v; v.f = f;
    unsigned r = (v.u + 0x7FFFu + ((v.u >> 16) & 1u)) >> 16;
    return (short)r;
}

__device__ __forceinline__ float bf2f(unsigned short u) {
    union { unsigned u; float f; } v; v.u = (unsigned)u << 16;
    return v.f;
}

// ===================== 256-point radix-2 DIT FFT, wave-synchronous ==========
__device__ __forceinline__ void wave_sync() {
    asm volatile("s_waitcnt lgkmcnt(0)" ::: "memory");
}

__device__ __forceinline__ void fft256_wave(c32* X, const c32* tw, int j, float conjf) {
    #pragma unroll
    for (int s = 1; s <= 8; ++s) {
        const int half = 1 << (s - 1);
        #pragma unroll
        for (int b = 0; b < 2; ++b) {
            int idx = j + (b << 6);
            int grp = idx >> (s - 1);
            int pos = idx & (half - 1);
            int i0 = (grp << s) + pos;
            int i1 = i0 + half;
            c32 w = tw[pos << (8 - s)];
            float wy = conjf * w.y;
            c32 a = X[i0], cc = X[i1];
            c32 t = make_float2(w.x * cc.x - wy * cc.y, w.x * cc.y + wy * cc.x);
            X[i0] = make_float2(a.x + t.x, a.y + t.y);
            X[i1] = make_float2(a.x - t.x, a.y - t.y);
        }
        wave_sync();
    }
}

__device__ __forceinline__ void build_tw(c32* tw, int tid) {
    if (tid < 128) {
        float a = -3.14159265358979323846f * (float)tid * (1.0f / 128.0f);
        float sv, cv;
        sincosf(a, &sv, &cv);
        tw[tid] = make_float2(cv, sv);
    }
}

__global__ __launch_bounds__(256) void fft_rows_pre(c32* __restrict__ buf,
        const c32* __restrict__ pred) {
    __shared__ c32 lds[4][256];
    __shared__ c32 tw[128];
    int tid = threadIdx.x;
    build_tw(tw, tid);
    int wid = tid >> 6, j = tid & 63;
    int r = blockIdx.x * 4 + wid;
    int coil = r >> 8, y = r & 255;
    c32* rp = buf + (size_t)r * 256;
    c32* X = lds[wid];
    #pragma unroll
    for (int e = 0; e < 4; ++e) {
        int n = (e << 6) + j;
        float s = ((n + y) & 1) ? -1.0f : 1.0f;
        c32 pv = pred[(size_t)coil * HW + y * 256 + n];
        X[__brev((unsigned)n) >> 24] = make_float2(s * pv.x, s * pv.y);
    }
    __syncthreads();
    fft256_wave(X, tw, j, -1.0f);
    #pragma unroll
    for (int e = 0; e < 4; ++e) {
        int n = (e << 6) + j;
        rp[n] = X[n];
    }
}

__global__ __launch_bounds__(256) void fft_rows_exp(c32* __restrict__ buf,
        const c32* __restrict__ eta, const c32* __restrict__ sense) {
    __shared__ c32 lds[4][256];
    __shared__ c32 tw[128];
    int tid = threadIdx.x;
    build_tw(tw, tid);
    int wid = tid >> 6, j = tid & 63;
    int r = blockIdx.x * 4 + wid;
    int coil = r >> 8, y = r & 255;
    c32* rp = buf + (size_t)r * 256;
    c32* X = lds[wid];
    #pragma unroll
    for (int e = 0; e < 4; ++e) {
        int n = (e << 6) + j;
        float s = ((n + y) & 1) ? -1.0f : 1.0f;
        c32 ev = eta[y * 256 + n];
        c32 sn = sense[(size_t)coil * HW + y * 256 + n];
        X[__brev((unsigned)n) >> 24] =
            make_float2(s * (ev.x * sn.x - ev.y * sn.y),
                        s * (ev.x * sn.y + ev.y * sn.x));
    }
    __syncthreads();
    fft256_wave(X, tw, j, 1.0f);
    #pragma unroll
    for (int e = 0; e < 4; ++e) {
        int n = (e << 6) + j;
        rp[n] = X[n];
    }
}

// Merged: row-inverse FFT of all 12 coils of row y + coil-combine + g emit.
__global__ __launch_bounds__(256) void fft_rows_grad(const c32* __restrict__ Fk,
        const c32* __restrict__ sense, const c32* __restrict__ eta,
        short* __restrict__ gTp) {
    __shared__ c32 lds[12][256];     // 24 KB
    __shared__ c32 tw[128];
    int tid = threadIdx.x;
    build_tw(tw, tid);
    int wid = tid >> 6, j = tid & 63;
    int y = blockIdx.x;
    #pragma unroll
    for (int cc = 0; cc < 3; ++cc) {
        int c = wid * 3 + cc;
        const c32* rp = Fk + (size_t)c * HW + y * 256;
        #pragma unroll
        for (int e = 0; e < 4; ++e) {
            int n = (e << 6) + j;
            lds[c][__brev((unsigned)n) >> 24] = rp[n];
        }
    }
    __syncthreads();
    #pragma unroll
    for (int cc = 0; cc < 3; ++cc)
        fft256_wave(&lds[wid * 3 + cc][0], tw, j, -1.0f);
    __syncthreads();
    int x = tid;
    int p = y * 256 + x;
    float ax = 0.f, ay = 0.f;
    #pragma unroll
    for (int c = 0; c < NC; ++c) {
        c32 t = lds[c][x];
        c32 s = sense[(size_t)c * HW + p];
        ax += t.x * s.x + t.y * s.y;
        ay += t.y * s.x - t.x * s.y;
    }
    float sc = (((x + y) & 1) ? -1.0f : 1.0f) * (1.0f / 256.0f);
    c32 e = eta[p];
    ushort4 o;
    o.x = (unsigned short)f2bf(e.x);
    o.y = (unsigned short)f2bf(e.y);
    o.z = (unsigned short)f2bf(ax * sc);
    o.w = (unsigned short)f2bf(ay * sc);
    ((ushort4*)gTp)[(y + 2) * P2 + x + 2] = o;
}

__global__ __launch_bounds__(256) void fft_cols(c32* __restrict__ buf, float conjf) {
    __shared__ c32 lds[4][257];
    __shared__ c32 tw[128];
    int tid = threadIdx.x;
    build_tw(tw, tid);
    c32* ip = buf + (size_t)blockIdx.y * HW;
    int x0 = blockIdx.x * 4;
    int cl = tid & 3, yb = tid >> 2;
    #pragma unroll
    for (int e = 0; e < 4; ++e) {
        int y = yb + (e << 6);
        lds[cl][__brev((unsigned)y) >> 24] = ip[y * 256 + x0 + cl];
    }
    __syncthreads();
    int col = tid >> 6, j = tid & 63;
    fft256_wave(&lds[col][0], tw, j, conjf);
    __syncthreads();
    #pragma unroll
    for (int e = 0; e < 4; ++e) {
        int y = yb + (e << 6);
        ip[y * 256 + x0 + cl] = lds[cl][y];
    }
}

// Fused: fwd col FFT -> (out write + masked residual) -> inv col FFT.
__global__ __launch_bounds__(256) void fft_cols_fused(c32* __restrict__ buf,
        const c32* __restrict__ base, const c32* __restrict__ ksp,
        const int* __restrict__ mask, c32* __restrict__ outp, int write_out) {
    __shared__ c32 lds[4][257];
    __shared__ c32 tw[128];
    int tid = threadIdx.x;
    build_tw(tw, tid);
    int coil = blockIdx.y;
    c32* ip = buf + (size_t)coil * HW;
    int x0 = blockIdx.x * 4;
    int cl = tid & 3, yb = tid >> 2;
    #pragma unroll
    for (int e = 0; e < 4; ++e) {
        int y = yb + (e << 6);
        lds[cl][__brev((unsigned)y) >> 24] = ip[y * 256 + x0 + cl];
    }
    __syncthreads();
    int col = tid >> 6, j = tid & 63;
    fft256_wave(&lds[col][0], tw, j, 1.0f);
    __syncthreads();

    int x = x0 + cl;
    c32 G[4];
    #pragma unroll
    for (int e = 0; e < 4; ++e) {
        int y = yb + (e << 6);
        G[e] = lds[cl][y];
    }
    __syncthreads();
    #pragma unroll
    for (int e = 0; e < 4; ++e) {
        int y = yb + (e << 6);
        int p = y * 256 + x;
        size_t i = (size_t)coil * HW + p;
        float s = ((p ^ (p >> 8)) & 1) ? -1.0f : 1.0f;
        if (write_out) {
            c32 bv = base[i];
            float sc = s * (1.0f / 256.0f);
            outp[i] = make_float2(bv.x - sc * G[e].x, bv.y - sc * G[e].y);
        }
        c32 rv = make_float2(0.f, 0.f);
        if (mask[p]) {
            c32 k = ksp[i];
            rv = make_float2(G[e].x * (1.0f / 256.0f) - s * k.x,
                             G[e].y * (1.0f / 256.0f) - s * k.y);
        }
        lds[cl][__brev((unsigned)y) >> 24] = rv;
    }
    __syncthreads();
    fft256_wave(&lds[col][0], tw, j, -1.0f);
    __syncthreads();
    #pragma unroll
    for (int e = 0; e < 4; ++e) {
        int y = yb + (e << 6);
        ip[y * 256 + x0 + cl] = lds[cl][y];
    }
}

// ===================== pointwise kernels =====================
__global__ __launch_bounds__(256) void k_combine_eta0(const c32* __restrict__ tmp,
        const c32* __restrict__ sense, c32* __restrict__ eta) {
    int p = blockIdx.x * 256 + threadIdx.x;
    float ax = 0.f, ay = 0.f;
    for (int c = 0; c < NC; ++c) {
        c32 t = tmp[c * HW + p], s = sense[c * HW + p];
        ax += t.x * s.x + t.y * s.y;
        ay += t.y * s.x - t.x * s.y;
    }
    float sc = ssign(p) * (1.0f / 256.0f);
    eta[p] = make_float2(ax * sc, ay * sc);
}

__global__ __launch_bounds__(256) void k_base(const c32* __restrict__ ksp,
        const c32* __restrict__ pred, const int* __restrict__ mask,
        const float* __restrict__ dcw, c32* __restrict__ base) {
    int i = blockIdx.x * 256 + threadIdx.x;
    int p = i & (HW - 1);
    c32 k = ksp[i];
    c32 o = k;
    if (mask[p]) {
        float w = dcw[0];
        c32 pr = pred[i];
        o.x -= (pr.x - k.x) * w;
        o.y -= (pr.y - k.y) * w;
    }
    base[i] = o;
}

// Zero the border pixels of gTp + the 4 padded h buffers.
__global__ __launch_bounds__(256) void k_zero_border(short* __restrict__ gTp,
        short* __restrict__ h1a, short* __restrict__ h1b,
        short* __restrict__ h2a, short* __restrict__ h2b) {
    int i = blockIdx.x * 256 + threadIdx.x;
    if (i >= 2064) return;
    int y, x;
    if (i < 1040) {
        int r = i / 260;
        y = (r < 2) ? r : 256 + r;
        x = i % 260;
    } else {
        int j = i - 1040;
        y = 2 + (j >> 2);
        int cix = j & 3;
        x = (cix < 2) ? cix : 256 + cix;
    }
    size_t px = (size_t)y * P2 + x;
    ((ushort4*)gTp)[px] = make_ushort4(0, 0, 0, 0);
    uint4 z = make_uint4(0, 0, 0, 0);
    uint4* p1 = (uint4*)(h1a + (px << 6));
    uint4* p2 = (uint4*)(h1b + (px << 6));
    uint4* p3 = (uint4*)(h2a + (px << 6));
    uint4* p4 = (uint4*)(h2b + (px << 6));
    #pragma unroll
    for (int e = 0; e < 8; ++e) { p1[e] = z; p2[e] = z; p3[e] = z; p4[e] = z; }
}

// ===================== weight prep kernels =====================
__global__ __launch_bounds__(256) void k_prep_c1(const float* __restrict__ w,
        short* __restrict__ wA) {
    int i = blockIdx.x * 256 + threadIdx.x;    // 64*128
    int co = i >> 7, k = i & 127;
    int tap = k >> 2, ci = k & 3;
    float v = (tap < 25) ? w[co * 100 + ci * 25 + tap] : 0.f;
    wA[i] = f2bf(v);
}

__global__ __launch_bounds__(256) void k_prep_c2(const float* __restrict__ w,
        short* __restrict__ wA) {
    int i = blockIdx.x * 256 + threadIdx.x;     // 36864
    int tap = i >> 12, co = (i >> 6) & 63, ci = i & 63;
    wA[i] = f2bf(w[co * 576 + ci * 9 + tap]);
}

__global__ __launch_bounds__(256) void k_prep_cf(const float* __restrict__ w,
        short* __restrict__ wA) {
    int i = blockIdx.x * 256 + threadIdx.x;    // 9216
    int tap = i >> 10, r = (i >> 6) & 15, ci = i & 63;
    float v = (r < 2) ? w[r * 576 + ci * 9 + tap] : 0.f;
    wA[i] = f2bf(v);
}

__global__ __launch_bounds__(128) void k_prep_gru(const float* __restrict__ ihw,
        const float* __restrict__ ihb, const float* __restrict__ hhw,
        const float* __restrict__ hhb, short* __restrict__ w2, float* __restrict__ bias) {
    int k = threadIdx.x;
    int r = blockIdx.x;
    int g = r >> 6, co = r & 63;
    float v = 0.f;
    if (g == 0)      v = (k < 64) ? ihw[co * 64 + k]         : hhw[co * 64 + k - 64];
    else if (g == 1) v = (k < 64) ? ihw[(64 + co) * 64 + k]  : hhw[(64 + co) * 64 + k - 64];
    else if (g == 2) v = (k < 64) ? ihw[(128 + co) * 64 + k] : 0.f;
    else             v = (k < 64) ? 0.f : hhw[(128 + co) * 64 + k - 64];
    w2[r * 128 + k] = f2bf(v);
    if (k == 0) {
        float b = (g == 0) ? ihb[co] + hhb[co]
                : (g == 1) ? ihb[64 + co] + hhb[64 + co]
                : (g == 2) ? ihb[128 + co] : hhb[128 + co];
        bias[r] = b;
    }
}

// ===================== conv1 via MFMA -> bf16 transposed out ===============
// grid 2048 (y*8 xseg), 256 thr, nt=2. Output xT[px][64] bf16.
__global__ __launch_bounds__(256, 2) void conv1_mfma(const short* __restrict__ gTp,
        const short* __restrict__ wA, const float* __restrict__ bias,
        short* __restrict__ xT) {
    int wv = threadIdx.x >> 6, l = threadIdx.x & 63;
    int lr = l & 15, lg = l >> 4;
    int y = blockIdx.x >> 3;
    int x0 = (blockIdx.x & 7) << 5;

    bf16x8 A[4];
    const short* pA = wA + (size_t)(wv * 16 + lr) * 128 + lg * 8;
    #pragma unroll
    for (int kt = 0; kt < 4; ++kt) A[kt] = *(const bf16x8*)(pA + kt * 32);

    bf16x8 B[2][4];
    #pragma unroll
    for (int nt = 0; nt < 2; ++nt) {
        int x = x0 + nt * 16 + lr;
        #pragma unroll
        for (int kt = 0; kt < 4; ++kt) {
            int t0 = kt * 8 + lg * 2;
            #pragma unroll
            for (int half = 0; half < 2; ++half) {
                int tap = t0 + half;
                int tt = (tap < 25) ? tap : 0;
                int dy = tt / 5 - 2, dx = tt % 5 - 2;
                ushort4 v = *(const ushort4*)(gTp +
                    ((size_t)((y + dy + 2) * P2 + (x + dx + 2)) << 2));
                B[nt][kt][half * 4 + 0] = (short)v.x;
                B[nt][kt][half * 4 + 1] = (short)v.y;
                B[nt][kt][half * 4 + 2] = (short)v.z;
                B[nt][kt][half * 4 + 3] = (short)v.w;
            }
        }
    }
    f32x4 C[2];
    #pragma unroll
    for (int nt = 0; nt < 2; ++nt) {
        C[nt] = (f32x4){0.f, 0.f, 0.f, 0.f};
        #pragma unroll
        for (int kt = 0; kt < 4; ++kt)
            C[nt] = __builtin_amdgcn_mfma_f32_16x16x32_bf16(A[kt], B[nt][kt], C[nt], 0, 0, 0);
    }
    int co = wv * 16 + lg * 4;
    #pragma unroll
    for (int nt = 0; nt < 2; ++nt) {
        int px = y * 256 + x0 + nt * 16 + lr;
        ushort4 st;
        st.x = (unsigned short)f2bf(fmaxf(C[nt][0] + bias[co + 0], 0.f));
        st.y = (unsigned short)f2bf(fmaxf(C[nt][1] + bias[co + 1], 0.f));
        st.z = (unsigned short)f2bf(fmaxf(C[nt][2] + bias[co + 2], 0.f));
        st.w = (unsigned short)f2bf(fmaxf(C[nt][3] + bias[co + 3], 0.f));
        *(ushort4*)(xT + ((size_t)px << 6) + co) = st;
    }
}

// ===================== conv2 via MFMA + LDS staging -> bf16 out ============
__global__ __launch_bounds__(256, 2) void conv2_mfma(const short* __restrict__ hTp,
        const short* __restrict__ wA, const float* __restrict__ bias,
        short* __restrict__ xT) {
    __shared__ uint4 Ld[3][68][9];       // 29376 B
    int tid = threadIdx.x;
    int wv = tid >> 6, l = tid & 63;
    int lr = l & 15, lg = l >> 4;
    int y = blockIdx.x >> 2;
    int x0 = (blockIdx.x & 3) << 6;

    for (int n = tid; n < 3 * 68 * 8; n += 256) {
        int r = n / (68 * 8);
        int rem = n - r * (68 * 8);
        int px = rem >> 3, e = rem & 7;
        const uint4* src = (const uint4*)(hTp +
            (((size_t)(y + 2 * r) * P2 + (x0 + px)) << 6)) + e;
        Ld[r][px][e] = *src;
    }
    __syncthreads();

    f32x4 C[4];
    #pragma unroll
    for (int nt = 0; nt < 4; ++nt) C[nt] = (f32x4){0.f, 0.f, 0.f, 0.f};

    #pragma unroll
    for (int tap = 0; tap < 9; ++tap) {
        int r = tap / 3;
        int dx = (tap % 3 - 1) * 2;
        const short* pA = wA + (size_t)(tap * 64 + wv * 16 + lr) * 64 + lg * 8;
        bf16x8 A0 = *(const bf16x8*)(pA);
        bf16x8 A1 = *(const bf16x8*)(pA + 32);
        #pragma unroll
        for (int nt = 0; nt < 4; ++nt) {
            int xl = nt * 16 + lr + dx + 2;
            bf16x8 B0 = *(const bf16x8*)&Ld[r][xl][lg];
            bf16x8 B1 = *(const bf16x8*)&Ld[r][xl][4 + lg];
            C[nt] = __builtin_amdgcn_mfma_f32_16x16x32_bf16(A0, B0, C[nt], 0, 0, 0);
            C[nt] = __builtin_amdgcn_mfma_f32_16x16x32_bf16(A1, B1, C[nt], 0, 0, 0);
        }
    }
    int co = wv * 16 + lg * 4;
    #pragma unroll
    for (int nt = 0; nt < 4; ++nt) {
        int px = y * 256 + x0 + nt * 16 + lr;
        ushort4 st;
        st.x = (unsigned short)f2bf(fmaxf(C[nt][0] + bias[co + 0], 0.f));
        st.y = (unsigned short)f2bf(fmaxf(C[nt][1] + bias[co + 1], 0.f));
        st.z = (unsigned short)f2bf(fmaxf(C[nt][2] + bias[co + 2], 0.f));
        st.w = (unsigned short)f2bf(fmaxf(C[nt][3] + bias[co + 3], 0.f));
        *(ushort4*)(xT + ((size_t)px << 6) + co) = st;
    }
}

// ===================== GRU via MFMA, bf16 in/out ===========================
// xT: [px][64] bf16. hprev/hnext: padded [(y+2)*P2+x+2][64] bf16.
// FIRST=true: h==0 -> skip h reads; C3=0; hv=(1-z)*n.
template <bool FIRST>
__global__ __launch_bounds__(256, 2) void gru_mfma(const short* __restrict__ xT,
        const short* __restrict__ hprev, const short* __restrict__ w2,
        const float* __restrict__ bias, short* __restrict__ hnext) {
    int wv = threadIdx.x >> 6, l = threadIdx.x & 63;
    int lr = l & 15, lg = l >> 4;
    int px0 = blockIdx.x * 64;

    bf16x8 A0[4], A1[4], A2[2], A3[2];
    {
        const short* w0 = w2 + (0   + wv * 16 + lr) * 128 + lg * 8;
        const short* w1 = w2 + (64  + wv * 16 + lr) * 128 + lg * 8;
        const short* w2p = w2 + (128 + wv * 16 + lr) * 128 + lg * 8;
        const short* w3 = w2 + (192 + wv * 16 + lr) * 128 + lg * 8;
        #pragma unroll
        for (int kt = 0; kt < 4; ++kt) {
            A0[kt] = *(const bf16x8*)(w0 + kt * 32);
            A1[kt] = *(const bf16x8*)(w1 + kt * 32);
        }
        A2[0] = *(const bf16x8*)(w2p);          A2[1] = *(const bf16x8*)(w2p + 32);
        A3[0] = *(const bf16x8*)(w3 + 64);      A3[1] = *(const bf16x8*)(w3 + 96);
    }

    f32x4 C0[4], C1[4], C2[4], C3[4];
    #pragma unroll
    for (int nt = 0; nt < 4; ++nt) {
        C0[nt] = (f32x4){0.f, 0.f, 0.f, 0.f};
        C1[nt] = (f32x4){0.f, 0.f, 0.f, 0.f};
        C2[nt] = (f32x4){0.f, 0.f, 0.f, 0.f};
        C3[nt] = (f32x4){0.f, 0.f, 0.f, 0.f};
    }

    #pragma unroll
    for (int nt = 0; nt < 4; ++nt) {
        int px = px0 + nt * 16 + lr;
        int yy = px >> 8, xx = px & 255;
        size_t pb = ((size_t)((yy + 2) * P2 + (xx + 2)) << 6);
        bf16x8 B0 = *(const bf16x8*)(xT + ((size_t)px << 6) + lg * 8);
        bf16x8 B1 = *(const bf16x8*)(xT + ((size_t)px << 6) + 32 + lg * 8);
        C0[nt] = __builtin_amdgcn_mfma_f32_16x16x32_bf16(A0[0], B0, C0[nt], 0, 0, 0);
        C0[nt] = __builtin_amdgcn_mfma_f32_16x16x32_bf16(A0[1], B1, C0[nt], 0, 0, 0);
        C1[nt] = __builtin_amdgcn_mfma_f32_16x16x32_bf16(A1[0], B0, C1[nt], 0, 0, 0);
        C1[nt] = __builtin_amdgcn_mfma_f32_16x16x32_bf16(A1[1], B1, C1[nt], 0, 0, 0);
        C2[nt] = __builtin_amdgcn_mfma_f32_16x16x32_bf16(A2[0], B0, C2[nt], 0, 0, 0);
        C2[nt] = __builtin_amdgcn_mfma_f32_16x16x32_bf16(A2[1], B1, C2[nt], 0, 0, 0);
        if (!FIRST) {
            bf16x8 B2 = *(const bf16x8*)(hprev + pb + lg * 8);
            bf16x8 B3 = *(const bf16x8*)(hprev + pb + 32 + lg * 8);
            C0[nt] = __builtin_amdgcn_mfma_f32_16x16x32_bf16(A0[2], B2, C0[nt], 0, 0, 0);
            C0[nt] = __builtin_amdgcn_mfma_f32_16x16x32_bf16(A0[3], B3, C0[nt], 0, 0, 0);
            C1[nt] = __builtin_amdgcn_mfma_f32_16x16x32_bf16(A1[2], B2, C1[nt], 0, 0, 0);
            C1[nt] = __builtin_amdgcn_mfma_f32_16x16x32_bf16(A1[3], B3, C1[nt], 0, 0, 0);
            C3[nt] = __builtin_amdgcn_mfma_f32_16x16x32_bf16(A3[0], B2, C3[nt], 0, 0, 0);
            C3[nt] = __builtin_amdgcn_mfma_f32_16x16x32_bf16(A3[1], B3, C3[nt], 0, 0, 0);
        }
    }

    int co = wv * 16 + lg * 4;
    float br[4], bz[4], bin_[4], bhn[4];
    #pragma unroll
    for (int i = 0; i < 4; ++i) {
        br[i]   = bias[co + i];
        bz[i]   = bias[64 + co + i];
        bin_[i] = bias[128 + co + i];
        bhn[i]  = bias[192 + co + i];
    }
    #pragma unroll
    for (int nt = 0; nt < 4; ++nt) {
        int px = px0 + nt * 16 + lr;
        int yy = px >> 8, xx = px & 255;
        size_t pb = ((size_t)((yy + 2) * P2 + (xx + 2)) << 6);
        ushort4 hov = make_ushort4(0, 0, 0, 0);
        if (!FIRST) hov = *(const ushort4*)(hprev + pb + co);
        float ho[4] = {bf2f(hov.x), bf2f(hov.y), bf2f(hov.z), bf2f(hov.w)};
        ushort4 st;
        unsigned short* sp = &st.x;
        #pragma unroll
        for (int i = 0; i < 4; ++i) {
            float r = 1.0f / (1.0f + expf(-(C0[nt][i] + br[i])));
            float z = 1.0f / (1.0f + expf(-(C1[nt][i] + bz[i])));
            float nn = tanhf(C2[nt][i] + bin_[i] + r * (C3[nt][i] + bhn[i]));
            float hv = FIRST ? (1.0f - z) * nn : (1.0f - z) * nn + z * ho[i];
            sp[i] = (unsigned short)f2bf(hv);
        }
        *(ushort4*)(hnext + pb + co) = st;
    }
}

// ===================== final conv via MFMA (padded, prefetch) ==============
__global__ __launch_bounds__(256, 2) void final_mfma(const short* __restrict__ hTp,
        const short* __restrict__ wA, c32* __restrict__ eta) {
    int wv = threadIdx.x >> 6, l = threadIdx.x & 63;
    int lr = l & 15, lg = l >> 4;
    int y = blockIdx.x >> 2;
    int x0 = (blockIdx.x & 3) << 6;
    int x = x0 + wv * 16 + lr;

    auto loadB = [&](int tap, bf16x8& b0, bf16x8& b1) {
        int dy = tap / 3 - 1, dx = tap % 3 - 1;
        const short* pB = hTp +
            ((size_t)((y + dy + 2) * P2 + (x + dx + 2)) << 6) + lg * 8;
        b0 = *(const bf16x8*)(pB);
        b1 = *(const bf16x8*)(pB + 32);
    };

    f32x4 C = (f32x4){0.f, 0.f, 0.f, 0.f};
    bf16x8 cB0, cB1;
    loadB(0, cB0, cB1);
    #pragma unroll
    for (int tap = 0; tap < 9; ++tap) {
        const short* pA = wA + (size_t)(tap * 16 + lr) * 64 + lg * 8;
        bf16x8 A0 = *(const bf16x8*)(pA);
        bf16x8 A1 = *(const bf16x8*)(pA + 32);
        bf16x8 nB0, nB1;
        if (tap < 8) loadB(tap + 1, nB0, nB1);
        C = __builtin_amdgcn_mfma_f32_16x16x32_bf16(A0, cB0, C, 0, 0, 0);
        C = __builtin_amdgcn_mfma_f32_16x16x32_bf16(A1, cB1, C, 0, 0, 0);
        if (tap < 8) { cB0 = nB0; cB1 = nB1; }
    }
    if (lg == 0) {
        int px = y * 256 + x;
        c32 e = eta[px];
        eta[px] = make_float2(e.x + C[0], e.y + C[1]);
    }
}

// ===================== host orchestration =====================
extern "C" void kernel_launch(void* const* d_in, const int* in_sizes, int n_in,
                              void* d_out, int out_size, void* d_ws, size_t ws_size,
                              hipStream_t stream) {
    const c32* pred   = (const c32*)d_in[0];
    const c32* ksp    = (const c32*)d_in[1];
    const c32* sense  = (const c32*)d_in[2];
    const int* mask   = (const int*)d_in[3];
    const float* c1w  = (const float*)d_in[4];
    const float* c1b  = (const float*)d_in[5];
    const float* g1iw = (const float*)d_in[6];
    const float* g1ib = (const float*)d_in[7];
    const float* g1hw = (const float*)d_in[8];
    const float* g1hb = (const float*)d_in[9];
    const float* c2w  = (const float*)d_in[10];
    const float* c2b  = (const float*)d_in[11];
    const float* g2iw = (const float*)d_in[12];
    const float* g2ib = (const float*)d_in[13];
    const float* g2hw = (const float*)d_in[14];
    const float* g2hb = (const float*)d_in[15];
    const float* fw   = (const float*)d_in[16];
    const float* dcw  = (const float*)d_in[17];

    const size_t PP = (size_t)P2 * P2;     // 67600 padded pixels
    float* w0 = (float*)d_ws;
    c32* base = (c32*)w0;                  // NC*HW complex
    c32* Fk   = base + NC * HW;            // NC*HW complex
    c32* tmp  = Fk + NC * HW;              // NC*HW complex (init only)
    c32* eta  = tmp + NC * HW;             // HW complex
    short* gTp = (short*)(eta + HW);       // PP*4 bf16 (padded)
    short* xT  = gTp + PP * 4;             // HW*64 bf16 (conv out, transposed)
    short* h1Ta = xT + (size_t)HW * 64;    // PP*64 bf16 (padded)
    short* h1Tb = h1Ta + PP * 64;
    short* h2Ta = h1Tb + PP * 64;
    short* h2Tb = h2Ta + PP * 64;
    short* w2a  = h2Tb + PP * 64;          // 256*128 bf16
    short* w2b  = w2a + 256 * 128;
    float* biasA = (float*)(w2b + 256 * 128);
    float* biasB = biasA + 256;
    short* wAc2 = (short*)(biasB + 256);   // 9*64*64 bf16
    short* wAc1 = wAc2 + 9 * 64 * 64;      // 64*128 bf16
    short* wAcf = wAc1 + 64 * 128;         // 9*16*64 bf16

    dim3 B(256);
    const int gCHW = NC * HW / 256;   // 3072
    const int gHW  = HW / 256;        // 256
    const int gROW = NC * 256 / 4;    // 768
    dim3 gCOL(64, NC);
    const int gGRU = HW / 64;         // 1024 blocks
    const int gCNV = HW / 32;         // 2048 blocks (conv1, nt=2)

    // border zeroing + weight prep (once per call)
    k_zero_border<<<9, B, 0, stream>>>(gTp, h1Ta, h1Tb, h2Ta, h2Tb);
    k_prep_gru<<<256, 128, 0, stream>>>(g1iw, g1ib, g1hw, g1hb, w2a, biasA);
    k_prep_gru<<<256, 128, 0, stream>>>(g2iw, g2ib, g2hw, g2hb, w2b, biasB);
    k_prep_c2<<<144, 256, 0, stream>>>(c2w, wAc2);
    k_prep_c1<<<32, 256, 0, stream>>>(c1w, wAc1);
    k_prep_cf<<<36, 256, 0, stream>>>(fw, wAcf);

    // eta0 = sum_c ifft2c(pred_c) * conj(sense_c)
    fft_rows_pre<<<gROW, B, 0, stream>>>(tmp, pred);
    fft_cols<<<gCOL, B, 0, stream>>>(tmp, -1.0f);
    k_combine_eta0<<<gHW, B, 0, stream>>>(tmp, sense, eta);

    k_base<<<gCHW, B, 0, stream>>>(ksp, pred, mask, dcw, base);

    // F_0: forward FFT of S*(eta0*sense); fused epilogue -> residual (no out)
    fft_rows_exp<<<gROW, B, 0, stream>>>(Fk, eta, sense);
    fft_cols_fused<<<gCOL, B, 0, stream>>>(Fk, base, ksp, mask, (c32*)d_out, 0);

    short* h1c = h1Ta; short* h1n = h1Tb;
    short* h2c = h2Ta; short* h2n = h2Tb;
    c32* outp = (c32*)d_out;

    for (int t = 0; t < NT; ++t) {
        fft_rows_grad<<<gHW, B, 0, stream>>>(Fk, sense, eta, gTp);

        conv1_mfma<<<gCNV, B, 0, stream>>>(gTp, wAc1, c1b, xT);
        if (t == 0) {
            gru_mfma<true><<<gGRU, B, 0, stream>>>(xT, h1c, w2a, biasA, h1n);
        } else {
            gru_mfma<false><<<gGRU, B, 0, stream>>>(xT, h1c, w2a, biasA, h1n);
        }
        { short* s = h1c; h1c = h1n; h1n = s; }
        conv2_mfma<<<gGRU, B, 0, stream>>>(h1c, wAc2, c2b, xT);
        if (t == 0) {
            gru_mfma<true><<<gGRU, B, 0, stream>>>(xT, h2c, w2b, biasB, h2n);
        } else {
            gru_mfma<false><<<gGRU, B, 0, stream>>>(xT, h2c, w2b, biasB, h2n);
        }
        { short* s = h2c; h2c = h2n; h2n = s; }
        final_mfma<<<gGRU, B, 0, stream>>>(h2c, wAcf, eta);

        fft_rows_exp<<<gROW, B, 0, stream>>>(Fk, eta, sense);
        fft_cols_fused<<<gCOL, B, 0, stream>>>(Fk, base, ksp, mask,
                                               outp + (size_t)t * NC * HW, 1);
    }
}

// Round 14
// 918.196 us; speedup vs baseline: 1.5390x; 1.0657x over previous
//
#include <hip/hip_runtime.h>

#define HW 65536
#define NC 12
#define NF 64
#define NT 8
#define P2 260   // padded pitch (2-wide zero border each side)

typedef float2 c32;
typedef __attribute__((ext_vector_type(8))) short bf16x8;   // 8 bf16 = 4 VGPR
typedef __attribute__((ext_vector_type(4))) float f32x4;    // MFMA C/D

__device__ __forceinline__ float ssign(int p) {
    return ((p ^ (p >> 8)) & 1) ? -1.0f : 1.0f;
}

__device__ __forceinline__ short f2bf(float f) {   // RNE float->bf16
    union { float f; unsigned u; } v; v.f = f;
    unsigned r = (v.u + 0x7FFFu + ((v.u >> 16) & 1u)) >> 16;
    return (short)r;
}

__device__ __forceinline__ float bf2f(unsigned short u) {
    union { unsigned u; float f; } v; v.u = (unsigned)u << 16;
    return v.f;
}

// ===================== 256-point radix-2 DIT FFT, wave-synchronous ==========
__device__ __forceinline__ void wave_sync() {
    asm volatile("s_waitcnt lgkmcnt(0)" ::: "memory");
}

__device__ __forceinline__ void fft256_wave(c32* X, const c32* tw, int j, float conjf) {
    #pragma unroll
    for (int s = 1; s <= 8; ++s) {
        const int half = 1 << (s - 1);
        #pragma unroll
        for (int b = 0; b < 2; ++b) {
            int idx = j + (b << 6);
            int grp = idx >> (s - 1);
            int pos = idx & (half - 1);
            int i0 = (grp << s) + pos;
            int i1 = i0 + half;
            c32 w = tw[pos << (8 - s)];
            float wy = conjf * w.y;
            c32 a = X[i0], cc = X[i1];
            c32 t = make_float2(w.x * cc.x - wy * cc.y, w.x * cc.y + wy * cc.x);
            X[i0] = make_float2(a.x + t.x, a.y + t.y);
            X[i1] = make_float2(a.x - t.x, a.y - t.y);
        }
        wave_sync();
    }
}

__device__ __forceinline__ void build_tw(c32* tw, int tid) {
    if (tid < 128) {
        float a = -3.14159265358979323846f * (float)tid * (1.0f / 128.0f);
        float sv, cv;
        sincosf(a, &sv, &cv);
        tw[tid] = make_float2(cv, sv);
    }
}

__global__ __launch_bounds__(256) void fft_rows_pre(c32* __restrict__ buf,
        const c32* __restrict__ pred) {
    __shared__ c32 lds[4][256];
    __shared__ c32 tw[128];
    int tid = threadIdx.x;
    build_tw(tw, tid);
    int wid = tid >> 6, j = tid & 63;
    int r = blockIdx.x * 4 + wid;
    int coil = r >> 8, y = r & 255;
    c32* rp = buf + (size_t)r * 256;
    c32* X = lds[wid];
    #pragma unroll
    for (int e = 0; e < 4; ++e) {
        int n = (e << 6) + j;
        float s = ((n + y) & 1) ? -1.0f : 1.0f;
        c32 pv = pred[(size_t)coil * HW + y * 256 + n];
        X[__brev((unsigned)n) >> 24] = make_float2(s * pv.x, s * pv.y);
    }
    __syncthreads();
    fft256_wave(X, tw, j, -1.0f);
    #pragma unroll
    for (int e = 0; e < 4; ++e) {
        int n = (e << 6) + j;
        rp[n] = X[n];
    }
}

__global__ __launch_bounds__(256) void fft_rows_exp(c32* __restrict__ buf,
        const c32* __restrict__ eta, const c32* __restrict__ sense) {
    __shared__ c32 lds[4][256];
    __shared__ c32 tw[128];
    int tid = threadIdx.x;
    build_tw(tw, tid);
    int wid = tid >> 6, j = tid & 63;
    int r = blockIdx.x * 4 + wid;
    int coil = r >> 8, y = r & 255;
    c32* rp = buf + (size_t)r * 256;
    c32* X = lds[wid];
    #pragma unroll
    for (int e = 0; e < 4; ++e) {
        int n = (e << 6) + j;
        float s = ((n + y) & 1) ? -1.0f : 1.0f;
        c32 ev = eta[y * 256 + n];
        c32 sn = sense[(size_t)coil * HW + y * 256 + n];
        X[__brev((unsigned)n) >> 24] =
            make_float2(s * (ev.x * sn.x - ev.y * sn.y),
                        s * (ev.x * sn.y + ev.y * sn.x));
    }
    __syncthreads();
    fft256_wave(X, tw, j, 1.0f);
    #pragma unroll
    for (int e = 0; e < 4; ++e) {
        int n = (e << 6) + j;
        rp[n] = X[n];
    }
}

// Merged: row-inverse FFT of all 12 coils of row y + coil-combine + g emit.
__global__ __launch_bounds__(256) void fft_rows_grad(const c32* __restrict__ Fk,
        const c32* __restrict__ sense, const c32* __restrict__ eta,
        short* __restrict__ gTp) {
    __shared__ c32 lds[12][256];     // 24 KB
    __shared__ c32 tw[128];
    int tid = threadIdx.x;
    build_tw(tw, tid);
    int wid = tid >> 6, j = tid & 63;
    int y = blockIdx.x;
    #pragma unroll
    for (int cc = 0; cc < 3; ++cc) {
        int c = wid * 3 + cc;
        const c32* rp = Fk + (size_t)c * HW + y * 256;
        #pragma unroll
        for (int e = 0; e < 4; ++e) {
            int n = (e << 6) + j;
            lds[c][__brev((unsigned)n) >> 24] = rp[n];
        }
    }
    __syncthreads();
    #pragma unroll
    for (int cc = 0; cc < 3; ++cc)
        fft256_wave(&lds[wid * 3 + cc][0], tw, j, -1.0f);
    __syncthreads();
    int x = tid;
    int p = y * 256 + x;
    float ax = 0.f, ay = 0.f;
    #pragma unroll
    for (int c = 0; c < NC; ++c) {
        c32 t = lds[c][x];
        c32 s = sense[(size_t)c * HW + p];
        ax += t.x * s.x + t.y * s.y;
        ay += t.y * s.x - t.x * s.y;
    }
    float sc = (((x + y) & 1) ? -1.0f : 1.0f) * (1.0f / 256.0f);
    c32 e = eta[p];
    ushort4 o;
    o.x = (unsigned short)f2bf(e.x);
    o.y = (unsigned short)f2bf(e.y);
    o.z = (unsigned short)f2bf(ax * sc);
    o.w = (unsigned short)f2bf(ay * sc);
    ((ushort4*)gTp)[(y + 2) * P2 + x + 2] = o;
}

__global__ __launch_bounds__(256) void fft_cols(c32* __restrict__ buf, float conjf) {
    __shared__ c32 lds[4][257];
    __shared__ c32 tw[128];
    int tid = threadIdx.x;
    build_tw(tw, tid);
    c32* ip = buf + (size_t)blockIdx.y * HW;
    int x0 = blockIdx.x * 4;
    int cl = tid & 3, yb = tid >> 2;
    #pragma unroll
    for (int e = 0; e < 4; ++e) {
        int y = yb + (e << 6);
        lds[cl][__brev((unsigned)y) >> 24] = ip[y * 256 + x0 + cl];
    }
    __syncthreads();
    int col = tid >> 6, j = tid & 63;
    fft256_wave(&lds[col][0], tw, j, conjf);
    __syncthreads();
    #pragma unroll
    for (int e = 0; e < 4; ++e) {
        int y = yb + (e << 6);
        ip[y * 256 + x0 + cl] = lds[cl][y];
    }
}

// Fused: fwd col FFT -> (out write + masked residual) -> inv col FFT.
__global__ __launch_bounds__(256) void fft_cols_fused(c32* __restrict__ buf,
        const c32* __restrict__ base, const c32* __restrict__ ksp,
        const int* __restrict__ mask, c32* __restrict__ outp, int write_out) {
    __shared__ c32 lds[4][257];
    __shared__ c32 tw[128];
    int tid = threadIdx.x;
    build_tw(tw, tid);
    int coil = blockIdx.y;
    c32* ip = buf + (size_t)coil * HW;
    int x0 = blockIdx.x * 4;
    int cl = tid & 3, yb = tid >> 2;
    #pragma unroll
    for (int e = 0; e < 4; ++e) {
        int y = yb + (e << 6);
        lds[cl][__brev((unsigned)y) >> 24] = ip[y * 256 + x0 + cl];
    }
    __syncthreads();
    int col = tid >> 6, j = tid & 63;
    fft256_wave(&lds[col][0], tw, j, 1.0f);
    __syncthreads();

    int x = x0 + cl;
    c32 G[4];
    #pragma unroll
    for (int e = 0; e < 4; ++e) {
        int y = yb + (e << 6);
        G[e] = lds[cl][y];
    }
    __syncthreads();
    #pragma unroll
    for (int e = 0; e < 4; ++e) {
        int y = yb + (e << 6);
        int p = y * 256 + x;
        size_t i = (size_t)coil * HW + p;
        float s = ((p ^ (p >> 8)) & 1) ? -1.0f : 1.0f;
        if (write_out) {
            c32 bv = base[i];
            float sc = s * (1.0f / 256.0f);
            outp[i] = make_float2(bv.x - sc * G[e].x, bv.y - sc * G[e].y);
        }
        c32 rv = make_float2(0.f, 0.f);
        if (mask[p]) {
            c32 k = ksp[i];
            rv = make_float2(G[e].x * (1.0f / 256.0f) - s * k.x,
                             G[e].y * (1.0f / 256.0f) - s * k.y);
        }
        lds[cl][__brev((unsigned)y) >> 24] = rv;
    }
    __syncthreads();
    fft256_wave(&lds[col][0], tw, j, -1.0f);
    __syncthreads();
    #pragma unroll
    for (int e = 0; e < 4; ++e) {
        int y = yb + (e << 6);
        ip[y * 256 + x0 + cl] = lds[cl][y];
    }
}

// ===================== pointwise kernels =====================
__global__ __launch_bounds__(256) void k_combine_eta0(const c32* __restrict__ tmp,
        const c32* __restrict__ sense, c32* __restrict__ eta) {
    int p = blockIdx.x * 256 + threadIdx.x;
    float ax = 0.f, ay = 0.f;
    for (int c = 0; c < NC; ++c) {
        c32 t = tmp[c * HW + p], s = sense[c * HW + p];
        ax += t.x * s.x + t.y * s.y;
        ay += t.y * s.x - t.x * s.y;
    }
    float sc = ssign(p) * (1.0f / 256.0f);
    eta[p] = make_float2(ax * sc, ay * sc);
}

__global__ __launch_bounds__(256) void k_base(const c32* __restrict__ ksp,
        const c32* __restrict__ pred, const int* __restrict__ mask,
        const float* __restrict__ dcw, c32* __restrict__ base) {
    int i = blockIdx.x * 256 + threadIdx.x;
    int p = i & (HW - 1);
    c32 k = ksp[i];
    c32 o = k;
    if (mask[p]) {
        float w = dcw[0];
        c32 pr = pred[i];
        o.x -= (pr.x - k.x) * w;
        o.y -= (pr.y - k.y) * w;
    }
    base[i] = o;
}

// Zero the border pixels of gTp + the 4 padded h buffers.
__global__ __launch_bounds__(256) void k_zero_border(short* __restrict__ gTp,
        short* __restrict__ h1a, short* __restrict__ h1b,
        short* __restrict__ h2a, short* __restrict__ h2b) {
    int i = blockIdx.x * 256 + threadIdx.x;
    if (i >= 2064) return;
    int y, x;
    if (i < 1040) {
        int r = i / 260;
        y = (r < 2) ? r : 256 + r;
        x = i % 260;
    } else {
        int j = i - 1040;
        y = 2 + (j >> 2);
        int cix = j & 3;
        x = (cix < 2) ? cix : 256 + cix;
    }
    size_t px = (size_t)y * P2 + x;
    ((ushort4*)gTp)[px] = make_ushort4(0, 0, 0, 0);
    uint4 z = make_uint4(0, 0, 0, 0);
    uint4* p1 = (uint4*)(h1a + (px << 6));
    uint4* p2 = (uint4*)(h1b + (px << 6));
    uint4* p3 = (uint4*)(h2a + (px << 6));
    uint4* p4 = (uint4*)(h2b + (px << 6));
    #pragma unroll
    for (int e = 0; e < 8; ++e) { p1[e] = z; p2[e] = z; p3[e] = z; p4[e] = z; }
}

// ===================== weight prep kernels =====================
__global__ __launch_bounds__(256) void k_prep_c1(const float* __restrict__ w,
        short* __restrict__ wA) {
    int i = blockIdx.x * 256 + threadIdx.x;    // 64*128
    int co = i >> 7, k = i & 127;
    int tap = k >> 2, ci = k & 3;
    float v = (tap < 25) ? w[co * 100 + ci * 25 + tap] : 0.f;
    wA[i] = f2bf(v);
}

__global__ __launch_bounds__(256) void k_prep_c2(const float* __restrict__ w,
        short* __restrict__ wA) {
    int i = blockIdx.x * 256 + threadIdx.x;     // 36864
    int tap = i >> 12, co = (i >> 6) & 63, ci = i & 63;
    wA[i] = f2bf(w[co * 576 + ci * 9 + tap]);
}

__global__ __launch_bounds__(256) void k_prep_cf(const float* __restrict__ w,
        short* __restrict__ wA) {
    int i = blockIdx.x * 256 + threadIdx.x;    // 9216
    int tap = i >> 10, r = (i >> 6) & 15, ci = i & 63;
    float v = (r < 2) ? w[r * 576 + ci * 9 + tap] : 0.f;
    wA[i] = f2bf(v);
}

__global__ __launch_bounds__(128) void k_prep_gru(const float* __restrict__ ihw,
        const float* __restrict__ ihb, const float* __restrict__ hhw,
        const float* __restrict__ hhb, short* __restrict__ w2, float* __restrict__ bias) {
    int k = threadIdx.x;
    int r = blockIdx.x;
    int g = r >> 6, co = r & 63;
    float v = 0.f;
    if (g == 0)      v = (k < 64) ? ihw[co * 64 + k]         : hhw[co * 64 + k - 64];
    else if (g == 1) v = (k < 64) ? ihw[(64 + co) * 64 + k]  : hhw[(64 + co) * 64 + k - 64];
    else if (g == 2) v = (k < 64) ? ihw[(128 + co) * 64 + k] : 0.f;
    else             v = (k < 64) ? 0.f : hhw[(128 + co) * 64 + k - 64];
    w2[r * 128 + k] = f2bf(v);
    if (k == 0) {
        float b = (g == 0) ? ihb[co] + hhb[co]
                : (g == 1) ? ihb[64 + co] + hhb[64 + co]
                : (g == 2) ? ihb[128 + co] : hhb[128 + co];
        bias[r] = b;
    }
}

// ===================== shared GRU tail (x from LDS, h from global) =========
// PX = px strip per block (32 or 64). xch: [PX][68] bf16 pad-68 layout.
template <int NTN, bool FIRST>
__device__ __forceinline__ void gru_tail(const short (*xch)[68],
        const short* __restrict__ hprev, const short* __restrict__ w2,
        const float* __restrict__ bias, short* __restrict__ hnext,
        int wv, int lr, int lg, int px0 /* global px of strip start */) {
    bf16x8 A0[4], A1[4], A2[2], A3[2];
    {
        const short* w0 = w2 + (0   + wv * 16 + lr) * 128 + lg * 8;
        const short* w1 = w2 + (64  + wv * 16 + lr) * 128 + lg * 8;
        const short* w2p = w2 + (128 + wv * 16 + lr) * 128 + lg * 8;
        const short* w3 = w2 + (192 + wv * 16 + lr) * 128 + lg * 8;
        #pragma unroll
        for (int kt = 0; kt < 4; ++kt) {
            A0[kt] = *(const bf16x8*)(w0 + kt * 32);
            A1[kt] = *(const bf16x8*)(w1 + kt * 32);
        }
        A2[0] = *(const bf16x8*)(w2p);          A2[1] = *(const bf16x8*)(w2p + 32);
        A3[0] = *(const bf16x8*)(w3 + 64);      A3[1] = *(const bf16x8*)(w3 + 96);
    }

    f32x4 C0[NTN], C1[NTN], C2[NTN], C3[NTN];
    #pragma unroll
    for (int nt = 0; nt < NTN; ++nt) {
        C0[nt] = (f32x4){0.f, 0.f, 0.f, 0.f};
        C1[nt] = (f32x4){0.f, 0.f, 0.f, 0.f};
        C2[nt] = (f32x4){0.f, 0.f, 0.f, 0.f};
        C3[nt] = (f32x4){0.f, 0.f, 0.f, 0.f};
    }

    #pragma unroll
    for (int nt = 0; nt < NTN; ++nt) {
        int pxl = nt * 16 + lr;
        int px = px0 + pxl;
        int yy = px >> 8, xx = px & 255;
        size_t pb = ((size_t)((yy + 2) * P2 + (xx + 2)) << 6);
        bf16x8 B0 = *(const bf16x8*)&xch[pxl][lg * 8];
        bf16x8 B1 = *(const bf16x8*)&xch[pxl][32 + lg * 8];
        C0[nt] = __builtin_amdgcn_mfma_f32_16x16x32_bf16(A0[0], B0, C0[nt], 0, 0, 0);
        C0[nt] = __builtin_amdgcn_mfma_f32_16x16x32_bf16(A0[1], B1, C0[nt], 0, 0, 0);
        C1[nt] = __builtin_amdgcn_mfma_f32_16x16x32_bf16(A1[0], B0, C1[nt], 0, 0, 0);
        C1[nt] = __builtin_amdgcn_mfma_f32_16x16x32_bf16(A1[1], B1, C1[nt], 0, 0, 0);
        C2[nt] = __builtin_amdgcn_mfma_f32_16x16x32_bf16(A2[0], B0, C2[nt], 0, 0, 0);
        C2[nt] = __builtin_amdgcn_mfma_f32_16x16x32_bf16(A2[1], B1, C2[nt], 0, 0, 0);
        if (!FIRST) {
            bf16x8 B2 = *(const bf16x8*)(hprev + pb + lg * 8);
            bf16x8 B3 = *(const bf16x8*)(hprev + pb + 32 + lg * 8);
            C0[nt] = __builtin_amdgcn_mfma_f32_16x16x32_bf16(A0[2], B2, C0[nt], 0, 0, 0);
            C0[nt] = __builtin_amdgcn_mfma_f32_16x16x32_bf16(A0[3], B3, C0[nt], 0, 0, 0);
            C1[nt] = __builtin_amdgcn_mfma_f32_16x16x32_bf16(A1[2], B2, C1[nt], 0, 0, 0);
            C1[nt] = __builtin_amdgcn_mfma_f32_16x16x32_bf16(A1[3], B3, C1[nt], 0, 0, 0);
            C3[nt] = __builtin_amdgcn_mfma_f32_16x16x32_bf16(A3[0], B2, C3[nt], 0, 0, 0);
            C3[nt] = __builtin_amdgcn_mfma_f32_16x16x32_bf16(A3[1], B3, C3[nt], 0, 0, 0);
        }
    }

    int co = wv * 16 + lg * 4;
    float br[4], bz[4], bin_[4], bhn[4];
    #pragma unroll
    for (int i = 0; i < 4; ++i) {
        br[i]   = bias[co + i];
        bz[i]   = bias[64 + co + i];
        bin_[i] = bias[128 + co + i];
        bhn[i]  = bias[192 + co + i];
    }
    #pragma unroll
    for (int nt = 0; nt < NTN; ++nt) {
        int px = px0 + nt * 16 + lr;
        int yy = px >> 8, xx = px & 255;
        size_t pb = ((size_t)((yy + 2) * P2 + (xx + 2)) << 6);
        ushort4 hov = make_ushort4(0, 0, 0, 0);
        if (!FIRST) hov = *(const ushort4*)(hprev + pb + co);
        float ho[4] = {bf2f(hov.x), bf2f(hov.y), bf2f(hov.z), bf2f(hov.w)};
        ushort4 st;
        unsigned short* sp = &st.x;
        #pragma unroll
        for (int i = 0; i < 4; ++i) {
            float r = 1.0f / (1.0f + expf(-(C0[nt][i] + br[i])));
            float z = 1.0f / (1.0f + expf(-(C1[nt][i] + bz[i])));
            float nn = tanhf(C2[nt][i] + bin_[i] + r * (C3[nt][i] + bhn[i]));
            float hv = FIRST ? (1.0f - z) * nn : (1.0f - z) * nn + z * ho[i];
            sp[i] = (unsigned short)f2bf(hv);
        }
        *(ushort4*)(hnext + pb + co) = st;
    }
}

// ===================== conv1 + gru1 fused =====================
// grid 2048 (y * 8 xseg), 256 thr; 32-px strip; conv out -> LDS -> GRU.
template <bool FIRST>
__global__ __launch_bounds__(256, 2) void conv1_gru1(const short* __restrict__ gTp,
        const short* __restrict__ wA, const float* __restrict__ cbias,
        const short* __restrict__ w2, const float* __restrict__ gbias,
        const short* __restrict__ hprev, short* __restrict__ hnext) {
    __shared__ short xch[32][68];
    int wv = threadIdx.x >> 6, l = threadIdx.x & 63;
    int lr = l & 15, lg = l >> 4;
    int y = blockIdx.x >> 3;
    int x0 = (blockIdx.x & 7) << 5;

    // ---- conv1 ----
    bf16x8 A[4];
    const short* pA = wA + (size_t)(wv * 16 + lr) * 128 + lg * 8;
    #pragma unroll
    for (int kt = 0; kt < 4; ++kt) A[kt] = *(const bf16x8*)(pA + kt * 32);

    bf16x8 B[2][4];
    #pragma unroll
    for (int nt = 0; nt < 2; ++nt) {
        int x = x0 + nt * 16 + lr;
        #pragma unroll
        for (int kt = 0; kt < 4; ++kt) {
            int t0 = kt * 8 + lg * 2;
            #pragma unroll
            for (int half = 0; half < 2; ++half) {
                int tap = t0 + half;
                int tt = (tap < 25) ? tap : 0;
                int dy = tt / 5 - 2, dx = tt % 5 - 2;
                ushort4 v = *(const ushort4*)(gTp +
                    ((size_t)((y + dy + 2) * P2 + (x + dx + 2)) << 2));
                B[nt][kt][half * 4 + 0] = (short)v.x;
                B[nt][kt][half * 4 + 1] = (short)v.y;
                B[nt][kt][half * 4 + 2] = (short)v.z;
                B[nt][kt][half * 4 + 3] = (short)v.w;
            }
        }
    }
    int co = wv * 16 + lg * 4;
    #pragma unroll
    for (int nt = 0; nt < 2; ++nt) {
        f32x4 C = (f32x4){0.f, 0.f, 0.f, 0.f};
        #pragma unroll
        for (int kt = 0; kt < 4; ++kt)
            C = __builtin_amdgcn_mfma_f32_16x16x32_bf16(A[kt], B[nt][kt], C, 0, 0, 0);
        ushort4 st;
        st.x = (unsigned short)f2bf(fmaxf(C[0] + cbias[co + 0], 0.f));
        st.y = (unsigned short)f2bf(fmaxf(C[1] + cbias[co + 1], 0.f));
        st.z = (unsigned short)f2bf(fmaxf(C[2] + cbias[co + 2], 0.f));
        st.w = (unsigned short)f2bf(fmaxf(C[3] + cbias[co + 3], 0.f));
        *(ushort4*)&xch[nt * 16 + lr][co] = st;
    }
    __syncthreads();

    // ---- gru1 ----
    gru_tail<2, FIRST>(xch, hprev, w2, gbias, hnext, wv, lr, lg, y * 256 + x0);
}

// ===================== conv2 + gru2 fused =====================
// grid 1024 (256 y x 4 xseg), 256 thr; 64-px strip; conv2 LDS-staged.
template <bool FIRST>
__global__ __launch_bounds__(256, 2) void conv2_gru2(const short* __restrict__ h1Tp,
        const short* __restrict__ wA, const float* __restrict__ cbias,
        const short* __restrict__ w2, const float* __restrict__ gbias,
        const short* __restrict__ hprev, short* __restrict__ hnext) {
    __shared__ uint4 Ld[3][68][9];       // 29376 B
    __shared__ short xch[64][68];        // 8704 B
    int tid = threadIdx.x;
    int wv = tid >> 6, l = tid & 63;
    int lr = l & 15, lg = l >> 4;
    int y = blockIdx.x >> 2;
    int x0 = (blockIdx.x & 3) << 6;

    for (int n = tid; n < 3 * 68 * 8; n += 256) {
        int r = n / (68 * 8);
        int rem = n - r * (68 * 8);
        int px = rem >> 3, e = rem & 7;
        const uint4* src = (const uint4*)(h1Tp +
            (((size_t)(y + 2 * r) * P2 + (x0 + px)) << 6)) + e;
        Ld[r][px][e] = *src;
    }
    __syncthreads();

    f32x4 C[4];
    #pragma unroll
    for (int nt = 0; nt < 4; ++nt) C[nt] = (f32x4){0.f, 0.f, 0.f, 0.f};

    #pragma unroll
    for (int tap = 0; tap < 9; ++tap) {
        int r = tap / 3;
        int dx = (tap % 3 - 1) * 2;
        const short* pA = wA + (size_t)(tap * 64 + wv * 16 + lr) * 64 + lg * 8;
        bf16x8 A0 = *(const bf16x8*)(pA);
        bf16x8 A1 = *(const bf16x8*)(pA + 32);
        #pragma unroll
        for (int nt = 0; nt < 4; ++nt) {
            int xl = nt * 16 + lr + dx + 2;
            bf16x8 B0 = *(const bf16x8*)&Ld[r][xl][lg];
            bf16x8 B1 = *(const bf16x8*)&Ld[r][xl][4 + lg];
            C[nt] = __builtin_amdgcn_mfma_f32_16x16x32_bf16(A0, B0, C[nt], 0, 0, 0);
            C[nt] = __builtin_amdgcn_mfma_f32_16x16x32_bf16(A1, B1, C[nt], 0, 0, 0);
        }
    }
    int co = wv * 16 + lg * 4;
    #pragma unroll
    for (int nt = 0; nt < 4; ++nt) {
        ushort4 st;
        st.x = (unsigned short)f2bf(fmaxf(C[nt][0] + cbias[co + 0], 0.f));
        st.y = (unsigned short)f2bf(fmaxf(C[nt][1] + cbias[co + 1], 0.f));
        st.z = (unsigned short)f2bf(fmaxf(C[nt][2] + cbias[co + 2], 0.f));
        st.w = (unsigned short)f2bf(fmaxf(C[nt][3] + cbias[co + 3], 0.f));
        *(ushort4*)&xch[nt * 16 + lr][co] = st;
    }
    __syncthreads();

    // ---- gru2 ----
    gru_tail<4, FIRST>(xch, hprev, w2, gbias, hnext, wv, lr, lg, y * 256 + x0);
}

// ===================== final conv via MFMA (padded, prefetch) ==============
__global__ __launch_bounds__(256, 2) void final_mfma(const short* __restrict__ hTp,
        const short* __restrict__ wA, c32* __restrict__ eta) {
    int wv = threadIdx.x >> 6, l = threadIdx.x & 63;
    int lr = l & 15, lg = l >> 4;
    int y = blockIdx.x >> 2;
    int x0 = (blockIdx.x & 3) << 6;
    int x = x0 + wv * 16 + lr;

    auto loadB = [&](int tap, bf16x8& b0, bf16x8& b1) {
        int dy = tap / 3 - 1, dx = tap % 3 - 1;
        const short* pB = hTp +
            ((size_t)((y + dy + 2) * P2 + (x + dx + 2)) << 6) + lg * 8;
        b0 = *(const bf16x8*)(pB);
        b1 = *(const bf16x8*)(pB + 32);
    };

    f32x4 C = (f32x4){0.f, 0.f, 0.f, 0.f};
    bf16x8 cB0, cB1;
    loadB(0, cB0, cB1);
    #pragma unroll
    for (int tap = 0; tap < 9; ++tap) {
        const short* pA = wA + (size_t)(tap * 16 + lr) * 64 + lg * 8;
        bf16x8 A0 = *(const bf16x8*)(pA);
        bf16x8 A1 = *(const bf16x8*)(pA + 32);
        bf16x8 nB0, nB1;
        if (tap < 8) loadB(tap + 1, nB0, nB1);
        C = __builtin_amdgcn_mfma_f32_16x16x32_bf16(A0, cB0, C, 0, 0, 0);
        C = __builtin_amdgcn_mfma_f32_16x16x32_bf16(A1, cB1, C, 0, 0, 0);
        if (tap < 8) { cB0 = nB0; cB1 = nB1; }
    }
    if (lg == 0) {
        int px = y * 256 + x;
        c32 e = eta[px];
        eta[px] = make_float2(e.x + C[0], e.y + C[1]);
    }
}

// ===================== host orchestration =====================
extern "C" void kernel_launch(void* const* d_in, const int* in_sizes, int n_in,
                              void* d_out, int out_size, void* d_ws, size_t ws_size,
                              hipStream_t stream) {
    const c32* pred   = (const c32*)d_in[0];
    const c32* ksp    = (const c32*)d_in[1];
    const c32* sense  = (const c32*)d_in[2];
    const int* mask   = (const int*)d_in[3];
    const float* c1w  = (const float*)d_in[4];
    const float* c1b  = (const float*)d_in[5];
    const float* g1iw = (const float*)d_in[6];
    const float* g1ib = (const float*)d_in[7];
    const float* g1hw = (const float*)d_in[8];
    const float* g1hb = (const float*)d_in[9];
    const float* c2w  = (const float*)d_in[10];
    const float* c2b  = (const float*)d_in[11];
    const float* g2iw = (const float*)d_in[12];
    const float* g2ib = (const float*)d_in[13];
    const float* g2hw = (const float*)d_in[14];
    const float* g2hb = (const float*)d_in[15];
    const float* fw   = (const float*)d_in[16];
    const float* dcw  = (const float*)d_in[17];

    const size_t PP = (size_t)P2 * P2;     // 67600 padded pixels
    float* w0 = (float*)d_ws;
    c32* base = (c32*)w0;                  // NC*HW complex
    c32* Fk   = base + NC * HW;            // NC*HW complex
    c32* tmp  = Fk + NC * HW;              // NC*HW complex (init only)
    c32* eta  = tmp + NC * HW;             // HW complex
    short* gTp = (short*)(eta + HW);       // PP*4 bf16 (padded)
    short* h1Ta = gTp + PP * 4;            // PP*64 bf16 (padded)
    short* h1Tb = h1Ta + PP * 64;
    short* h2Ta = h1Tb + PP * 64;
    short* h2Tb = h2Ta + PP * 64;
    short* w2a  = h2Tb + PP * 64;          // 256*128 bf16
    short* w2b  = w2a + 256 * 128;
    float* biasA = (float*)(w2b + 256 * 128);
    float* biasB = biasA + 256;
    short* wAc2 = (short*)(biasB + 256);   // 9*64*64 bf16
    short* wAc1 = wAc2 + 9 * 64 * 64;      // 64*128 bf16
    short* wAcf = wAc1 + 64 * 128;         // 9*16*64 bf16

    dim3 B(256);
    const int gCHW = NC * HW / 256;   // 3072
    const int gHW  = HW / 256;        // 256
    const int gROW = NC * 256 / 4;    // 768
    dim3 gCOL(64, NC);
    const int gC1 = HW / 32;          // 2048 blocks (conv1+gru1)
    const int gC2 = HW / 64;          // 1024 blocks (conv2+gru2, final)

    // border zeroing + weight prep (once per call)
    k_zero_border<<<9, B, 0, stream>>>(gTp, h1Ta, h1Tb, h2Ta, h2Tb);
    k_prep_gru<<<256, 128, 0, stream>>>(g1iw, g1ib, g1hw, g1hb, w2a, biasA);
    k_prep_gru<<<256, 128, 0, stream>>>(g2iw, g2ib, g2hw, g2hb, w2b, biasB);
    k_prep_c2<<<144, 256, 0, stream>>>(c2w, wAc2);
    k_prep_c1<<<32, 256, 0, stream>>>(c1w, wAc1);
    k_prep_cf<<<36, 256, 0, stream>>>(fw, wAcf);

    // eta0 = sum_c ifft2c(pred_c) * conj(sense_c)
    fft_rows_pre<<<gROW, B, 0, stream>>>(tmp, pred);
    fft_cols<<<gCOL, B, 0, stream>>>(tmp, -1.0f);
    k_combine_eta0<<<gHW, B, 0, stream>>>(tmp, sense, eta);

    k_base<<<gCHW, B, 0, stream>>>(ksp, pred, mask, dcw, base);

    // F_0: forward FFT of S*(eta0*sense); fused epilogue -> residual (no out)
    fft_rows_exp<<<gROW, B, 0, stream>>>(Fk, eta, sense);
    fft_cols_fused<<<gCOL, B, 0, stream>>>(Fk, base, ksp, mask, (c32*)d_out, 0);

    short* h1c = h1Ta; short* h1n = h1Tb;
    short* h2c = h2Ta; short* h2n = h2Tb;
    c32* outp = (c32*)d_out;

    for (int t = 0; t < NT; ++t) {
        fft_rows_grad<<<gHW, B, 0, stream>>>(Fk, sense, eta, gTp);

        if (t == 0) {
            conv1_gru1<true><<<gC1, B, 0, stream>>>(gTp, wAc1, c1b, w2a, biasA, h1c, h1n);
        } else {
            conv1_gru1<false><<<gC1, B, 0, stream>>>(gTp, wAc1, c1b, w2a, biasA, h1c, h1n);
        }
        { short* s = h1c; h1c = h1n; h1n = s; }
        if (t == 0) {
            conv2_gru2<true><<<gC2, B, 0, stream>>>(h1c, wAc2, c2b, w2b, biasB, h2c, h2n);
        } else {
            conv2_gru2<false><<<gC2, B, 0, stream>>>(h1c, wAc2, c2b, w2b, biasB, h2c, h2n);
        }
        { short* s = h2c; h2c = h2n; h2n = s; }
        final_mfma<<<gC2, B, 0, stream>>>(h2c, wAcf, eta);

        fft_rows_exp<<<gROW, B, 0, stream>>>(Fk, eta, sense);
        fft_cols_fused<<<gCOL, B, 0, stream>>>(Fk, base, ksp, mask,
                                               outp + (size_t)t * NC * HW, 1);
    }
}

// Round 15
// 900.503 us; speedup vs baseline: 1.5693x; 1.0196x over previous
//
#include <hip/hip_runtime.h>

#define HW 65536
#define NC 12
#define NF 64
#define NT 8
#define P2 260   // padded pitch (2-wide zero border each side)

typedef float2 c32;
typedef __attribute__((ext_vector_type(8))) short bf16x8;   // 8 bf16 = 4 VGPR
typedef __attribute__((ext_vector_type(4))) float f32x4;    // MFMA C/D

__device__ __forceinline__ float ssign(int p) {
    return ((p ^ (p >> 8)) & 1) ? -1.0f : 1.0f;
}

__device__ __forceinline__ short f2bf(float f) {   // RNE float->bf16
    union { float f; unsigned u; } v; v.f = f;
    unsigned r = (v.u + 0x7FFFu + ((v.u >> 16) & 1u)) >> 16;
    return (short)r;
}

__device__ __forceinline__ float bf2f(unsigned short u) {
    union { unsigned u; float f; } v; v.u = (unsigned)u << 16;
    return v.f;
}

// ===================== 256-point FFT, wave-synchronous, fused stage-pairs ===
// Two radix-2 stages per LDS round-trip (radix-4 dataflow, radix-2 math —
// bit-identical to the 8-stage version). 4 syncs instead of 8.
__device__ __forceinline__ void wave_sync() {
    asm volatile("s_waitcnt lgkmcnt(0)" ::: "memory");
}

__device__ __forceinline__ void fft256_wave(c32* X, const c32* tw, int j, float conjf) {
    #pragma unroll
    for (int s = 1; s <= 8; s += 2) {
        const int H = 1 << (s - 1);
        int p = j & (H - 1);
        int r = j >> (s - 1);
        int i0 = r * 4 * H + p;
        c32 e0 = X[i0], e1 = X[i0 + H], e2 = X[i0 + 2 * H], e3 = X[i0 + 3 * H];
        // stage s: pairs (e0,e1),(e2,e3), twiddle tw[p<<(8-s)]
        c32 w = tw[p << (8 - s)];
        float wy = conjf * w.y;
        c32 t = make_float2(w.x * e1.x - wy * e1.y, w.x * e1.y + wy * e1.x);
        c32 a0 = make_float2(e0.x + t.x, e0.y + t.y);
        c32 a1 = make_float2(e0.x - t.x, e0.y - t.y);
        t = make_float2(w.x * e3.x - wy * e3.y, w.x * e3.y + wy * e3.x);
        c32 a2 = make_float2(e2.x + t.x, e2.y + t.y);
        c32 a3 = make_float2(e2.x - t.x, e2.y - t.y);
        // stage s+1: pairs (a0,a2) pos=p, (a1,a3) pos=p+H, twiddles <<(7-s)
        c32 w0 = tw[p << (7 - s)];
        c32 w1 = tw[(p + H) << (7 - s)];
        float w0y = conjf * w0.y, w1y = conjf * w1.y;
        t = make_float2(w0.x * a2.x - w0y * a2.y, w0.x * a2.y + w0y * a2.x);
        X[i0]         = make_float2(a0.x + t.x, a0.y + t.y);
        X[i0 + 2 * H] = make_float2(a0.x - t.x, a0.y - t.y);
        t = make_float2(w1.x * a3.x - w1y * a3.y, w1.x * a3.y + w1y * a3.x);
        X[i0 + H]     = make_float2(a1.x + t.x, a1.y + t.y);
        X[i0 + 3 * H] = make_float2(a1.x - t.x, a1.y - t.y);
        wave_sync();
    }
}

__device__ __forceinline__ void build_tw(c32* tw, int tid) {
    if (tid < 128) {
        float a = -3.14159265358979323846f * (float)tid * (1.0f / 128.0f);
        float sv, cv;
        sincosf(a, &sv, &cv);
        tw[tid] = make_float2(cv, sv);
    }
}

__global__ __launch_bounds__(256) void fft_rows_pre(c32* __restrict__ buf,
        const c32* __restrict__ pred) {
    __shared__ c32 lds[4][256];
    __shared__ c32 tw[128];
    int tid = threadIdx.x;
    build_tw(tw, tid);
    int wid = tid >> 6, j = tid & 63;
    int r = blockIdx.x * 4 + wid;
    int coil = r >> 8, y = r & 255;
    c32* rp = buf + (size_t)r * 256;
    c32* X = lds[wid];
    #pragma unroll
    for (int e = 0; e < 4; ++e) {
        int n = (e << 6) + j;
        float s = ((n + y) & 1) ? -1.0f : 1.0f;
        c32 pv = pred[(size_t)coil * HW + y * 256 + n];
        X[__brev((unsigned)n) >> 24] = make_float2(s * pv.x, s * pv.y);
    }
    __syncthreads();
    fft256_wave(X, tw, j, -1.0f);
    #pragma unroll
    for (int e = 0; e < 4; ++e) {
        int n = (e << 6) + j;
        rp[n] = X[n];
    }
}

__global__ __launch_bounds__(256) void fft_rows_exp(c32* __restrict__ buf,
        const c32* __restrict__ eta, const c32* __restrict__ sense) {
    __shared__ c32 lds[4][256];
    __shared__ c32 tw[128];
    int tid = threadIdx.x;
    build_tw(tw, tid);
    int wid = tid >> 6, j = tid & 63;
    int r = blockIdx.x * 4 + wid;
    int coil = r >> 8, y = r & 255;
    c32* rp = buf + (size_t)r * 256;
    c32* X = lds[wid];
    #pragma unroll
    for (int e = 0; e < 4; ++e) {
        int n = (e << 6) + j;
        float s = ((n + y) & 1) ? -1.0f : 1.0f;
        c32 ev = eta[y * 256 + n];
        c32 sn = sense[(size_t)coil * HW + y * 256 + n];
        X[__brev((unsigned)n) >> 24] =
            make_float2(s * (ev.x * sn.x - ev.y * sn.y),
                        s * (ev.x * sn.y + ev.y * sn.x));
    }
    __syncthreads();
    fft256_wave(X, tw, j, 1.0f);
    #pragma unroll
    for (int e = 0; e < 4; ++e) {
        int n = (e << 6) + j;
        rp[n] = X[n];
    }
}

// Merged: row-inverse FFT of all 12 coils of row y + coil-combine + g emit.
__global__ __launch_bounds__(256) void fft_rows_grad(const c32* __restrict__ Fk,
        const c32* __restrict__ sense, const c32* __restrict__ eta,
        short* __restrict__ gTp) {
    __shared__ c32 lds[12][256];     // 24 KB
    __shared__ c32 tw[128];
    int tid = threadIdx.x;
    build_tw(tw, tid);
    int wid = tid >> 6, j = tid & 63;
    int y = blockIdx.x;
    #pragma unroll
    for (int cc = 0; cc < 3; ++cc) {
        int c = wid * 3 + cc;
        const c32* rp = Fk + (size_t)c * HW + y * 256;
        #pragma unroll
        for (int e = 0; e < 4; ++e) {
            int n = (e << 6) + j;
            lds[c][__brev((unsigned)n) >> 24] = rp[n];
        }
    }
    __syncthreads();
    #pragma unroll
    for (int cc = 0; cc < 3; ++cc)
        fft256_wave(&lds[wid * 3 + cc][0], tw, j, -1.0f);
    __syncthreads();
    int x = tid;
    int p = y * 256 + x;
    float ax = 0.f, ay = 0.f;
    #pragma unroll
    for (int c = 0; c < NC; ++c) {
        c32 t = lds[c][x];
        c32 s = sense[(size_t)c * HW + p];
        ax += t.x * s.x + t.y * s.y;
        ay += t.y * s.x - t.x * s.y;
    }
    float sc = (((x + y) & 1) ? -1.0f : 1.0f) * (1.0f / 256.0f);
    c32 e = eta[p];
    ushort4 o;
    o.x = (unsigned short)f2bf(e.x);
    o.y = (unsigned short)f2bf(e.y);
    o.z = (unsigned short)f2bf(ax * sc);
    o.w = (unsigned short)f2bf(ay * sc);
    ((ushort4*)gTp)[(y + 2) * P2 + x + 2] = o;
}

__global__ __launch_bounds__(256) void fft_cols(c32* __restrict__ buf, float conjf) {
    __shared__ c32 lds[4][257];
    __shared__ c32 tw[128];
    int tid = threadIdx.x;
    build_tw(tw, tid);
    c32* ip = buf + (size_t)blockIdx.y * HW;
    int x0 = blockIdx.x * 4;
    int cl = tid & 3, yb = tid >> 2;
    #pragma unroll
    for (int e = 0; e < 4; ++e) {
        int y = yb + (e << 6);
        lds[cl][__brev((unsigned)y) >> 24] = ip[y * 256 + x0 + cl];
    }
    __syncthreads();
    int col = tid >> 6, j = tid & 63;
    fft256_wave(&lds[col][0], tw, j, conjf);
    __syncthreads();
    #pragma unroll
    for (int e = 0; e < 4; ++e) {
        int y = yb + (e << 6);
        ip[y * 256 + x0 + cl] = lds[cl][y];
    }
}

// Fused: fwd col FFT -> (out write + masked residual) -> inv col FFT.
__global__ __launch_bounds__(256) void fft_cols_fused(c32* __restrict__ buf,
        const c32* __restrict__ base, const c32* __restrict__ ksp,
        const int* __restrict__ mask, c32* __restrict__ outp, int write_out) {
    __shared__ c32 lds[4][257];
    __shared__ c32 tw[128];
    int tid = threadIdx.x;
    build_tw(tw, tid);
    int coil = blockIdx.y;
    c32* ip = buf + (size_t)coil * HW;
    int x0 = blockIdx.x * 4;
    int cl = tid & 3, yb = tid >> 2;
    #pragma unroll
    for (int e = 0; e < 4; ++e) {
        int y = yb + (e << 6);
        lds[cl][__brev((unsigned)y) >> 24] = ip[y * 256 + x0 + cl];
    }
    __syncthreads();
    int col = tid >> 6, j = tid & 63;
    fft256_wave(&lds[col][0], tw, j, 1.0f);
    __syncthreads();

    int x = x0 + cl;
    c32 G[4];
    #pragma unroll
    for (int e = 0; e < 4; ++e) {
        int y = yb + (e << 6);
        G[e] = lds[cl][y];
    }
    __syncthreads();
    #pragma unroll
    for (int e = 0; e < 4; ++e) {
        int y = yb + (e << 6);
        int p = y * 256 + x;
        size_t i = (size_t)coil * HW + p;
        float s = ((p ^ (p >> 8)) & 1) ? -1.0f : 1.0f;
        if (write_out) {
            c32 bv = base[i];
            float sc = s * (1.0f / 256.0f);
            outp[i] = make_float2(bv.x - sc * G[e].x, bv.y - sc * G[e].y);
        }
        c32 rv = make_float2(0.f, 0.f);
        if (mask[p]) {
            c32 k = ksp[i];
            rv = make_float2(G[e].x * (1.0f / 256.0f) - s * k.x,
                             G[e].y * (1.0f / 256.0f) - s * k.y);
        }
        lds[cl][__brev((unsigned)y) >> 24] = rv;
    }
    __syncthreads();
    fft256_wave(&lds[col][0], tw, j, -1.0f);
    __syncthreads();
    #pragma unroll
    for (int e = 0; e < 4; ++e) {
        int y = yb + (e << 6);
        ip[y * 256 + x0 + cl] = lds[cl][y];
    }
}

// ===================== pointwise kernels =====================
__global__ __launch_bounds__(256) void k_combine_eta0(const c32* __restrict__ tmp,
        const c32* __restrict__ sense, c32* __restrict__ eta) {
    int p = blockIdx.x * 256 + threadIdx.x;
    float ax = 0.f, ay = 0.f;
    for (int c = 0; c < NC; ++c) {
        c32 t = tmp[c * HW + p], s = sense[c * HW + p];
        ax += t.x * s.x + t.y * s.y;
        ay += t.y * s.x - t.x * s.y;
    }
    float sc = ssign(p) * (1.0f / 256.0f);
    eta[p] = make_float2(ax * sc, ay * sc);
}

__global__ __launch_bounds__(256) void k_base(const c32* __restrict__ ksp,
        const c32* __restrict__ pred, const int* __restrict__ mask,
        const float* __restrict__ dcw, c32* __restrict__ base) {
    int i = blockIdx.x * 256 + threadIdx.x;
    int p = i & (HW - 1);
    c32 k = ksp[i];
    c32 o = k;
    if (mask[p]) {
        float w = dcw[0];
        c32 pr = pred[i];
        o.x -= (pr.x - k.x) * w;
        o.y -= (pr.y - k.y) * w;
    }
    base[i] = o;
}

// Zero the border pixels of gTp + the 4 padded h buffers.
__global__ __launch_bounds__(256) void k_zero_border(short* __restrict__ gTp,
        short* __restrict__ h1a, short* __restrict__ h1b,
        short* __restrict__ h2a, short* __restrict__ h2b) {
    int i = blockIdx.x * 256 + threadIdx.x;
    if (i >= 2064) return;
    int y, x;
    if (i < 1040) {
        int r = i / 260;
        y = (r < 2) ? r : 256 + r;
        x = i % 260;
    } else {
        int j = i - 1040;
        y = 2 + (j >> 2);
        int cix = j & 3;
        x = (cix < 2) ? cix : 256 + cix;
    }
    size_t px = (size_t)y * P2 + x;
    ((ushort4*)gTp)[px] = make_ushort4(0, 0, 0, 0);
    uint4 z = make_uint4(0, 0, 0, 0);
    uint4* p1 = (uint4*)(h1a + (px << 6));
    uint4* p2 = (uint4*)(h1b + (px << 6));
    uint4* p3 = (uint4*)(h2a + (px << 6));
    uint4* p4 = (uint4*)(h2b + (px << 6));
    #pragma unroll
    for (int e = 0; e < 8; ++e) { p1[e] = z; p2[e] = z; p3[e] = z; p4[e] = z; }
}

// ===================== weight prep kernels =====================
__global__ __launch_bounds__(256) void k_prep_c1(const float* __restrict__ w,
        short* __restrict__ wA) {
    int i = blockIdx.x * 256 + threadIdx.x;    // 64*128
    int co = i >> 7, k = i & 127;
    int tap = k >> 2, ci = k & 3;
    float v = (tap < 25) ? w[co * 100 + ci * 25 + tap] : 0.f;
    wA[i] = f2bf(v);
}

__global__ __launch_bounds__(256) void k_prep_c2(const float* __restrict__ w,
        short* __restrict__ wA) {
    int i = blockIdx.x * 256 + threadIdx.x;     // 36864
    int tap = i >> 12, co = (i >> 6) & 63, ci = i & 63;
    wA[i] = f2bf(w[co * 576 + ci * 9 + tap]);
}

__global__ __launch_bounds__(256) void k_prep_cf(const float* __restrict__ w,
        short* __restrict__ wA) {
    int i = blockIdx.x * 256 + threadIdx.x;    // 9216
    int tap = i >> 10, r = (i >> 6) & 15, ci = i & 63;
    float v = (r < 2) ? w[r * 576 + ci * 9 + tap] : 0.f;
    wA[i] = f2bf(v);
}

__global__ __launch_bounds__(128) void k_prep_gru(const float* __restrict__ ihw,
        const float* __restrict__ ihb, const float* __restrict__ hhw,
        const float* __restrict__ hhb, short* __restrict__ w2, float* __restrict__ bias) {
    int k = threadIdx.x;
    int r = blockIdx.x;
    int g = r >> 6, co = r & 63;
    float v = 0.f;
    if (g == 0)      v = (k < 64) ? ihw[co * 64 + k]         : hhw[co * 64 + k - 64];
    else if (g == 1) v = (k < 64) ? ihw[(64 + co) * 64 + k]  : hhw[(64 + co) * 64 + k - 64];
    else if (g == 2) v = (k < 64) ? ihw[(128 + co) * 64 + k] : 0.f;
    else             v = (k < 64) ? 0.f : hhw[(128 + co) * 64 + k - 64];
    w2[r * 128 + k] = f2bf(v);
    if (k == 0) {
        float b = (g == 0) ? ihb[co] + hhb[co]
                : (g == 1) ? ihb[64 + co] + hhb[64 + co]
                : (g == 2) ? ihb[128 + co] : hhb[128 + co];
        bias[r] = b;
    }
}

// ===================== shared GRU tail (x from LDS, h from global) =========
template <int NTN, bool FIRST>
__device__ __forceinline__ void gru_tail(const short (*xch)[68],
        const short* __restrict__ hprev, const short* __restrict__ w2,
        const float* __restrict__ bias, short* __restrict__ hnext,
        int wv, int lr, int lg, int px0) {
    bf16x8 A0[4], A1[4], A2[2], A3[2];
    {
        const short* w0 = w2 + (0   + wv * 16 + lr) * 128 + lg * 8;
        const short* w1 = w2 + (64  + wv * 16 + lr) * 128 + lg * 8;
        const short* w2p = w2 + (128 + wv * 16 + lr) * 128 + lg * 8;
        const short* w3 = w2 + (192 + wv * 16 + lr) * 128 + lg * 8;
        #pragma unroll
        for (int kt = 0; kt < 4; ++kt) {
            A0[kt] = *(const bf16x8*)(w0 + kt * 32);
            A1[kt] = *(const bf16x8*)(w1 + kt * 32);
        }
        A2[0] = *(const bf16x8*)(w2p);          A2[1] = *(const bf16x8*)(w2p + 32);
        A3[0] = *(const bf16x8*)(w3 + 64);      A3[1] = *(const bf16x8*)(w3 + 96);
    }

    f32x4 C0[NTN], C1[NTN], C2[NTN], C3[NTN];
    #pragma unroll
    for (int nt = 0; nt < NTN; ++nt) {
        C0[nt] = (f32x4){0.f, 0.f, 0.f, 0.f};
        C1[nt] = (f32x4){0.f, 0.f, 0.f, 0.f};
        C2[nt] = (f32x4){0.f, 0.f, 0.f, 0.f};
        C3[nt] = (f32x4){0.f, 0.f, 0.f, 0.f};
    }

    #pragma unroll
    for (int nt = 0; nt < NTN; ++nt) {
        int pxl = nt * 16 + lr;
        int px = px0 + pxl;
        int yy = px >> 8, xx = px & 255;
        size_t pb = ((size_t)((yy + 2) * P2 + (xx + 2)) << 6);
        bf16x8 B0 = *(const bf16x8*)&xch[pxl][lg * 8];
        bf16x8 B1 = *(const bf16x8*)&xch[pxl][32 + lg * 8];
        C0[nt] = __builtin_amdgcn_mfma_f32_16x16x32_bf16(A0[0], B0, C0[nt], 0, 0, 0);
        C0[nt] = __builtin_amdgcn_mfma_f32_16x16x32_bf16(A0[1], B1, C0[nt], 0, 0, 0);
        C1[nt] = __builtin_amdgcn_mfma_f32_16x16x32_bf16(A1[0], B0, C1[nt], 0, 0, 0);
        C1[nt] = __builtin_amdgcn_mfma_f32_16x16x32_bf16(A1[1], B1, C1[nt], 0, 0, 0);
        C2[nt] = __builtin_amdgcn_mfma_f32_16x16x32_bf16(A2[0], B0, C2[nt], 0, 0, 0);
        C2[nt] = __builtin_amdgcn_mfma_f32_16x16x32_bf16(A2[1], B1, C2[nt], 0, 0, 0);
        if (!FIRST) {
            bf16x8 B2 = *(const bf16x8*)(hprev + pb + lg * 8);
            bf16x8 B3 = *(const bf16x8*)(hprev + pb + 32 + lg * 8);
            C0[nt] = __builtin_amdgcn_mfma_f32_16x16x32_bf16(A0[2], B2, C0[nt], 0, 0, 0);
            C0[nt] = __builtin_amdgcn_mfma_f32_16x16x32_bf16(A0[3], B3, C0[nt], 0, 0, 0);
            C1[nt] = __builtin_amdgcn_mfma_f32_16x16x32_bf16(A1[2], B2, C1[nt], 0, 0, 0);
            C1[nt] = __builtin_amdgcn_mfma_f32_16x16x32_bf16(A1[3], B3, C1[nt], 0, 0, 0);
            C3[nt] = __builtin_amdgcn_mfma_f32_16x16x32_bf16(A3[0], B2, C3[nt], 0, 0, 0);
            C3[nt] = __builtin_amdgcn_mfma_f32_16x16x32_bf16(A3[1], B3, C3[nt], 0, 0, 0);
        }
    }

    int co = wv * 16 + lg * 4;
    float br[4], bz[4], bin_[4], bhn[4];
    #pragma unroll
    for (int i = 0; i < 4; ++i) {
        br[i]   = bias[co + i];
        bz[i]   = bias[64 + co + i];
        bin_[i] = bias[128 + co + i];
        bhn[i]  = bias[192 + co + i];
    }
    #pragma unroll
    for (int nt = 0; nt < NTN; ++nt) {
        int px = px0 + nt * 16 + lr;
        int yy = px >> 8, xx = px & 255;
        size_t pb = ((size_t)((yy + 2) * P2 + (xx + 2)) << 6);
        ushort4 hov = make_ushort4(0, 0, 0, 0);
        if (!FIRST) hov = *(const ushort4*)(hprev + pb + co);
        float ho[4] = {bf2f(hov.x), bf2f(hov.y), bf2f(hov.z), bf2f(hov.w)};
        ushort4 st;
        unsigned short* sp = &st.x;
        #pragma unroll
        for (int i = 0; i < 4; ++i) {
            float r = 1.0f / (1.0f + expf(-(C0[nt][i] + br[i])));
            float z = 1.0f / (1.0f + expf(-(C1[nt][i] + bz[i])));
            float nn = tanhf(C2[nt][i] + bin_[i] + r * (C3[nt][i] + bhn[i]));
            float hv = FIRST ? (1.0f - z) * nn : (1.0f - z) * nn + z * ho[i];
            sp[i] = (unsigned short)f2bf(hv);
        }
        *(ushort4*)(hnext + pb + co) = st;
    }
}

// ===================== conv1 + gru1 fused =====================
template <bool FIRST>
__global__ __launch_bounds__(256, 2) void conv1_gru1(const short* __restrict__ gTp,
        const short* __restrict__ wA, const float* __restrict__ cbias,
        const short* __restrict__ w2, const float* __restrict__ gbias,
        const short* __restrict__ hprev, short* __restrict__ hnext) {
    __shared__ short xch[32][68];
    int wv = threadIdx.x >> 6, l = threadIdx.x & 63;
    int lr = l & 15, lg = l >> 4;
    int y = blockIdx.x >> 3;
    int x0 = (blockIdx.x & 7) << 5;

    bf16x8 A[4];
    const short* pA = wA + (size_t)(wv * 16 + lr) * 128 + lg * 8;
    #pragma unroll
    for (int kt = 0; kt < 4; ++kt) A[kt] = *(const bf16x8*)(pA + kt * 32);

    bf16x8 B[2][4];
    #pragma unroll
    for (int nt = 0; nt < 2; ++nt) {
        int x = x0 + nt * 16 + lr;
        #pragma unroll
        for (int kt = 0; kt < 4; ++kt) {
            int t0 = kt * 8 + lg * 2;
            #pragma unroll
            for (int half = 0; half < 2; ++half) {
                int tap = t0 + half;
                int tt = (tap < 25) ? tap : 0;
                int dy = tt / 5 - 2, dx = tt % 5 - 2;
                ushort4 v = *(const ushort4*)(gTp +
                    ((size_t)((y + dy + 2) * P2 + (x + dx + 2)) << 2));
                B[nt][kt][half * 4 + 0] = (short)v.x;
                B[nt][kt][half * 4 + 1] = (short)v.y;
                B[nt][kt][half * 4 + 2] = (short)v.z;
                B[nt][kt][half * 4 + 3] = (short)v.w;
            }
        }
    }
    int co = wv * 16 + lg * 4;
    #pragma unroll
    for (int nt = 0; nt < 2; ++nt) {
        f32x4 C = (f32x4){0.f, 0.f, 0.f, 0.f};
        #pragma unroll
        for (int kt = 0; kt < 4; ++kt)
            C = __builtin_amdgcn_mfma_f32_16x16x32_bf16(A[kt], B[nt][kt], C, 0, 0, 0);
        ushort4 st;
        st.x = (unsigned short)f2bf(fmaxf(C[0] + cbias[co + 0], 0.f));
        st.y = (unsigned short)f2bf(fmaxf(C[1] + cbias[co + 1], 0.f));
        st.z = (unsigned short)f2bf(fmaxf(C[2] + cbias[co + 2], 0.f));
        st.w = (unsigned short)f2bf(fmaxf(C[3] + cbias[co + 3], 0.f));
        *(ushort4*)&xch[nt * 16 + lr][co] = st;
    }
    __syncthreads();

    gru_tail<2, FIRST>(xch, hprev, w2, gbias, hnext, wv, lr, lg, y * 256 + x0);
}

// ===================== conv2 + gru2 fused =====================
template <bool FIRST>
__global__ __launch_bounds__(256, 2) void conv2_gru2(const short* __restrict__ h1Tp,
        const short* __restrict__ wA, const float* __restrict__ cbias,
        const short* __restrict__ w2, const float* __restrict__ gbias,
        const short* __restrict__ hprev, short* __restrict__ hnext) {
    __shared__ uint4 Ld[3][68][9];       // 29376 B
    __shared__ short xch[64][68];        // 8704 B
    int tid = threadIdx.x;
    int wv = tid >> 6, l = tid & 63;
    int lr = l & 15, lg = l >> 4;
    int y = blockIdx.x >> 2;
    int x0 = (blockIdx.x & 3) << 6;

    for (int n = tid; n < 3 * 68 * 8; n += 256) {
        int r = n / (68 * 8);
        int rem = n - r * (68 * 8);
        int px = rem >> 3, e = rem & 7;
        const uint4* src = (const uint4*)(h1Tp +
            (((size_t)(y + 2 * r) * P2 + (x0 + px)) << 6)) + e;
        Ld[r][px][e] = *src;
    }
    __syncthreads();

    f32x4 C[4];
    #pragma unroll
    for (int nt = 0; nt < 4; ++nt) C[nt] = (f32x4){0.f, 0.f, 0.f, 0.f};

    #pragma unroll
    for (int tap = 0; tap < 9; ++tap) {
        int r = tap / 3;
        int dx = (tap % 3 - 1) * 2;
        const short* pA = wA + (size_t)(tap * 64 + wv * 16 + lr) * 64 + lg * 8;
        bf16x8 A0 = *(const bf16x8*)(pA);
        bf16x8 A1 = *(const bf16x8*)(pA + 32);
        #pragma unroll
        for (int nt = 0; nt < 4; ++nt) {
            int xl = nt * 16 + lr + dx + 2;
            bf16x8 B0 = *(const bf16x8*)&Ld[r][xl][lg];
            bf16x8 B1 = *(const bf16x8*)&Ld[r][xl][4 + lg];
            C[nt] = __builtin_amdgcn_mfma_f32_16x16x32_bf16(A0, B0, C[nt], 0, 0, 0);
            C[nt] = __builtin_amdgcn_mfma_f32_16x16x32_bf16(A1, B1, C[nt], 0, 0, 0);
        }
    }
    int co = wv * 16 + lg * 4;
    #pragma unroll
    for (int nt = 0; nt < 4; ++nt) {
        ushort4 st;
        st.x = (unsigned short)f2bf(fmaxf(C[nt][0] + cbias[co + 0], 0.f));
        st.y = (unsigned short)f2bf(fmaxf(C[nt][1] + cbias[co + 1], 0.f));
        st.z = (unsigned short)f2bf(fmaxf(C[nt][2] + cbias[co + 2], 0.f));
        st.w = (unsigned short)f2bf(fmaxf(C[nt][3] + cbias[co + 3], 0.f));
        *(ushort4*)&xch[nt * 16 + lr][co] = st;
    }
    __syncthreads();

    gru_tail<4, FIRST>(xch, hprev, w2, gbias, hnext, wv, lr, lg, y * 256 + x0);
}

// ===================== final conv via MFMA (padded, prefetch) ==============
__global__ __launch_bounds__(256, 2) void final_mfma(const short* __restrict__ hTp,
        const short* __restrict__ wA, c32* __restrict__ eta) {
    int wv = threadIdx.x >> 6, l = threadIdx.x & 63;
    int lr = l & 15, lg = l >> 4;
    int y = blockIdx.x >> 2;
    int x0 = (blockIdx.x & 3) << 6;
    int x = x0 + wv * 16 + lr;

    auto loadB = [&](int tap, bf16x8& b0, bf16x8& b1) {
        int dy = tap / 3 - 1, dx = tap % 3 - 1;
        const short* pB = hTp +
            ((size_t)((y + dy + 2) * P2 + (x + dx + 2)) << 6) + lg * 8;
        b0 = *(const bf16x8*)(pB);
        b1 = *(const bf16x8*)(pB + 32);
    };

    f32x4 C = (f32x4){0.f, 0.f, 0.f, 0.f};
    bf16x8 cB0, cB1;
    loadB(0, cB0, cB1);
    #pragma unroll
    for (int tap = 0; tap < 9; ++tap) {
        const short* pA = wA + (size_t)(tap * 16 + lr) * 64 + lg * 8;
        bf16x8 A0 = *(const bf16x8*)(pA);
        bf16x8 A1 = *(const bf16x8*)(pA + 32);
        bf16x8 nB0, nB1;
        if (tap < 8) loadB(tap + 1, nB0, nB1);
        C = __builtin_amdgcn_mfma_f32_16x16x32_bf16(A0, cB0, C, 0, 0, 0);
        C = __builtin_amdgcn_mfma_f32_16x16x32_bf16(A1, cB1, C, 0, 0, 0);
        if (tap < 8) { cB0 = nB0; cB1 = nB1; }
    }
    if (lg == 0) {
        int px = y * 256 + x;
        c32 e = eta[px];
        eta[px] = make_float2(e.x + C[0], e.y + C[1]);
    }
}

// ===================== host orchestration =====================
extern "C" void kernel_launch(void* const* d_in, const int* in_sizes, int n_in,
                              void* d_out, int out_size, void* d_ws, size_t ws_size,
                              hipStream_t stream) {
    const c32* pred   = (const c32*)d_in[0];
    const c32* ksp    = (const c32*)d_in[1];
    const c32* sense  = (const c32*)d_in[2];
    const int* mask   = (const int*)d_in[3];
    const float* c1w  = (const float*)d_in[4];
    const float* c1b  = (const float*)d_in[5];
    const float* g1iw = (const float*)d_in[6];
    const float* g1ib = (const float*)d_in[7];
    const float* g1hw = (const float*)d_in[8];
    const float* g1hb = (const float*)d_in[9];
    const float* c2w  = (const float*)d_in[10];
    const float* c2b  = (const float*)d_in[11];
    const float* g2iw = (const float*)d_in[12];
    const float* g2ib = (const float*)d_in[13];
    const float* g2hw = (const float*)d_in[14];
    const float* g2hb = (const float*)d_in[15];
    const float* fw   = (const float*)d_in[16];
    const float* dcw  = (const float*)d_in[17];

    const size_t PP = (size_t)P2 * P2;     // 67600 padded pixels
    float* w0 = (float*)d_ws;
    c32* base = (c32*)w0;                  // NC*HW complex
    c32* Fk   = base + NC * HW;            // NC*HW complex
    c32* tmp  = Fk + NC * HW;              // NC*HW complex (init only)
    c32* eta  = tmp + NC * HW;             // HW complex
    short* gTp = (short*)(eta + HW);       // PP*4 bf16 (padded)
    short* h1Ta = gTp + PP * 4;            // PP*64 bf16 (padded)
    short* h1Tb = h1Ta + PP * 64;
    short* h2Ta = h1Tb + PP * 64;
    short* h2Tb = h2Ta + PP * 64;
    short* w2a  = h2Tb + PP * 64;          // 256*128 bf16
    short* w2b  = w2a + 256 * 128;
    float* biasA = (float*)(w2b + 256 * 128);
    float* biasB = biasA + 256;
    short* wAc2 = (short*)(biasB + 256);   // 9*64*64 bf16
    short* wAc1 = wAc2 + 9 * 64 * 64;      // 64*128 bf16
    short* wAcf = wAc1 + 64 * 128;         // 9*16*64 bf16

    dim3 B(256);
    const int gCHW = NC * HW / 256;   // 3072
    const int gHW  = HW / 256;        // 256
    const int gROW = NC * 256 / 4;    // 768
    dim3 gCOL(64, NC);
    const int gC1 = HW / 32;          // 2048 blocks (conv1+gru1)
    const int gC2 = HW / 64;          // 1024 blocks (conv2+gru2, final)

    // border zeroing + weight prep (once per call)
    k_zero_border<<<9, B, 0, stream>>>(gTp, h1Ta, h1Tb, h2Ta, h2Tb);
    k_prep_gru<<<256, 128, 0, stream>>>(g1iw, g1ib, g1hw, g1hb, w2a, biasA);
    k_prep_gru<<<256, 128, 0, stream>>>(g2iw, g2ib, g2hw, g2hb, w2b, biasB);
    k_prep_c2<<<144, 256, 0, stream>>>(c2w, wAc2);
    k_prep_c1<<<32, 256, 0, stream>>>(c1w, wAc1);
    k_prep_cf<<<36, 256, 0, stream>>>(fw, wAcf);

    // eta0 = sum_c ifft2c(pred_c) * conj(sense_c)
    fft_rows_pre<<<gROW, B, 0, stream>>>(tmp, pred);
    fft_cols<<<gCOL, B, 0, stream>>>(tmp, -1.0f);
    k_combine_eta0<<<gHW, B, 0, stream>>>(tmp, sense, eta);

    k_base<<<gCHW, B, 0, stream>>>(ksp, pred, mask, dcw, base);

    // F_0: forward FFT of S*(eta0*sense); fused epilogue -> residual (no out)
    fft_rows_exp<<<gROW, B, 0, stream>>>(Fk, eta, sense);
    fft_cols_fused<<<gCOL, B, 0, stream>>>(Fk, base, ksp, mask, (c32*)d_out, 0);

    short* h1c = h1Ta; short* h1n = h1Tb;
    short* h2c = h2Ta; short* h2n = h2Tb;
    c32* outp = (c32*)d_out;

    for (int t = 0; t < NT; ++t) {
        fft_rows_grad<<<gHW, B, 0, stream>>>(Fk, sense, eta, gTp);

        if (t == 0) {
            conv1_gru1<true><<<gC1, B, 0, stream>>>(gTp, wAc1, c1b, w2a, biasA, h1c, h1n);
        } else {
            conv1_gru1<false><<<gC1, B, 0, stream>>>(gTp, wAc1, c1b, w2a, biasA, h1c, h1n);
        }
        { short* s = h1c; h1c = h1n; h1n = s; }
        if (t == 0) {
            conv2_gru2<true><<<gC2, B, 0, stream>>>(h1c, wAc2, c2b, w2b, biasB, h2c, h2n);
        } else {
            conv2_gru2<false><<<gC2, B, 0, stream>>>(h1c, wAc2, c2b, w2b, biasB, h2c, h2n);
        }
        { short* s = h2c; h2c = h2n; h2n = s; }
        final_mfma<<<gC2, B, 0, stream>>>(h2c, wAcf, eta);

        fft_rows_exp<<<gROW, B, 0, stream>>>(Fk, eta, sense);
        fft_cols_fused<<<gCOL, B, 0, stream>>>(Fk, base, ksp, mask,
                                               outp + (size_t)t * NC * HW, 1);
    }
}